// Round 1
// baseline (926.702 us; speedup 1.0000x reference)
//
#include <hip/hip_runtime.h>
#include <stdint.h>

typedef unsigned short u16;
typedef unsigned int u32;
typedef __attribute__((ext_vector_type(8))) short short8;
typedef __attribute__((ext_vector_type(4))) float f32x4;

// ---------------- problem constants ----------------
#define Bsz 2
#define Tn 2048
#define Dm 1024
#define H_ATTN 16
#define HDx 64
#define WINx 128
#define H_SSM 8
#define DIx 2048
#define Nst 16
#define DTRx 64
#define Px 256          // DI / H_SSM
#define TOTx 4416       // 2*DI + DTR + 2*H*N
#define BT (Bsz*Tn)     // 4096
#define NCH 32          // chunks
#define LCH 64          // chunk length

// ---------------- helpers ----------------
__device__ __forceinline__ float b2f(u16 u){ u32 x = ((u32)u)<<16; float f; __builtin_memcpy(&f,&x,4); return f; }
__device__ __forceinline__ u16 f2b(float f){ u32 x; __builtin_memcpy(&x,&f,4); u32 r = x + 0x7fffu + ((x>>16)&1u); return (u16)(r>>16); }

__device__ __forceinline__ float block_sum256(float v){
  #pragma unroll
  for (int o=32;o;o>>=1) v += __shfl_xor(v,o,64);
  __shared__ float sb[4];
  int wid = threadIdx.x>>6;
  if ((threadIdx.x&63)==0) sb[wid]=v;
  __syncthreads();
  v = sb[0]+sb[1]+sb[2]+sb[3];
  __syncthreads();
  return v;
}

__device__ __forceinline__ void gload_lds16(const void* g, void* l){
  __builtin_amdgcn_global_load_lds((const __attribute__((address_space(1))) void*)g,
                                   (__attribute__((address_space(3))) void*)l, 16, 0, 0);
}

// ---------------- fp32 -> bf16 convert ----------------
__global__ __launch_bounds__(256) void k_f32_to_bf16(const float* __restrict__ s, u16* __restrict__ d, int n){
  int i = (blockIdx.x*256 + threadIdx.x)*4;
  if (i < n){
    float4 v = *(const float4*)(s+i);
    d[i+0]=f2b(v.x); d[i+1]=f2b(v.y); d[i+2]=f2b(v.z); d[i+3]=f2b(v.w);
  }
}

// ---------------- rms over 1024 (fp32 in -> bf16 out) ----------------
__global__ __launch_bounds__(256) void k_rms1024(const float* __restrict__ src, const float* __restrict__ w,
                                                 u16* __restrict__ dst){
  int row = blockIdx.x, tid = threadIdx.x;
  const float* s = src + (size_t)row*1024;
  float v[4]; float ss=0.f;
  #pragma unroll
  for (int i=0;i<4;i++){ v[i] = s[tid + i*256]; ss += v[i]*v[i]; }
  ss = block_sum256(ss);
  float sc = rsqrtf(ss*(1.0f/1024.0f) + 1e-6f);
  u16* d = dst + (size_t)row*1024;
  #pragma unroll
  for (int i=0;i<4;i++){ int c = tid+i*256; d[c] = f2b(v[i]*sc*w[c]); }
}

// ---------------- GEMM: C[M,N] (+)= A[M,K] * W[N,K]^T, bf16 in, fp32 out ----------------
__global__ __launch_bounds__(256) void k_gemm_bt(const u16* __restrict__ A, const u16* __restrict__ W,
                                                 float* __restrict__ C, int M, int N, int K, int accum){
  __shared__ u16 lA[128*32];
  __shared__ u16 lB[128*32];
  int tid = threadIdx.x, lane = tid&63, wid = tid>>6;
  int bm = blockIdx.y*128, bn = blockIdx.x*128;
  int wm = (wid>>1)*64, wn = (wid&1)*64;
  int fr = lane&15, fq = lane>>4;
  f32x4 acc[4][4];
  #pragma unroll
  for (int a=0;a<4;a++)
    #pragma unroll
    for (int b=0;b<4;b++)
      #pragma unroll
      for (int r=0;r<4;r++) acc[a][b][r] = 0.f;

  int cl = (lane&3)*8;
  for (int k0=0;k0<K;k0+=32){
    #pragma unroll
    for (int j=0;j<2;j++){
      int rt = wid*32 + j*16 + (lane>>2);
      int ra = bm + rt; if (ra > M-1) ra = M-1;
      int rb = bn + rt; if (rb > N-1) rb = N-1;
      gload_lds16(A + (size_t)ra*K + k0 + cl, &lA[(wid*2+j)*512]);
      gload_lds16(W + (size_t)rb*K + k0 + cl, &lB[(wid*2+j)*512]);
    }
    __syncthreads();
    short8 af[4], bfv[4];
    #pragma unroll
    for (int mi=0;mi<4;mi++) af[mi]  = *(const short8*)(&lA[(wm + mi*16 + fr)*32 + fq*8]);
    #pragma unroll
    for (int ni=0;ni<4;ni++) bfv[ni] = *(const short8*)(&lB[(wn + ni*16 + fr)*32 + fq*8]);
    #pragma unroll
    for (int mi=0;mi<4;mi++)
      #pragma unroll
      for (int ni=0;ni<4;ni++)
        acc[mi][ni] = __builtin_amdgcn_mfma_f32_16x16x32_bf16(af[mi], bfv[ni], acc[mi][ni], 0,0,0);
    __syncthreads();
  }
  #pragma unroll
  for (int mi=0;mi<4;mi++){
    int row0 = bm + wm + mi*16 + fq*4;
    #pragma unroll
    for (int ni=0;ni<4;ni++){
      int col = bn + wn + ni*16 + fr;
      if (col < N){
        #pragma unroll
        for (int r=0;r<4;r++){
          size_t idx = (size_t)(row0+r)*N + col;
          float v = acc[mi][ni][r];
          C[idx] = accum ? (C[idx] + v) : v;
        }
      }
    }
  }
}

// ---------------- depthwise causal conv (K=4) + silu ----------------
__global__ __launch_bounds__(256) void k_conv_silu(const float* __restrict__ proj, const float* __restrict__ cw,
                                                   const float* __restrict__ cb, float* __restrict__ xc){
  int idx = blockIdx.x*256 + threadIdx.x;   // over BT*DI
  int c = idx & (DIx-1);
  int bt = idx >> 11;
  int t = bt & (Tn-1);
  float acc = cb[c];
  #pragma unroll
  for (int k=0;k<4;k++){
    int tt = t - 3 + k;
    if (tt >= 0) acc += proj[(size_t)(bt-3+k)*TOTx + c] * cw[c*4+k];
  }
  xc[idx] = acc / (1.0f + expf(-acc));
}

// ---------------- dt prep: dt = clip(softplus(dtl@Wdt^T + bias)); dtA, dtB ----------------
__global__ __launch_bounds__(256) void k_dtprep(const float* __restrict__ proj, const float* __restrict__ Wdt,
      const float* __restrict__ dt_bias, const float* __restrict__ A_log,
      float* __restrict__ dtA, float* __restrict__ dtB){
  int idx = blockIdx.x*256 + threadIdx.x;  // BT*H_SSM
  int h = idx & 7; int bt = idx >> 3;
  const float* dtl  = proj + (size_t)bt*TOTx + 2*DIx;
  const float* wrow = Wdt + h*64;
  float v = dt_bias[h];
  #pragma unroll 8
  for (int i=0;i<64;i++) v += dtl[i]*wrow[i];
  float sp = (v > 20.0f) ? v : log1pf(expf(v));
  float dt = fminf(fmaxf(sp, 1e-4f), 1.0f);
  const float* bm = proj + (size_t)bt*TOTx + 2*DIx + DTRx + h*16;
  #pragma unroll
  for (int n=0;n<16;n++){
    float Av = -expf(A_log[h*16+n]);
    dtA[(size_t)idx*16+n] = dt*Av;
    dtB[(size_t)idx*16+n] = dt*bm[n];
  }
}

// ---------------- scan phase 1: per-chunk local scan ----------------
__global__ __launch_bounds__(256) void k_scan1(const float* __restrict__ dtA, const float* __restrict__ dtB,
    const float* __restrict__ proj, const float* __restrict__ xc,
    float* __restrict__ expS, float* __restrict__ y, float* __restrict__ LS){
  __shared__ float sA[1024], sS[1024], sB[1024], sC[1024];
  int bx = blockIdx.x;                 // b*256 + h*32 + c
  int c = bx & 31, h = (bx>>5)&7, b = bx>>8;
  int tid = threadIdx.x;
  size_t t0 = (size_t)b*Tn + c*64;
  int j = tid>>2, n0 = (tid&3)*4;
  {
    size_t ga = (t0 + j)*128 + h*16 + n0;
    float4 va = *(const float4*)(dtA + ga);
    float4 vb = *(const float4*)(dtB + ga);
    float4 vc = *(const float4*)(proj + (t0 + j)*TOTx + (2*DIx+DTRx+H_SSM*Nst) + h*16 + n0);
    *(float4*)(&sA[j*16+n0]) = va;
    *(float4*)(&sB[j*16+n0]) = vb;
    *(float4*)(&sC[j*16+n0]) = vc;
  }
  __syncthreads();
  if (tid < 16){
    float cum = 0.f;
    for (int jj=0;jj<64;jj++){ cum += sA[jj*16+tid]; sS[jj*16+tid] = cum; }
  }
  __syncthreads();
  {
    float e[4], s4[4];
    #pragma unroll
    for (int i=0;i<4;i++){ e[i] = expf(sA[j*16+n0+i]); s4[i] = expf(sS[j*16+n0+i]); }
    #pragma unroll
    for (int i=0;i<4;i++){ sA[j*16+n0+i] = e[i]; sS[j*16+n0+i] = s4[i]; }
    float4 ev; ev.x=s4[0]; ev.y=s4[1]; ev.z=s4[2]; ev.w=s4[3];
    *(float4*)(expS + (t0+j)*128 + h*16 + n0) = ev;
  }
  __syncthreads();
  float st[16];
  #pragma unroll
  for (int n=0;n<16;n++) st[n]=0.f;
  const float* xp = xc + t0*DIx + h*Px + tid;
  float* yp = y + t0*DIx + h*Px + tid;
  for (int jj=0;jj<64;jj++){
    float x = xp[(size_t)jj*DIx];
    float acc = 0.f;
    #pragma unroll
    for (int n=0;n<16;n++){ st[n] = st[n]*sA[jj*16+n] + x*sB[jj*16+n]; acc += st[n]*sC[jj*16+n]; }
    yp[(size_t)jj*DIx] = acc;
  }
  float* ls = LS + ((((size_t)b*8+h)*NCH + c)*Px + tid)*16;
  #pragma unroll
  for (int n=0;n<16;n++) ls[n] = st[n];
}

// ---------------- scan phase 2: chunk-state scan ----------------
__global__ __launch_bounds__(256) void k_scan2(const float* __restrict__ expS, const float* __restrict__ LS,
                                               float* __restrict__ H0){
  int bh = blockIdx.x; int b = bh>>3, h = bh&7;
  int tid = threadIdx.x;
  __shared__ float dl[16];
  float Hs[16];
  #pragma unroll
  for (int n=0;n<16;n++) Hs[n]=0.f;
  for (int c=0;c<NCH;c++){
    if (tid<16) dl[tid] = expS[((size_t)b*Tn + c*64 + 63)*128 + h*16 + tid];
    __syncthreads();
    size_t base = ((((size_t)b*8+h)*NCH + c)*Px + tid)*16;
    #pragma unroll
    for (int n=0;n<16;n++){ H0[base+n] = Hs[n]; Hs[n] = Hs[n]*dl[n] + LS[base+n]; }
    __syncthreads();
  }
}

// ---------------- scan phase 3: fixup + Dskip ----------------
__global__ __launch_bounds__(256) void k_scan3(const float* __restrict__ proj, const float* __restrict__ expS,
    const float* __restrict__ H0, const float* __restrict__ xc, const float* __restrict__ Dskip,
    float* __restrict__ y){
  __shared__ float ce[1024];
  int bx = blockIdx.x; int c = bx&31, h=(bx>>5)&7, b=bx>>8;
  int tid = threadIdx.x;
  size_t t0 = (size_t)b*Tn + c*64;
  int j = tid>>2, n0=(tid&3)*4;
  {
    float4 cv = *(const float4*)(proj + (t0+j)*TOTx + (2*DIx+DTRx+H_SSM*Nst) + h*16 + n0);
    float4 evv = *(const float4*)(expS + (t0+j)*128 + h*16 + n0);
    float4 o; o.x=cv.x*evv.x; o.y=cv.y*evv.y; o.z=cv.z*evv.z; o.w=cv.w*evv.w;
    *(float4*)(&ce[j*16+n0]) = o;
  }
  __syncthreads();
  float h0[16];
  size_t base = ((((size_t)b*8+h)*NCH + c)*Px + tid)*16;
  #pragma unroll
  for (int n=0;n<16;n++) h0[n] = H0[base+n];
  float dsk = Dskip[h*Px + tid];
  const float* xp = xc + t0*DIx + h*Px + tid;
  float* yp = y + t0*DIx + h*Px + tid;
  for (int jj=0;jj<64;jj++){
    float x = xp[(size_t)jj*DIx];
    float f = 0.f;
    #pragma unroll
    for (int n=0;n<16;n++) f += ce[jj*16+n]*h0[n];
    yp[(size_t)jj*DIx] += f + dsk*x;
  }
}

// ---------------- gated rms: yn = rms(y * silu(z)) * w, bf16 out ----------------
__global__ __launch_bounds__(256) void k_gatedrms(const float* __restrict__ y, const float* __restrict__ proj,
     const float* __restrict__ w, u16* __restrict__ yn){
  int row = blockIdx.x, tid = threadIdx.x;
  const float* yr = y + (size_t)row*DIx;
  const float* zr = proj + (size_t)row*TOTx + DIx;
  float v[8]; float ss=0.f;
  #pragma unroll
  for (int i=0;i<8;i++){
    int cidx = tid + i*256;
    float z = zr[cidx];
    float g = yr[cidx] * (z / (1.0f + expf(-z)));
    v[i]=g; ss += g*g;
  }
  ss = block_sum256(ss);
  float sc = rsqrtf(ss*(1.0f/2048.0f) + 1e-6f);
  u16* d = yn + (size_t)row*DIx;
  #pragma unroll
  for (int i=0;i<8;i++){ int cidx=tid+i*256; d[cidx] = f2b(v[i]*sc*w[cidx]); }
}

// ---------------- h = x + sout; u2 = rms(h)*w (bf16) ----------------
__global__ __launch_bounds__(256) void k_addrms(const float* __restrict__ x, const float* __restrict__ sout,
     const float* __restrict__ w, float* __restrict__ hbuf, u16* __restrict__ u2){
  int row=blockIdx.x, tid=threadIdx.x;
  float v[4]; float ss=0.f;
  #pragma unroll
  for (int i=0;i<4;i++){
    int cidx = tid + i*256;
    size_t idx = (size_t)row*1024 + cidx;
    float hv = x[idx] + sout[idx];
    hbuf[idx]=hv; v[i]=hv; ss+=hv*hv;
  }
  ss = block_sum256(ss);
  float sc = rsqrtf(ss*(1.0f/1024.0f)+1e-6f);
  #pragma unroll
  for (int i=0;i<4;i++){ int cidx=tid+i*256; u2[(size_t)row*1024+cidx] = f2b(v[i]*sc*w[cidx]); }
}

// ---------------- rope + transpose to [B,H,T,HD] (bf16) ----------------
__global__ __launch_bounds__(256) void k_rope(const float* __restrict__ qf, const float* __restrict__ kf,
    const float* __restrict__ vf, u16* __restrict__ qr, u16* __restrict__ kr, u16* __restrict__ vr){
  int idx = blockIdx.x*256 + threadIdx.x;  // B*T*D
  int d = idx & 63;
  int h = (idx>>6) & 15;
  int t = (idx>>10) & 2047;
  int b = idx >> 21;
  int dh = d & 31;
  float ang = (float)t * exp2f(-(float)dh * (13.287712379549449f/32.0f));  // t * 10000^(-dh/32)
  float cs = cosf(ang), sn = sinf(ang);
  int part = (d<32) ? 32 : -32;
  float q = qf[idx], qp = qf[idx+part];
  float k = kf[idx], kp = kf[idx+part];
  float rq = (d<32)? -qp : qp;
  float rk = (d<32)? -kp : kp;
  size_t dst = (((size_t)b*H_ATTN + h)*Tn + t)*64 + d;
  qr[dst] = f2b(q*cs + rq*sn);
  kr[dst] = f2b(k*cs + rk*sn);
  vr[dst] = f2b(vf[idx]);
}

// ---------------- sliding-window attention, one wave per query ----------------
__global__ __launch_bounds__(256) void k_attn(const u16* __restrict__ qr, const u16* __restrict__ kr,
    const u16* __restrict__ vr, u16* __restrict__ ya){
  __shared__ float qls[4*64];
  __shared__ float pls[4*128];
  int tid = threadIdx.x, lane = tid&63, wid = tid>>6;
  int gq = blockIdx.x*4 + wid;       // over B*H*T
  int t = gq & (Tn-1);
  int bh = gq >> 11;                 // b*16 + h
  size_t rowbase = (size_t)bh*Tn;
  qls[wid*64 + lane] = b2f(qr[(rowbase + t)*64 + lane]) * 0.125f;  // 1/sqrt(64)
  const float* qv = &qls[wid*64];
  float sc[2];
  #pragma unroll
  for (int r=0;r<2;r++){
    int s = t - 127 + lane + r*64;
    float dot = -1e30f;
    if (s >= 0){
      const u32* kp = (const u32*)(kr + (rowbase + s)*64);
      dot = 0.f;
      #pragma unroll
      for (int u=0;u<32;u++){
        u32 w = kp[u];
        dot += b2f((u16)(w&0xffffu))*qv[2*u] + b2f((u16)(w>>16))*qv[2*u+1];
      }
    }
    sc[r] = dot;
  }
  float m = fmaxf(sc[0], sc[1]);
  #pragma unroll
  for (int o=32;o;o>>=1) m = fmaxf(m, __shfl_xor(m,o,64));
  float p0 = expf(sc[0]-m), p1 = expf(sc[1]-m);
  float sum = p0+p1;
  #pragma unroll
  for (int o=32;o;o>>=1) sum += __shfl_xor(sum,o,64);
  pls[wid*128 + lane] = p0;
  pls[wid*128 + lane + 64] = p1;
  float inv = 1.0f / sum;
  const float* pv = &pls[wid*128];
  float acc = 0.f;
  int s0 = t - 127;
  for (int jj=0;jj<128;jj++){
    int s = s0 + jj;
    if (s >= 0) acc += pv[jj] * b2f(vr[(rowbase + s)*64 + lane]);
  }
  int b = bh >> 4, h = bh & 15;
  ya[((size_t)b*Tn + t)*Dm + h*64 + lane] = f2b(acc * inv);
}

// ---------------- final: out = h + att (fp32) ----------------
__global__ __launch_bounds__(256) void k_final(const float* __restrict__ hbuf, const float* __restrict__ att,
                                               float* __restrict__ out){
  int i = blockIdx.x*256 + threadIdx.x;
  out[i] = hbuf[i] + att[i];
}

// =================================================================
extern "C" void kernel_launch(void* const* d_in, const int* in_sizes, int n_in,
                              void* d_out, int out_size, void* d_ws, size_t ws_size,
                              hipStream_t stream) {
  const float* x        = (const float*)d_in[0];
  const float* norm1_w  = (const float*)d_in[1];
  const float* norm2_w  = (const float*)d_in[2];
  const float* Win      = (const float*)d_in[3];
  const float* Wdt      = (const float*)d_in[4];
  const float* conv_w   = (const float*)d_in[5];
  const float* conv_b   = (const float*)d_in[6];
  const float* A_log    = (const float*)d_in[7];
  const float* Dskip    = (const float*)d_in[8];
  const float* dt_bias  = (const float*)d_in[9];
  const float* ssd_norm = (const float*)d_in[10];
  const float* Wout_ssd = (const float*)d_in[11];
  const float* Wres     = (const float*)d_in[12];
  const float* Wq       = (const float*)d_in[13];
  const float* Wk       = (const float*)d_in[14];
  const float* Wv       = (const float*)d_in[15];
  const float* Wo       = (const float*)d_in[16];

  char* ws = (char*)d_ws;
  size_t off = 0;
  auto alloc = [&](size_t bytes){ size_t r = off; off += (bytes + 255) & ~(size_t)255; return r; };

  size_t o_WinB  = alloc((size_t)TOTx*Dm*2);
  size_t o_WresB = alloc((size_t)DIx*Dm*2);
  size_t o_WoutB = alloc((size_t)Dm*DIx*2);
  size_t o_WqB   = alloc((size_t)Dm*Dm*2);
  size_t o_WkB   = alloc((size_t)Dm*Dm*2);
  size_t o_WvB   = alloc((size_t)Dm*Dm*2);
  size_t o_WoB   = alloc((size_t)Dm*Dm*2);
  size_t o_u1    = alloc((size_t)BT*Dm*2);        // later reused as vr (same size)
  size_t o_proj  = alloc((size_t)BT*TOTx*4);      // later: qf/kf/vf (fp32), qr/kr (bf16)
  size_t o_xc    = alloc((size_t)BT*DIx*4);       // later: sout @+0, att @+16MiB
  size_t o_dtA   = alloc((size_t)BT*H_SSM*Nst*4);
  size_t o_dtB   = alloc((size_t)BT*H_SSM*Nst*4);
  size_t o_expS  = alloc((size_t)BT*H_SSM*Nst*4);
  size_t o_LS    = alloc((size_t)Bsz*H_SSM*NCH*Px*Nst*4);
  size_t o_H0    = alloc((size_t)Bsz*H_SSM*NCH*Px*Nst*4);
  size_t o_y     = alloc((size_t)BT*DIx*4);       // later: y_att bf16 @+0
  size_t o_yn    = alloc((size_t)BT*DIx*2);
  size_t o_hb    = alloc((size_t)BT*Dm*4);

  u16* WinB  = (u16*)(ws + o_WinB);
  u16* WresB = (u16*)(ws + o_WresB);
  u16* WoutB = (u16*)(ws + o_WoutB);
  u16* WqB   = (u16*)(ws + o_WqB);
  u16* WkB   = (u16*)(ws + o_WkB);
  u16* WvB   = (u16*)(ws + o_WvB);
  u16* WoB   = (u16*)(ws + o_WoB);
  u16* u1    = (u16*)(ws + o_u1);
  float* proj = (float*)(ws + o_proj);
  float* xc   = (float*)(ws + o_xc);
  float* dtA  = (float*)(ws + o_dtA);
  float* dtB  = (float*)(ws + o_dtB);
  float* expS = (float*)(ws + o_expS);
  float* LS   = (float*)(ws + o_LS);
  float* H0   = (float*)(ws + o_H0);
  float* ybuf = (float*)(ws + o_y);
  u16*   yn   = (u16*)(ws + o_yn);
  float* hb   = (float*)(ws + o_hb);
  // aliases (lifetimes disjoint)
  float* qf = (float*)(ws + o_proj);
  float* kf = (float*)(ws + o_proj + 16777216);
  float* vf = (float*)(ws + o_proj + 33554432);
  u16* qr = (u16*)(ws + o_proj + 50331648);
  u16* kr = (u16*)(ws + o_proj + 58720256);
  u16* vr = u1;
  float* sout = (float*)(ws + o_xc);
  float* att  = (float*)(ws + o_xc + 16777216);
  u16* yatt = (u16*)(ws + o_y);
  u16* u2   = (u16*)(ws + o_yn);  // NOTE: yn dead after Wout gemm; u2 written after -> reuse yn region? NO: yn needed in gemm that makes sout, u2 written after that gemm. Safe.

  auto cvt = [&](const float* src, u16* dst, int n){
    k_f32_to_bf16<<<dim3((n/4 + 255)/256), dim3(256), 0, stream>>>(src, dst, n);
  };
  cvt(Win,  WinB,  TOTx*Dm);
  cvt(Wres, WresB, DIx*Dm);
  cvt(Wout_ssd, WoutB, Dm*DIx);
  cvt(Wq, WqB, Dm*Dm);
  cvt(Wk, WkB, Dm*Dm);
  cvt(Wv, WvB, Dm*Dm);
  cvt(Wo, WoB, Dm*Dm);

  // 1) u1 = rms(x, norm1_w)
  k_rms1024<<<dim3(BT), dim3(256), 0, stream>>>(x, norm1_w, u1);
  // 2) proj = u1 @ Win^T
  k_gemm_bt<<<dim3((TOTx+127)/128, BT/128), dim3(256), 0, stream>>>(u1, WinB, proj, BT, TOTx, Dm, 0);
  // 3) xc = silu(conv(xin))
  k_conv_silu<<<dim3(BT*DIx/256), dim3(256), 0, stream>>>(proj, conv_w, conv_b, xc);
  // 4) dt prep
  k_dtprep<<<dim3(BT*H_SSM/256), dim3(256), 0, stream>>>(proj, Wdt, dt_bias, A_log, dtA, dtB);
  // 5) chunked scan
  k_scan1<<<dim3(Bsz*H_SSM*NCH), dim3(256), 0, stream>>>(dtA, dtB, proj, xc, expS, ybuf, LS);
  k_scan2<<<dim3(Bsz*H_SSM), dim3(256), 0, stream>>>(expS, LS, H0);
  k_scan3<<<dim3(Bsz*H_SSM*NCH), dim3(256), 0, stream>>>(proj, expS, H0, xc, Dskip, ybuf);
  // 6) y += u1 @ Wres^T
  k_gemm_bt<<<dim3(DIx/128, BT/128), dim3(256), 0, stream>>>(u1, WresB, ybuf, BT, DIx, Dm, 1);
  // 7) yn = rms(y * silu(z)) * ssd_norm_w
  k_gatedrms<<<dim3(BT), dim3(256), 0, stream>>>(ybuf, proj, ssd_norm, yn);
  // 8) sout = yn @ Wout^T
  k_gemm_bt<<<dim3(Dm/128, BT/128), dim3(256), 0, stream>>>(yn, WoutB, sout, BT, Dm, DIx, 0);
  // 9) h = x + sout; u2 = rms(h)*norm2_w
  k_addrms<<<dim3(BT), dim3(256), 0, stream>>>(x, sout, norm2_w, hb, (u16*)(ws + o_yn));
  u16* u2p = (u16*)(ws + o_yn);
  // 10) q/k/v projections
  k_gemm_bt<<<dim3(Dm/128, BT/128), dim3(256), 0, stream>>>(u2p, WqB, qf, BT, Dm, Dm, 0);
  k_gemm_bt<<<dim3(Dm/128, BT/128), dim3(256), 0, stream>>>(u2p, WkB, kf, BT, Dm, Dm, 0);
  k_gemm_bt<<<dim3(Dm/128, BT/128), dim3(256), 0, stream>>>(u2p, WvB, vf, BT, Dm, Dm, 0);
  // 11) rope + transpose
  k_rope<<<dim3(BT*Dm/256), dim3(256), 0, stream>>>(qf, kf, vf, qr, kr, vr);
  // 12) attention
  k_attn<<<dim3(Bsz*H_ATTN*Tn/4), dim3(256), 0, stream>>>(qr, kr, vr, yatt);
  // 13) att = yatt @ Wo^T
  k_gemm_bt<<<dim3(Dm/128, BT/128), dim3(256), 0, stream>>>(yatt, WoB, att, BT, Dm, Dm, 0);
  // 14) out = h + att
  k_final<<<dim3(BT*Dm/256), dim3(256), 0, stream>>>(hb, att, (float*)d_out);
  (void)in_sizes; (void)n_in; (void)out_size; (void)ws_size;
}

// Round 2
// 532.396 us; speedup vs baseline: 1.7406x; 1.7406x over previous
//
#include <hip/hip_runtime.h>
#include <stdint.h>

typedef unsigned short u16;
typedef unsigned int u32;
typedef __attribute__((ext_vector_type(8))) short short8;
typedef __attribute__((ext_vector_type(4))) float f32x4;

// ---------------- problem constants ----------------
#define Bsz 2
#define Tn 2048
#define Dm 1024
#define H_ATTN 16
#define HDx 64
#define WINx 128
#define H_SSM 8
#define DIx 2048
#define Nst 16
#define DTRx 64
#define Px 256          // DI / H_SSM
#define TOTx 4416       // 2*DI + DTR + 2*H*N
#define BT (Bsz*Tn)     // 4096
#define NCH 32          // chunks
#define LCH 64          // chunk length

// ---------------- helpers ----------------
__device__ __forceinline__ float b2f(u16 u){ u32 x = ((u32)u)<<16; float f; __builtin_memcpy(&f,&x,4); return f; }
__device__ __forceinline__ u16 f2b(float f){ u32 x; __builtin_memcpy(&x,&f,4); u32 r = x + 0x7fffu + ((x>>16)&1u); return (u16)(r>>16); }

__device__ __forceinline__ float block_sum256(float v){
  #pragma unroll
  for (int o=32;o;o>>=1) v += __shfl_xor(v,o,64);
  __shared__ float sb[4];
  int wid = threadIdx.x>>6;
  if ((threadIdx.x&63)==0) sb[wid]=v;
  __syncthreads();
  v = sb[0]+sb[1]+sb[2]+sb[3];
  __syncthreads();
  return v;
}

__device__ __forceinline__ void gload_lds16(const void* g, void* l){
  __builtin_amdgcn_global_load_lds((const __attribute__((address_space(1))) void*)g,
                                   (__attribute__((address_space(3))) void*)l, 16, 0, 0);
}

// ---------------- fp32 -> bf16 convert ----------------
__global__ __launch_bounds__(256) void k_f32_to_bf16(const float* __restrict__ s, u16* __restrict__ d, int n){
  int i = (blockIdx.x*256 + threadIdx.x)*4;
  if (i < n){
    float4 v = *(const float4*)(s+i);
    d[i+0]=f2b(v.x); d[i+1]=f2b(v.y); d[i+2]=f2b(v.z); d[i+3]=f2b(v.w);
  }
}

// ---------------- rms over 1024 (fp32 in -> bf16 out) ----------------
__global__ __launch_bounds__(256) void k_rms1024(const float* __restrict__ src, const float* __restrict__ w,
                                                 u16* __restrict__ dst){
  int row = blockIdx.x, tid = threadIdx.x;
  const float* s = src + (size_t)row*1024;
  float v[4]; float ss=0.f;
  #pragma unroll
  for (int i=0;i<4;i++){ v[i] = s[tid + i*256]; ss += v[i]*v[i]; }
  ss = block_sum256(ss);
  float sc = rsqrtf(ss*(1.0f/1024.0f) + 1e-6f);
  u16* d = dst + (size_t)row*1024;
  #pragma unroll
  for (int i=0;i<4;i++){ int c = tid+i*256; d[c] = f2b(v[i]*sc*w[c]); }
}

// ---------------- GEMM: C[M,N] (+)= A[M,K] * W[N,K]^T, bf16 in, fp32 out ----------------
__global__ __launch_bounds__(256) void k_gemm_bt(const u16* __restrict__ A, const u16* __restrict__ W,
                                                 float* __restrict__ C, int M, int N, int K, int accum){
  __shared__ u16 lA[128*32];
  __shared__ u16 lB[128*32];
  int tid = threadIdx.x, lane = tid&63, wid = tid>>6;
  int bm = blockIdx.y*128, bn = blockIdx.x*128;
  int wm = (wid>>1)*64, wn = (wid&1)*64;
  int fr = lane&15, fq = lane>>4;
  f32x4 acc[4][4];
  #pragma unroll
  for (int a=0;a<4;a++)
    #pragma unroll
    for (int b=0;b<4;b++)
      #pragma unroll
      for (int r=0;r<4;r++) acc[a][b][r] = 0.f;

  int cl = (lane&3)*8;
  for (int k0=0;k0<K;k0+=32){
    #pragma unroll
    for (int j=0;j<2;j++){
      int rt = wid*32 + j*16 + (lane>>2);
      int ra = bm + rt; if (ra > M-1) ra = M-1;
      int rb = bn + rt; if (rb > N-1) rb = N-1;
      gload_lds16(A + (size_t)ra*K + k0 + cl, &lA[(wid*2+j)*512]);
      gload_lds16(W + (size_t)rb*K + k0 + cl, &lB[(wid*2+j)*512]);
    }
    __syncthreads();
    short8 af[4], bfv[4];
    #pragma unroll
    for (int mi=0;mi<4;mi++) af[mi]  = *(const short8*)(&lA[(wm + mi*16 + fr)*32 + fq*8]);
    #pragma unroll
    for (int ni=0;ni<4;ni++) bfv[ni] = *(const short8*)(&lB[(wn + ni*16 + fr)*32 + fq*8]);
    #pragma unroll
    for (int mi=0;mi<4;mi++)
      #pragma unroll
      for (int ni=0;ni<4;ni++)
        acc[mi][ni] = __builtin_amdgcn_mfma_f32_16x16x32_bf16(af[mi], bfv[ni], acc[mi][ni], 0,0,0);
    __syncthreads();
  }
  #pragma unroll
  for (int mi=0;mi<4;mi++){
    int row0 = bm + wm + mi*16 + fq*4;
    #pragma unroll
    for (int ni=0;ni<4;ni++){
      int col = bn + wn + ni*16 + fr;
      if (col < N){
        #pragma unroll
        for (int r=0;r<4;r++){
          size_t idx = (size_t)(row0+r)*N + col;
          float v = acc[mi][ni][r];
          C[idx] = accum ? (C[idx] + v) : v;
        }
      }
    }
  }
}

// ---------------- depthwise causal conv (K=4) + silu ----------------
__global__ __launch_bounds__(256) void k_conv_silu(const float* __restrict__ proj, const float* __restrict__ cw,
                                                   const float* __restrict__ cb, float* __restrict__ xc){
  int idx = blockIdx.x*256 + threadIdx.x;   // over BT*DI
  int c = idx & (DIx-1);
  int bt = idx >> 11;
  int t = bt & (Tn-1);
  float acc = cb[c];
  #pragma unroll
  for (int k=0;k<4;k++){
    int tt = t - 3 + k;
    if (tt >= 0) acc += proj[(size_t)(bt-3+k)*TOTx + c] * cw[c*4+k];
  }
  xc[idx] = acc / (1.0f + expf(-acc));
}

// ---------------- dt prep: dt = clip(softplus(dtl@Wdt^T + bias)); dtA, dtB ----------------
__global__ __launch_bounds__(256) void k_dtprep(const float* __restrict__ proj, const float* __restrict__ Wdt,
      const float* __restrict__ dt_bias, const float* __restrict__ A_log,
      float* __restrict__ dtA, float* __restrict__ dtB){
  int idx = blockIdx.x*256 + threadIdx.x;  // BT*H_SSM
  int h = idx & 7; int bt = idx >> 3;
  const float* dtl  = proj + (size_t)bt*TOTx + 2*DIx;
  const float* wrow = Wdt + h*64;
  float v = dt_bias[h];
  #pragma unroll 8
  for (int i=0;i<64;i++) v += dtl[i]*wrow[i];
  float sp = (v > 20.0f) ? v : log1pf(expf(v));
  float dt = fminf(fmaxf(sp, 1e-4f), 1.0f);
  const float* bm = proj + (size_t)bt*TOTx + 2*DIx + DTRx + h*16;
  #pragma unroll
  for (int n=0;n<16;n++){
    float Av = -expf(A_log[h*16+n]);
    dtA[(size_t)idx*16+n] = dt*Av;
    dtB[(size_t)idx*16+n] = dt*bm[n];
  }
}

// ---------------- scan phase 1: per-chunk local scan ----------------
__global__ __launch_bounds__(256) void k_scan1(const float* __restrict__ dtA, const float* __restrict__ dtB,
    const float* __restrict__ proj, const float* __restrict__ xc,
    float* __restrict__ expS, float* __restrict__ y, float* __restrict__ LS){
  __shared__ float sA[1024], sS[1024], sB[1024], sC[1024];
  int bx = blockIdx.x;                 // b*256 + h*32 + c
  int c = bx & 31, h = (bx>>5)&7, b = bx>>8;
  int tid = threadIdx.x;
  size_t t0 = (size_t)b*Tn + c*64;
  int j = tid>>2, n0 = (tid&3)*4;
  {
    size_t ga = (t0 + j)*128 + h*16 + n0;
    float4 va = *(const float4*)(dtA + ga);
    float4 vb = *(const float4*)(dtB + ga);
    float4 vc = *(const float4*)(proj + (t0 + j)*TOTx + (2*DIx+DTRx+H_SSM*Nst) + h*16 + n0);
    *(float4*)(&sA[j*16+n0]) = va;
    *(float4*)(&sB[j*16+n0]) = vb;
    *(float4*)(&sC[j*16+n0]) = vc;
  }
  __syncthreads();
  if (tid < 16){
    float cum = 0.f;
    for (int jj=0;jj<64;jj++){ cum += sA[jj*16+tid]; sS[jj*16+tid] = cum; }
  }
  __syncthreads();
  {
    float e[4], s4[4];
    #pragma unroll
    for (int i=0;i<4;i++){ e[i] = expf(sA[j*16+n0+i]); s4[i] = expf(sS[j*16+n0+i]); }
    #pragma unroll
    for (int i=0;i<4;i++){ sA[j*16+n0+i] = e[i]; sS[j*16+n0+i] = s4[i]; }
    float4 ev; ev.x=s4[0]; ev.y=s4[1]; ev.z=s4[2]; ev.w=s4[3];
    *(float4*)(expS + (t0+j)*128 + h*16 + n0) = ev;
  }
  __syncthreads();
  float st[16];
  #pragma unroll
  for (int n=0;n<16;n++) st[n]=0.f;
  const float* xp = xc + t0*DIx + h*Px + tid;
  float* yp = y + t0*DIx + h*Px + tid;
  for (int jj=0;jj<64;jj++){
    float x = xp[(size_t)jj*DIx];
    float acc = 0.f;
    #pragma unroll
    for (int n=0;n<16;n++){ st[n] = st[n]*sA[jj*16+n] + x*sB[jj*16+n]; acc += st[n]*sC[jj*16+n]; }
    yp[(size_t)jj*DIx] = acc;
  }
  float* ls = LS + ((((size_t)b*8+h)*NCH + c)*Px + tid)*16;
  #pragma unroll
  for (int n=0;n<16;n++) ls[n] = st[n];
}

// ---------------- scan phase 2: chunk-state scan ----------------
__global__ __launch_bounds__(256) void k_scan2(const float* __restrict__ expS, const float* __restrict__ LS,
                                               float* __restrict__ H0){
  int bh = blockIdx.x; int b = bh>>3, h = bh&7;
  int tid = threadIdx.x;
  __shared__ float dl[16];
  float Hs[16];
  #pragma unroll
  for (int n=0;n<16;n++) Hs[n]=0.f;
  for (int c=0;c<NCH;c++){
    if (tid<16) dl[tid] = expS[((size_t)b*Tn + c*64 + 63)*128 + h*16 + tid];
    __syncthreads();
    size_t base = ((((size_t)b*8+h)*NCH + c)*Px + tid)*16;
    #pragma unroll
    for (int n=0;n<16;n++){ H0[base+n] = Hs[n]; Hs[n] = Hs[n]*dl[n] + LS[base+n]; }
    __syncthreads();
  }
}

// ---------------- scan phase 3: fixup + Dskip ----------------
__global__ __launch_bounds__(256) void k_scan3(const float* __restrict__ proj, const float* __restrict__ expS,
    const float* __restrict__ H0, const float* __restrict__ xc, const float* __restrict__ Dskip,
    float* __restrict__ y){
  __shared__ float ce[1024];
  int bx = blockIdx.x; int c = bx&31, h=(bx>>5)&7, b=bx>>8;
  int tid = threadIdx.x;
  size_t t0 = (size_t)b*Tn + c*64;
  int j = tid>>2, n0=(tid&3)*4;
  {
    float4 cv = *(const float4*)(proj + (t0+j)*TOTx + (2*DIx+DTRx+H_SSM*Nst) + h*16 + n0);
    float4 evv = *(const float4*)(expS + (t0+j)*128 + h*16 + n0);
    float4 o; o.x=cv.x*evv.x; o.y=cv.y*evv.y; o.z=cv.z*evv.z; o.w=cv.w*evv.w;
    *(float4*)(&ce[j*16+n0]) = o;
  }
  __syncthreads();
  float h0[16];
  size_t base = ((((size_t)b*8+h)*NCH + c)*Px + tid)*16;
  #pragma unroll
  for (int n=0;n<16;n++) h0[n] = H0[base+n];
  float dsk = Dskip[h*Px + tid];
  const float* xp = xc + t0*DIx + h*Px + tid;
  float* yp = y + t0*DIx + h*Px + tid;
  for (int jj=0;jj<64;jj++){
    float x = xp[(size_t)jj*DIx];
    float f = 0.f;
    #pragma unroll
    for (int n=0;n<16;n++) f += ce[jj*16+n]*h0[n];
    yp[(size_t)jj*DIx] += f + dsk*x;
  }
}

// ---------------- gated rms: yn = rms(y * silu(z)) * w, bf16 out ----------------
__global__ __launch_bounds__(256) void k_gatedrms(const float* __restrict__ y, const float* __restrict__ proj,
     const float* __restrict__ w, u16* __restrict__ yn){
  int row = blockIdx.x, tid = threadIdx.x;
  const float* yr = y + (size_t)row*DIx;
  const float* zr = proj + (size_t)row*TOTx + DIx;
  float v[8]; float ss=0.f;
  #pragma unroll
  for (int i=0;i<8;i++){
    int cidx = tid + i*256;
    float z = zr[cidx];
    float g = yr[cidx] * (z / (1.0f + expf(-z)));
    v[i]=g; ss += g*g;
  }
  ss = block_sum256(ss);
  float sc = rsqrtf(ss*(1.0f/2048.0f) + 1e-6f);
  u16* d = yn + (size_t)row*DIx;
  #pragma unroll
  for (int i=0;i<8;i++){ int cidx=tid+i*256; d[cidx] = f2b(v[i]*sc*w[cidx]); }
}

// ---------------- h = x + sout; u2 = rms(h)*w (bf16) ----------------
__global__ __launch_bounds__(256) void k_addrms(const float* __restrict__ x, const float* __restrict__ sout,
     const float* __restrict__ w, float* __restrict__ hbuf, u16* __restrict__ u2){
  int row=blockIdx.x, tid=threadIdx.x;
  float v[4]; float ss=0.f;
  #pragma unroll
  for (int i=0;i<4;i++){
    int cidx = tid + i*256;
    size_t idx = (size_t)row*1024 + cidx;
    float hv = x[idx] + sout[idx];
    hbuf[idx]=hv; v[i]=hv; ss+=hv*hv;
  }
  ss = block_sum256(ss);
  float sc = rsqrtf(ss*(1.0f/1024.0f)+1e-6f);
  #pragma unroll
  for (int i=0;i<4;i++){ int cidx=tid+i*256; u2[(size_t)row*1024+cidx] = f2b(v[i]*sc*w[cidx]); }
}

// ---------------- rope + transpose to [B,H,T,HD] (bf16) ----------------
__global__ __launch_bounds__(256) void k_rope(const float* __restrict__ qf, const float* __restrict__ kf,
    const float* __restrict__ vf, u16* __restrict__ qr, u16* __restrict__ kr, u16* __restrict__ vr){
  int idx = blockIdx.x*256 + threadIdx.x;  // B*T*D
  int d = idx & 63;
  int h = (idx>>6) & 15;
  int t = (idx>>10) & 2047;
  int b = idx >> 21;
  int dh = d & 31;
  float ang = (float)t * exp2f(-(float)dh * (13.287712379549449f/32.0f));  // t * 10000^(-dh/32)
  float cs = cosf(ang), sn = sinf(ang);
  int part = (d<32) ? 32 : -32;
  float q = qf[idx], qp = qf[idx+part];
  float k = kf[idx], kp = kf[idx+part];
  float rq = (d<32)? -qp : qp;
  float rk = (d<32)? -kp : kp;
  size_t dst = (((size_t)b*H_ATTN + h)*Tn + t)*64 + d;
  qr[dst] = f2b(q*cs + rq*sn);
  kr[dst] = f2b(k*cs + rk*sn);
  vr[dst] = f2b(vf[idx]);
}

// ---------------- MFMA sliding-window attention ----------------
// Block: one (b,h) x 64-query tile. Key span 192: s_global = t0-128+c, c in [0,192).
// bufK: K [192][64] bf16 (24KB), later reused as P [64][192] bf16 (24KB).
// bufV: V^T [64][192] bf16 (24KB).
#define QT 64
#define KSPAN 192
__device__ __forceinline__ u32 swz128(int row, int b){  // tile stride 128B
  return (u32)((row*128 + b) ^ ((((row&7)^((row>>3)&7)))<<4));
}
__device__ __forceinline__ u32 swz384(int row, int b){  // tile stride 384B
  return (u32)((row*384 + b) ^ ((((row&7)^((row>>3)&7)))<<4));
}

__global__ __launch_bounds__(256) void k_attn_mfma(const u16* __restrict__ qr, const u16* __restrict__ kr,
    const u16* __restrict__ vr, u16* __restrict__ ya){
  __shared__ u16 bufK[KSPAN*64];   // 24576 B ; later P[64][192] (same byte size)
  __shared__ u16 bufV[64*KSPAN];   // 24576 B
  int tid = threadIdx.x, lane = tid&63, wid = tid>>6;
  int fr = lane&15, fq = lane>>4;
  int blk = blockIdx.x;            // bh*32 + qt
  int qt = blk & 31, bh = blk >> 5;
  int t0 = qt*QT;
  size_t rowbase = (size_t)bh*Tn;
  char* cK = (char*)bufK;
  char* cV = (char*)bufV;

  // ---- stage K (rows with s_global<0 left unstaged; masked before use) ----
  #pragma unroll
  for (int it=0; it<6; ++it){
    int chunk = it*256 + tid;        // 1536 chunks of 16B
    int row = chunk>>3, c8 = chunk&7;
    int sg = t0 - 128 + row;
    if (sg >= 0){
      short8 v = *(const short8*)(kr + (rowbase+sg)*64 + c8*8);
      *(short8*)(cK + swz128(row, c8*16)) = v;
    }
  }
  // ---- stage V transposed: bufV[d][s] = vr[s][d]; zero-fill s_global<0 ----
  #pragma unroll
  for (int it=0; it<24; ++it){
    int idx = it*256 + tid;          // 6144 = 192 rows * 32 (u32 pairs)
    int s = idx>>5, dp = idx&31, d0 = dp*2;
    int sg = t0 - 128 + s;
    u16 lo = 0, hi = 0;
    if (sg >= 0){
      u32 w = *(const u32*)(vr + (rowbase+sg)*64 + d0);
      lo = (u16)(w & 0xffffu); hi = (u16)(w >> 16);
    }
    *(u16*)(cV + swz384(d0,   s*2)) = lo;
    *(u16*)(cV + swz384(d0+1, s*2)) = hi;
  }
  __syncthreads();

  // ---- QK^T: wave computes rows wid*16..+15 x all 192 cols ----
  f32x4 acc[12];
  #pragma unroll
  for (int j=0;j<12;j++)
    #pragma unroll
    for (int r=0;r<4;r++) acc[j][r]=0.f;
  #pragma unroll
  for (int kk=0;kk<2;kk++){
    short8 aq = *(const short8*)(qr + (rowbase + t0 + wid*16 + fr)*64 + kk*32 + fq*8);
    #pragma unroll
    for (int j=0;j<12;j++){
      short8 bk = *(const short8*)(cK + swz128(j*16+fr, kk*64 + fq*16));
      acc[j] = __builtin_amdgcn_mfma_f32_16x16x32_bf16(aq, bk, acc[j], 0,0,0);
    }
  }

  // ---- in-register softmax per row ----
  // C layout: col = j*16 + (lane&15); row(in 16-blk) = (lane>>4)*4 + r
  float p[12][4];
  int cb = lane&15;
  #pragma unroll
  for (int r=0;r<4;r++){
    int rq = wid*16 + (lane>>4)*4 + r;       // local query row in [0,64)
    float m = -3.0e38f;
    #pragma unroll
    for (int j=0;j<12;j++){
      int c = j*16 + cb;
      bool allowed = (c > rq) && (c <= rq+128) && (c >= 128 - t0);
      float v = allowed ? acc[j][r]*0.125f : -3.0e38f;
      p[j][r] = v;
      m = fmaxf(m, v);
    }
    #pragma unroll
    for (int o=1;o<16;o<<=1) m = fmaxf(m, __shfl_xor(m, o, 64));
    float sum = 0.f;
    #pragma unroll
    for (int j=0;j<12;j++){ float e = __expf(p[j][r]-m); p[j][r]=e; sum += e; }
    #pragma unroll
    for (int o=1;o<16;o<<=1) sum += __shfl_xor(sum, o, 64);
    float inv = 1.0f/sum;
    #pragma unroll
    for (int j=0;j<12;j++) p[j][r] *= inv;
  }
  __syncthreads();   // all waves done reading K -> safe to overwrite with P

  // ---- write P (bf16) into bufK region as [64][192] ----
  #pragma unroll
  for (int r=0;r<4;r++){
    int rq = wid*16 + (lane>>4)*4 + r;
    #pragma unroll
    for (int j=0;j<12;j++){
      *(u16*)(cK + swz384(rq, (j*16+cb)*2)) = f2b(p[j][r]);
    }
  }
  __syncthreads();

  // ---- PV: out rows = same 16 q, cols = 64 d; k-dim = 192 ----
  f32x4 acc2[4];
  #pragma unroll
  for (int f=0;f<4;f++)
    #pragma unroll
    for (int r=0;r<4;r++) acc2[f][r]=0.f;
  #pragma unroll
  for (int kk=0;kk<6;kk++){
    short8 ap = *(const short8*)(cK + swz384(wid*16 + fr, kk*64 + fq*16));
    #pragma unroll
    for (int f=0;f<4;f++){
      short8 bv = *(const short8*)(cV + swz384(f*16+fr, kk*64 + fq*16));
      acc2[f] = __builtin_amdgcn_mfma_f32_16x16x32_bf16(ap, bv, acc2[f], 0,0,0);
    }
  }
  // ---- store: ya[(b*Tn + q)*Dm + h*64 + d] ----
  int b = bh >> 4, h = bh & 15;
  #pragma unroll
  for (int f=0;f<4;f++){
    int d = f*16 + cb;
    #pragma unroll
    for (int r=0;r<4;r++){
      int q = t0 + wid*16 + (lane>>4)*4 + r;
      ya[((size_t)b*Tn + q)*Dm + h*64 + d] = f2b(acc2[f][r]);
    }
  }
}

// ---------------- final: out = h + att (fp32) ----------------
__global__ __launch_bounds__(256) void k_final(const float* __restrict__ hbuf, const float* __restrict__ att,
                                               float* __restrict__ out){
  int i = blockIdx.x*256 + threadIdx.x;
  out[i] = hbuf[i] + att[i];
}

// =================================================================
extern "C" void kernel_launch(void* const* d_in, const int* in_sizes, int n_in,
                              void* d_out, int out_size, void* d_ws, size_t ws_size,
                              hipStream_t stream) {
  const float* x        = (const float*)d_in[0];
  const float* norm1_w  = (const float*)d_in[1];
  const float* norm2_w  = (const float*)d_in[2];
  const float* Win      = (const float*)d_in[3];
  const float* Wdt      = (const float*)d_in[4];
  const float* conv_w   = (const float*)d_in[5];
  const float* conv_b   = (const float*)d_in[6];
  const float* A_log    = (const float*)d_in[7];
  const float* Dskip    = (const float*)d_in[8];
  const float* dt_bias  = (const float*)d_in[9];
  const float* ssd_norm = (const float*)d_in[10];
  const float* Wout_ssd = (const float*)d_in[11];
  const float* Wres     = (const float*)d_in[12];
  const float* Wq       = (const float*)d_in[13];
  const float* Wk       = (const float*)d_in[14];
  const float* Wv       = (const float*)d_in[15];
  const float* Wo       = (const float*)d_in[16];

  char* ws = (char*)d_ws;
  size_t off = 0;
  auto alloc = [&](size_t bytes){ size_t r = off; off += (bytes + 255) & ~(size_t)255; return r; };

  size_t o_WinB  = alloc((size_t)TOTx*Dm*2);
  size_t o_WresB = alloc((size_t)DIx*Dm*2);
  size_t o_WoutB = alloc((size_t)Dm*DIx*2);
  size_t o_WqB   = alloc((size_t)Dm*Dm*2);
  size_t o_WkB   = alloc((size_t)Dm*Dm*2);
  size_t o_WvB   = alloc((size_t)Dm*Dm*2);
  size_t o_WoB   = alloc((size_t)Dm*Dm*2);
  size_t o_u1    = alloc((size_t)BT*Dm*2);        // later reused as vr (same size)
  size_t o_proj  = alloc((size_t)BT*TOTx*4);      // later: qf/kf/vf (fp32), qr/kr (bf16)
  size_t o_xc    = alloc((size_t)BT*DIx*4);       // later: sout @+0, att @+16MiB
  size_t o_dtA   = alloc((size_t)BT*H_SSM*Nst*4);
  size_t o_dtB   = alloc((size_t)BT*H_SSM*Nst*4);
  size_t o_expS  = alloc((size_t)BT*H_SSM*Nst*4);
  size_t o_LS    = alloc((size_t)Bsz*H_SSM*NCH*Px*Nst*4);
  size_t o_H0    = alloc((size_t)Bsz*H_SSM*NCH*Px*Nst*4);
  size_t o_y     = alloc((size_t)BT*DIx*4);       // later: y_att bf16 @+0
  size_t o_yn    = alloc((size_t)BT*DIx*2);
  size_t o_hb    = alloc((size_t)BT*Dm*4);

  u16* WinB  = (u16*)(ws + o_WinB);
  u16* WresB = (u16*)(ws + o_WresB);
  u16* WoutB = (u16*)(ws + o_WoutB);
  u16* WqB   = (u16*)(ws + o_WqB);
  u16* WkB   = (u16*)(ws + o_WkB);
  u16* WvB   = (u16*)(ws + o_WvB);
  u16* WoB   = (u16*)(ws + o_WoB);
  u16* u1    = (u16*)(ws + o_u1);
  float* proj = (float*)(ws + o_proj);
  float* xc   = (float*)(ws + o_xc);
  float* dtA  = (float*)(ws + o_dtA);
  float* dtB  = (float*)(ws + o_dtB);
  float* expS = (float*)(ws + o_expS);
  float* LS   = (float*)(ws + o_LS);
  float* H0   = (float*)(ws + o_H0);
  float* ybuf = (float*)(ws + o_y);
  u16*   yn   = (u16*)(ws + o_yn);
  float* hb   = (float*)(ws + o_hb);
  // aliases (lifetimes disjoint)
  float* qf = (float*)(ws + o_proj);
  float* kf = (float*)(ws + o_proj + 16777216);
  float* vf = (float*)(ws + o_proj + 33554432);
  u16* qr = (u16*)(ws + o_proj + 50331648);
  u16* kr = (u16*)(ws + o_proj + 58720256);
  u16* vr = u1;
  float* sout = (float*)(ws + o_xc);
  float* att  = (float*)(ws + o_xc + 16777216);
  u16* yatt = (u16*)(ws + o_y);

  auto cvt = [&](const float* src, u16* dst, int n){
    k_f32_to_bf16<<<dim3((n/4 + 255)/256), dim3(256), 0, stream>>>(src, dst, n);
  };
  cvt(Win,  WinB,  TOTx*Dm);
  cvt(Wres, WresB, DIx*Dm);
  cvt(Wout_ssd, WoutB, Dm*DIx);
  cvt(Wq, WqB, Dm*Dm);
  cvt(Wk, WkB, Dm*Dm);
  cvt(Wv, WvB, Dm*Dm);
  cvt(Wo, WoB, Dm*Dm);

  // 1) u1 = rms(x, norm1_w)
  k_rms1024<<<dim3(BT), dim3(256), 0, stream>>>(x, norm1_w, u1);
  // 2) proj = u1 @ Win^T
  k_gemm_bt<<<dim3((TOTx+127)/128, BT/128), dim3(256), 0, stream>>>(u1, WinB, proj, BT, TOTx, Dm, 0);
  // 3) xc = silu(conv(xin))
  k_conv_silu<<<dim3(BT*DIx/256), dim3(256), 0, stream>>>(proj, conv_w, conv_b, xc);
  // 4) dt prep
  k_dtprep<<<dim3(BT*H_SSM/256), dim3(256), 0, stream>>>(proj, Wdt, dt_bias, A_log, dtA, dtB);
  // 5) chunked scan
  k_scan1<<<dim3(Bsz*H_SSM*NCH), dim3(256), 0, stream>>>(dtA, dtB, proj, xc, expS, ybuf, LS);
  k_scan2<<<dim3(Bsz*H_SSM), dim3(256), 0, stream>>>(expS, LS, H0);
  k_scan3<<<dim3(Bsz*H_SSM*NCH), dim3(256), 0, stream>>>(proj, expS, H0, xc, Dskip, ybuf);
  // 6) y += u1 @ Wres^T
  k_gemm_bt<<<dim3(DIx/128, BT/128), dim3(256), 0, stream>>>(u1, WresB, ybuf, BT, DIx, Dm, 1);
  // 7) yn = rms(y * silu(z)) * ssd_norm_w
  k_gatedrms<<<dim3(BT), dim3(256), 0, stream>>>(ybuf, proj, ssd_norm, yn);
  // 8) sout = yn @ Wout^T
  k_gemm_bt<<<dim3(Dm/128, BT/128), dim3(256), 0, stream>>>(yn, WoutB, sout, BT, Dm, DIx, 0);
  // 9) h = x + sout; u2 = rms(h)*norm2_w
  k_addrms<<<dim3(BT), dim3(256), 0, stream>>>(x, sout, norm2_w, hb, (u16*)(ws + o_yn));
  u16* u2p = (u16*)(ws + o_yn);
  // 10) q/k/v projections
  k_gemm_bt<<<dim3(Dm/128, BT/128), dim3(256), 0, stream>>>(u2p, WqB, qf, BT, Dm, Dm, 0);
  k_gemm_bt<<<dim3(Dm/128, BT/128), dim3(256), 0, stream>>>(u2p, WkB, kf, BT, Dm, Dm, 0);
  k_gemm_bt<<<dim3(Dm/128, BT/128), dim3(256), 0, stream>>>(u2p, WvB, vf, BT, Dm, Dm, 0);
  // 11) rope + transpose
  k_rope<<<dim3(BT*Dm/256), dim3(256), 0, stream>>>(qf, kf, vf, qr, kr, vr);
  // 12) attention (MFMA sliding-window)
  k_attn_mfma<<<dim3(Bsz*H_ATTN*(Tn/QT)), dim3(256), 0, stream>>>(qr, kr, vr, yatt);
  // 13) att = yatt @ Wo^T
  k_gemm_bt<<<dim3(Dm/128, BT/128), dim3(256), 0, stream>>>(yatt, WoB, att, BT, Dm, Dm, 0);
  // 14) out = h + att
  k_final<<<dim3(BT*Dm/256), dim3(256), 0, stream>>>(hb, att, (float*)d_out);
  (void)in_sizes; (void)n_in; (void)out_size; (void)ws_size;
}

// Round 3
// 487.795 us; speedup vs baseline: 1.8998x; 1.0914x over previous
//
#include <hip/hip_runtime.h>
#include <stdint.h>

typedef unsigned short u16;
typedef unsigned int u32;
typedef __attribute__((ext_vector_type(8))) short short8;
typedef __attribute__((ext_vector_type(4))) float f32x4;

// ---------------- problem constants ----------------
#define Bsz 2
#define Tn 2048
#define Dm 1024
#define H_ATTN 16
#define HDx 64
#define WINx 128
#define H_SSM 8
#define DIx 2048
#define Nst 16
#define DTRx 64
#define Px 256          // DI / H_SSM
#define TOTx 4416       // 2*DI + DTR + 2*H*N
#define BT (Bsz*Tn)     // 4096
#define NCH 32          // chunks
#define LCH 64          // chunk length

// ---------------- helpers ----------------
__device__ __forceinline__ float b2f(u16 u){ u32 x = ((u32)u)<<16; float f; __builtin_memcpy(&f,&x,4); return f; }
__device__ __forceinline__ u16 f2b(float f){ u32 x; __builtin_memcpy(&x,&f,4); u32 r = x + 0x7fffu + ((x>>16)&1u); return (u16)(r>>16); }

__device__ __forceinline__ float block_sum256(float v){
  #pragma unroll
  for (int o=32;o;o>>=1) v += __shfl_xor(v,o,64);
  __shared__ float sb[4];
  int wid = threadIdx.x>>6;
  if ((threadIdx.x&63)==0) sb[wid]=v;
  __syncthreads();
  v = sb[0]+sb[1]+sb[2]+sb[3];
  __syncthreads();
  return v;
}

__device__ __forceinline__ void gload_lds16(const void* g, void* l){
  __builtin_amdgcn_global_load_lds((const __attribute__((address_space(1))) void*)g,
                                   (__attribute__((address_space(3))) void*)l, 16, 0, 0);
}

// ---------------- fused fp32 -> bf16 convert (all 7 weights, 1 launch) ----------------
struct CvtArgs { const float* s[7]; u16* d[7]; int n[7]; };
__global__ __launch_bounds__(256) void k_cvt_all(CvtArgs a, int total4){
  int i = blockIdx.x*256 + threadIdx.x;   // in float4 units
  if (i >= total4) return;
  int e = i*4;
  #pragma unroll
  for (int j=0;j<7;j++){
    if (e < a.n[j]){
      float4 v = *(const float4*)(a.s[j]+e);
      u16* d = a.d[j]+e;
      d[0]=f2b(v.x); d[1]=f2b(v.y); d[2]=f2b(v.z); d[3]=f2b(v.w);
      return;
    }
    e -= a.n[j];
  }
}

// ---------------- rms over 1024 (fp32 in -> bf16 out) ----------------
__global__ __launch_bounds__(256) void k_rms1024(const float* __restrict__ src, const float* __restrict__ w,
                                                 u16* __restrict__ dst){
  int row = blockIdx.x, tid = threadIdx.x;
  const float* s = src + (size_t)row*1024;
  float v[4]; float ss=0.f;
  #pragma unroll
  for (int i=0;i<4;i++){ v[i] = s[tid + i*256]; ss += v[i]*v[i]; }
  ss = block_sum256(ss);
  float sc = rsqrtf(ss*(1.0f/1024.0f) + 1e-6f);
  u16* d = dst + (size_t)row*1024;
  #pragma unroll
  for (int i=0;i<4;i++){ int c = tid+i*256; d[c] = f2b(v[i]*sc*w[c]); }
}

// ---------------- GEMM 128x128 BK=32 (for N<=2048 shapes) ----------------
__global__ __launch_bounds__(256) void k_gemm_bt(const u16* __restrict__ A, const u16* __restrict__ W,
                                                 float* __restrict__ C, int M, int N, int K, int accum){
  __shared__ u16 lA[128*32];
  __shared__ u16 lB[128*32];
  int tid = threadIdx.x, lane = tid&63, wid = tid>>6;
  int bm = blockIdx.y*128, bn = blockIdx.x*128;
  int wm = (wid>>1)*64, wn = (wid&1)*64;
  int fr = lane&15, fq = lane>>4;
  f32x4 acc[4][4];
  #pragma unroll
  for (int a=0;a<4;a++)
    #pragma unroll
    for (int b=0;b<4;b++)
      #pragma unroll
      for (int r=0;r<4;r++) acc[a][b][r] = 0.f;

  int cl = (lane&3)*8;
  for (int k0=0;k0<K;k0+=32){
    #pragma unroll
    for (int j=0;j<2;j++){
      int rt = wid*32 + j*16 + (lane>>2);
      int ra = bm + rt; if (ra > M-1) ra = M-1;
      int rb = bn + rt; if (rb > N-1) rb = N-1;
      gload_lds16(A + (size_t)ra*K + k0 + cl, &lA[(wid*2+j)*512]);
      gload_lds16(W + (size_t)rb*K + k0 + cl, &lB[(wid*2+j)*512]);
    }
    __syncthreads();
    short8 af[4], bfv[4];
    #pragma unroll
    for (int mi=0;mi<4;mi++) af[mi]  = *(const short8*)(&lA[(wm + mi*16 + fr)*32 + fq*8]);
    #pragma unroll
    for (int ni=0;ni<4;ni++) bfv[ni] = *(const short8*)(&lB[(wn + ni*16 + fr)*32 + fq*8]);
    #pragma unroll
    for (int mi=0;mi<4;mi++)
      #pragma unroll
      for (int ni=0;ni<4;ni++)
        acc[mi][ni] = __builtin_amdgcn_mfma_f32_16x16x32_bf16(af[mi], bfv[ni], acc[mi][ni], 0,0,0);
    __syncthreads();
  }
  #pragma unroll
  for (int mi=0;mi<4;mi++){
    int row0 = bm + wm + mi*16 + fq*4;
    #pragma unroll
    for (int ni=0;ni<4;ni++){
      int col = bn + wn + ni*16 + fr;
      if (col < N){
        #pragma unroll
        for (int r=0;r<4;r++){
          size_t idx = (size_t)(row0+r)*N + col;
          float v = acc[mi][ni][r];
          C[idx] = accum ? (C[idx] + v) : v;
        }
      }
    }
  }
}

// ---------------- GEMM 256x256 BK=64, 8 waves, 2-phase min-pipeline ----------------
// 1D grid (nwg%8==0), XCD-bijective swizzle. C[M,N] = A[M,K]*W[N,K]^T fp32 out.
#define BKq 64
__global__ __launch_bounds__(512,2) void k_gemm256(const u16* __restrict__ A, const u16* __restrict__ W,
                                                   float* __restrict__ C, int M, int N, int K, int gx){
  __shared__ u16 lA[2][256*BKq];   // 2 x 32KB
  __shared__ u16 lB[2][256*BKq];   // 2 x 32KB
  int tid = threadIdx.x, lane = tid&63, wid = tid>>6;
  int nwg = gridDim.x;
  int cpx = nwg>>3;
  int bid = blockIdx.x;
  int swz = (bid&7)*cpx + (bid>>3);
  int bx = swz % gx, by = swz / gx;
  int bm = by*256, bn = bx*256;
  int wr = wid>>2, wc = wid&3;
  int fr = lane&15, fq = lane>>4;
  f32x4 acc[8][4];
  #pragma unroll
  for (int mi=0;mi<8;mi++)
    #pragma unroll
    for (int ni=0;ni<4;ni++)
      #pragma unroll
      for (int r=0;r<4;r++) acc[mi][ni][r]=0.f;

  int srow = (lane>>3);        // 0..7
  int scol = (lane&7)*8;       // element offset 0..56
  auto stage = [&](int buf, int t){
    int k0 = t*BKq;
    #pragma unroll
    for (int i=0;i<4;i++){
      int row = (wid*4+i)*8 + srow;
      int ra = bm + row;                       // M always multiple of 256 here
      gload_lds16(A + (size_t)ra*K + k0 + scol, &lA[buf][(wid*4+i)*512]);
      int rb = bn + row; if (rb > N-1) rb = N-1;
      gload_lds16(W + (size_t)rb*K + k0 + scol, &lB[buf][(wid*4+i)*512]);
    }
  };

  stage(0, 0);
  __syncthreads();
  int NT = K/BKq;
  for (int t=0;t<NT;t++){
    int cur = t&1;
    if (t+1 < NT) stage(cur^1, t+1);
    #pragma unroll
    for (int kk=0;kk<2;kk++){
      short8 bf4[4];
      #pragma unroll
      for (int ni=0;ni<4;ni++)
        bf4[ni] = *(const short8*)(&lB[cur][(wc*64 + ni*16 + fr)*BKq + kk*32 + fq*8]);
      #pragma unroll
      for (int mi=0;mi<8;mi++){
        short8 af = *(const short8*)(&lA[cur][(wr*128 + mi*16 + fr)*BKq + kk*32 + fq*8]);
        #pragma unroll
        for (int ni=0;ni<4;ni++)
          acc[mi][ni] = __builtin_amdgcn_mfma_f32_16x16x32_bf16(af, bf4[ni], acc[mi][ni], 0,0,0);
      }
    }
    __syncthreads();
  }
  // epilogue
  #pragma unroll
  for (int mi=0;mi<8;mi++){
    int row0 = bm + wr*128 + mi*16 + fq*4;
    #pragma unroll
    for (int ni=0;ni<4;ni++){
      int col = bn + wc*64 + ni*16 + fr;
      if (col < N){
        #pragma unroll
        for (int r=0;r<4;r++)
          C[(size_t)(row0+r)*N + col] = acc[mi][ni][r];
      }
    }
  }
}

// ---------------- depthwise causal conv (K=4) + silu ----------------
__global__ __launch_bounds__(256) void k_conv_silu(const float* __restrict__ proj, const float* __restrict__ cw,
                                                   const float* __restrict__ cb, float* __restrict__ xc){
  int idx = blockIdx.x*256 + threadIdx.x;   // over BT*DI
  int c = idx & (DIx-1);
  int bt = idx >> 11;
  int t = bt & (Tn-1);
  float acc = cb[c];
  #pragma unroll
  for (int k=0;k<4;k++){
    int tt = t - 3 + k;
    if (tt >= 0) acc += proj[(size_t)(bt-3+k)*TOTx + c] * cw[c*4+k];
  }
  xc[idx] = acc / (1.0f + expf(-acc));
}

// ---------------- dt prep ----------------
__global__ __launch_bounds__(256) void k_dtprep(const float* __restrict__ proj, const float* __restrict__ Wdt,
      const float* __restrict__ dt_bias, const float* __restrict__ A_log,
      float* __restrict__ dtA, float* __restrict__ dtB){
  int idx = blockIdx.x*256 + threadIdx.x;  // BT*H_SSM
  int h = idx & 7; int bt = idx >> 3;
  const float* dtl  = proj + (size_t)bt*TOTx + 2*DIx;
  const float* wrow = Wdt + h*64;
  float v = dt_bias[h];
  #pragma unroll 8
  for (int i=0;i<64;i++) v += dtl[i]*wrow[i];
  float sp = (v > 20.0f) ? v : log1pf(expf(v));
  float dt = fminf(fmaxf(sp, 1e-4f), 1.0f);
  const float* bm = proj + (size_t)bt*TOTx + 2*DIx + DTRx + h*16;
  #pragma unroll
  for (int n=0;n<16;n++){
    float Av = -expf(A_log[h*16+n]);
    dtA[(size_t)idx*16+n] = dt*Av;
    dtB[(size_t)idx*16+n] = dt*bm[n];
  }
}

// ---------------- scan phase 1: per-chunk local scan ----------------
__global__ __launch_bounds__(256) void k_scan1(const float* __restrict__ dtA, const float* __restrict__ dtB,
    const float* __restrict__ proj, const float* __restrict__ xc,
    float* __restrict__ expS, float* __restrict__ y, float* __restrict__ LS){
  __shared__ float sA[1024], sS[1024], sB[1024], sC[1024];
  int bx = blockIdx.x;                 // b*256 + h*32 + c
  int c = bx & 31, h = (bx>>5)&7, b = bx>>8;
  int tid = threadIdx.x;
  size_t t0 = (size_t)b*Tn + c*64;
  int j = tid>>2, n0 = (tid&3)*4;
  {
    size_t ga = (t0 + j)*128 + h*16 + n0;
    float4 va = *(const float4*)(dtA + ga);
    float4 vb = *(const float4*)(dtB + ga);
    float4 vc = *(const float4*)(proj + (t0 + j)*TOTx + (2*DIx+DTRx+H_SSM*Nst) + h*16 + n0);
    *(float4*)(&sA[j*16+n0]) = va;
    *(float4*)(&sB[j*16+n0]) = vb;
    *(float4*)(&sC[j*16+n0]) = vc;
  }
  __syncthreads();
  if (tid < 16){
    float cum = 0.f;
    for (int jj=0;jj<64;jj++){ cum += sA[jj*16+tid]; sS[jj*16+tid] = cum; }
  }
  __syncthreads();
  {
    float e[4], s4[4];
    #pragma unroll
    for (int i=0;i<4;i++){ e[i] = expf(sA[j*16+n0+i]); s4[i] = expf(sS[j*16+n0+i]); }
    #pragma unroll
    for (int i=0;i<4;i++){ sA[j*16+n0+i] = e[i]; sS[j*16+n0+i] = s4[i]; }
    float4 ev; ev.x=s4[0]; ev.y=s4[1]; ev.z=s4[2]; ev.w=s4[3];
    *(float4*)(expS + (t0+j)*128 + h*16 + n0) = ev;
  }
  __syncthreads();
  float st[16];
  #pragma unroll
  for (int n=0;n<16;n++) st[n]=0.f;
  const float* xp = xc + t0*DIx + h*Px + tid;
  float* yp = y + t0*DIx + h*Px + tid;
  for (int jj=0;jj<64;jj++){
    float x = xp[(size_t)jj*DIx];
    float acc = 0.f;
    #pragma unroll
    for (int n=0;n<16;n++){ st[n] = st[n]*sA[jj*16+n] + x*sB[jj*16+n]; acc += st[n]*sC[jj*16+n]; }
    yp[(size_t)jj*DIx] = acc;
  }
  float* ls = LS + ((((size_t)b*8+h)*NCH + c)*Px + tid)*16;
  #pragma unroll
  for (int n=0;n<16;n++) ls[n] = st[n];
}

// ---------------- scan phase 2: chunk-state scan ----------------
__global__ __launch_bounds__(256) void k_scan2(const float* __restrict__ expS, const float* __restrict__ LS,
                                               float* __restrict__ H0){
  int bh = blockIdx.x; int b = bh>>3, h = bh&7;
  int tid = threadIdx.x;
  __shared__ float dl[16];
  float Hs[16];
  #pragma unroll
  for (int n=0;n<16;n++) Hs[n]=0.f;
  for (int c=0;c<NCH;c++){
    if (tid<16) dl[tid] = expS[((size_t)b*Tn + c*64 + 63)*128 + h*16 + tid];
    __syncthreads();
    size_t base = ((((size_t)b*8+h)*NCH + c)*Px + tid)*16;
    #pragma unroll
    for (int n=0;n<16;n++){ H0[base+n] = Hs[n]; Hs[n] = Hs[n]*dl[n] + LS[base+n]; }
    __syncthreads();
  }
}

// ---------------- scan phase 3: fixup + Dskip ----------------
__global__ __launch_bounds__(256) void k_scan3(const float* __restrict__ proj, const float* __restrict__ expS,
    const float* __restrict__ H0, const float* __restrict__ xc, const float* __restrict__ Dskip,
    float* __restrict__ y){
  __shared__ float ce[1024];
  int bx = blockIdx.x; int c = bx&31, h=(bx>>5)&7, b=bx>>8;
  int tid = threadIdx.x;
  size_t t0 = (size_t)b*Tn + c*64;
  int j = tid>>2, n0=(tid&3)*4;
  {
    float4 cv = *(const float4*)(proj + (t0+j)*TOTx + (2*DIx+DTRx+H_SSM*Nst) + h*16 + n0);
    float4 evv = *(const float4*)(expS + (t0+j)*128 + h*16 + n0);
    float4 o; o.x=cv.x*evv.x; o.y=cv.y*evv.y; o.z=cv.z*evv.z; o.w=cv.w*evv.w;
    *(float4*)(&ce[j*16+n0]) = o;
  }
  __syncthreads();
  float h0[16];
  size_t base = ((((size_t)b*8+h)*NCH + c)*Px + tid)*16;
  #pragma unroll
  for (int n=0;n<16;n++) h0[n] = H0[base+n];
  float dsk = Dskip[h*Px + tid];
  const float* xp = xc + t0*DIx + h*Px + tid;
  float* yp = y + t0*DIx + h*Px + tid;
  for (int jj=0;jj<64;jj++){
    float x = xp[(size_t)jj*DIx];
    float f = 0.f;
    #pragma unroll
    for (int n=0;n<16;n++) f += ce[jj*16+n]*h0[n];
    yp[(size_t)jj*DIx] += f + dsk*x;
  }
}

// ---------------- gated rms ----------------
__global__ __launch_bounds__(256) void k_gatedrms(const float* __restrict__ y, const float* __restrict__ proj,
     const float* __restrict__ w, u16* __restrict__ yn){
  int row = blockIdx.x, tid = threadIdx.x;
  const float* yr = y + (size_t)row*DIx;
  const float* zr = proj + (size_t)row*TOTx + DIx;
  float v[8]; float ss=0.f;
  #pragma unroll
  for (int i=0;i<8;i++){
    int cidx = tid + i*256;
    float z = zr[cidx];
    float g = yr[cidx] * (z / (1.0f + expf(-z)));
    v[i]=g; ss += g*g;
  }
  ss = block_sum256(ss);
  float sc = rsqrtf(ss*(1.0f/2048.0f) + 1e-6f);
  u16* d = yn + (size_t)row*DIx;
  #pragma unroll
  for (int i=0;i<8;i++){ int cidx=tid+i*256; d[cidx] = f2b(v[i]*sc*w[cidx]); }
}

// ---------------- h = x + sout; u2 = rms(h)*w (bf16) ----------------
__global__ __launch_bounds__(256) void k_addrms(const float* __restrict__ x, const float* __restrict__ sout,
     const float* __restrict__ w, float* __restrict__ hbuf, u16* __restrict__ u2){
  int row=blockIdx.x, tid=threadIdx.x;
  float v[4]; float ss=0.f;
  #pragma unroll
  for (int i=0;i<4;i++){
    int cidx = tid + i*256;
    size_t idx = (size_t)row*1024 + cidx;
    float hv = x[idx] + sout[idx];
    hbuf[idx]=hv; v[i]=hv; ss+=hv*hv;
  }
  ss = block_sum256(ss);
  float sc = rsqrtf(ss*(1.0f/1024.0f)+1e-6f);
  #pragma unroll
  for (int i=0;i<4;i++){ int cidx=tid+i*256; u2[(size_t)row*1024+cidx] = f2b(v[i]*sc*w[cidx]); }
}

// ---------------- rope + transpose to [B,H,T,HD] (bf16), fused-QKV input ----------------
__global__ __launch_bounds__(256) void k_rope(const float* __restrict__ qkvf,
    u16* __restrict__ qr, u16* __restrict__ kr, u16* __restrict__ vr){
  int idx = blockIdx.x*256 + threadIdx.x;  // B*T*D
  int d = idx & 63;
  int h = (idx>>6) & 15;
  int t = (idx>>10) & 2047;
  int b = idx >> 21;
  int col = idx & 1023;
  size_t base = (size_t)(idx>>10)*3072;
  int dh = d & 31;
  float ang = (float)t * exp2f(-(float)dh * (13.287712379549449f/32.0f));  // t * 10000^(-dh/32)
  float cs = cosf(ang), sn = sinf(ang);
  int part = (d<32) ? 32 : -32;
  float q = qkvf[base + col],        qp = qkvf[base + col + part];
  float k = qkvf[base + 1024 + col], kp = qkvf[base + 1024 + col + part];
  float vv = qkvf[base + 2048 + col];
  float rq = (d<32)? -qp : qp;
  float rk = (d<32)? -kp : kp;
  size_t dst = (((size_t)b*H_ATTN + h)*Tn + t)*64 + d;
  qr[dst] = f2b(q*cs + rq*sn);
  kr[dst] = f2b(k*cs + rk*sn);
  vr[dst] = f2b(vv);
}

// ---------------- MFMA sliding-window attention ----------------
#define QT 64
#define KSPAN 192
__device__ __forceinline__ u32 swz128(int row, int b){  // tile stride 128B
  return (u32)((row*128 + b) ^ ((((row&7)^((row>>3)&7)))<<4));
}
__device__ __forceinline__ u32 swz384(int row, int b){  // tile stride 384B
  return (u32)((row*384 + b) ^ ((((row&7)^((row>>3)&7)))<<4));
}

__global__ __launch_bounds__(256) void k_attn_mfma(const u16* __restrict__ qr, const u16* __restrict__ kr,
    const u16* __restrict__ vr, u16* __restrict__ ya){
  __shared__ u16 bufK[KSPAN*64];   // 24576 B ; later P[64][192]
  __shared__ u16 bufV[64*KSPAN];   // 24576 B
  int tid = threadIdx.x, lane = tid&63, wid = tid>>6;
  int fr = lane&15, fq = lane>>4;
  int blk = blockIdx.x;            // bh*32 + qt
  int qt = blk & 31, bh = blk >> 5;
  int t0 = qt*QT;
  size_t rowbase = (size_t)bh*Tn;
  char* cK = (char*)bufK;
  char* cV = (char*)bufV;

  #pragma unroll
  for (int it=0; it<6; ++it){
    int chunk = it*256 + tid;
    int row = chunk>>3, c8 = chunk&7;
    int sg = t0 - 128 + row;
    if (sg >= 0){
      short8 v = *(const short8*)(kr + (rowbase+sg)*64 + c8*8);
      *(short8*)(cK + swz128(row, c8*16)) = v;
    }
  }
  #pragma unroll
  for (int it=0; it<24; ++it){
    int idx = it*256 + tid;
    int s = idx>>5, dp = idx&31, d0 = dp*2;
    int sg = t0 - 128 + s;
    u16 lo = 0, hi = 0;
    if (sg >= 0){
      u32 w = *(const u32*)(vr + (rowbase+sg)*64 + d0);
      lo = (u16)(w & 0xffffu); hi = (u16)(w >> 16);
    }
    *(u16*)(cV + swz384(d0,   s*2)) = lo;
    *(u16*)(cV + swz384(d0+1, s*2)) = hi;
  }
  __syncthreads();

  f32x4 acc[12];
  #pragma unroll
  for (int j=0;j<12;j++)
    #pragma unroll
    for (int r=0;r<4;r++) acc[j][r]=0.f;
  #pragma unroll
  for (int kk=0;kk<2;kk++){
    short8 aq = *(const short8*)(qr + (rowbase + t0 + wid*16 + fr)*64 + kk*32 + fq*8);
    #pragma unroll
    for (int j=0;j<12;j++){
      short8 bk = *(const short8*)(cK + swz128(j*16+fr, kk*64 + fq*16));
      acc[j] = __builtin_amdgcn_mfma_f32_16x16x32_bf16(aq, bk, acc[j], 0,0,0);
    }
  }

  float p[12][4];
  int cb = lane&15;
  #pragma unroll
  for (int r=0;r<4;r++){
    int rq = wid*16 + (lane>>4)*4 + r;
    float m = -3.0e38f;
    #pragma unroll
    for (int j=0;j<12;j++){
      int c = j*16 + cb;
      bool allowed = (c > rq) && (c <= rq+128) && (c >= 128 - t0);
      float v = allowed ? acc[j][r]*0.125f : -3.0e38f;
      p[j][r] = v;
      m = fmaxf(m, v);
    }
    #pragma unroll
    for (int o=1;o<16;o<<=1) m = fmaxf(m, __shfl_xor(m, o, 64));
    float sum = 0.f;
    #pragma unroll
    for (int j=0;j<12;j++){ float e = __expf(p[j][r]-m); p[j][r]=e; sum += e; }
    #pragma unroll
    for (int o=1;o<16;o<<=1) sum += __shfl_xor(sum, o, 64);
    float inv = 1.0f/sum;
    #pragma unroll
    for (int j=0;j<12;j++) p[j][r] *= inv;
  }
  __syncthreads();

  #pragma unroll
  for (int r=0;r<4;r++){
    int rq = wid*16 + (lane>>4)*4 + r;
    #pragma unroll
    for (int j=0;j<12;j++){
      *(u16*)(cK + swz384(rq, (j*16+cb)*2)) = f2b(p[j][r]);
    }
  }
  __syncthreads();

  f32x4 acc2[4];
  #pragma unroll
  for (int f=0;f<4;f++)
    #pragma unroll
    for (int r=0;r<4;r++) acc2[f][r]=0.f;
  #pragma unroll
  for (int kk=0;kk<6;kk++){
    short8 ap = *(const short8*)(cK + swz384(wid*16 + fr, kk*64 + fq*16));
    #pragma unroll
    for (int f=0;f<4;f++){
      short8 bv = *(const short8*)(cV + swz384(f*16+fr, kk*64 + fq*16));
      acc2[f] = __builtin_amdgcn_mfma_f32_16x16x32_bf16(ap, bv, acc2[f], 0,0,0);
    }
  }
  int b = bh >> 4, h = bh & 15;
  #pragma unroll
  for (int f=0;f<4;f++){
    int d = f*16 + cb;
    #pragma unroll
    for (int r=0;r<4;r++){
      int q = t0 + wid*16 + (lane>>4)*4 + r;
      ya[((size_t)b*Tn + q)*Dm + h*64 + d] = f2b(acc2[f][r]);
    }
  }
}

// ---------------- final: out = h + att (fp32) ----------------
__global__ __launch_bounds__(256) void k_final(const float* __restrict__ hbuf, const float* __restrict__ att,
                                               float* __restrict__ out){
  int i = blockIdx.x*256 + threadIdx.x;
  out[i] = hbuf[i] + att[i];
}

// =================================================================
extern "C" void kernel_launch(void* const* d_in, const int* in_sizes, int n_in,
                              void* d_out, int out_size, void* d_ws, size_t ws_size,
                              hipStream_t stream) {
  const float* x        = (const float*)d_in[0];
  const float* norm1_w  = (const float*)d_in[1];
  const float* norm2_w  = (const float*)d_in[2];
  const float* Win      = (const float*)d_in[3];
  const float* Wdt      = (const float*)d_in[4];
  const float* conv_w   = (const float*)d_in[5];
  const float* conv_b   = (const float*)d_in[6];
  const float* A_log    = (const float*)d_in[7];
  const float* Dskip    = (const float*)d_in[8];
  const float* dt_bias  = (const float*)d_in[9];
  const float* ssd_norm = (const float*)d_in[10];
  const float* Wout_ssd = (const float*)d_in[11];
  const float* Wres     = (const float*)d_in[12];
  const float* Wq       = (const float*)d_in[13];
  const float* Wk       = (const float*)d_in[14];
  const float* Wv       = (const float*)d_in[15];
  const float* Wo       = (const float*)d_in[16];

  char* ws = (char*)d_ws;
  size_t off = 0;
  auto alloc = [&](size_t bytes){ size_t r = off; off += (bytes + 255) & ~(size_t)255; return r; };

  size_t o_WinB  = alloc((size_t)TOTx*Dm*2);
  size_t o_WresB = alloc((size_t)DIx*Dm*2);
  size_t o_WoutB = alloc((size_t)Dm*DIx*2);
  size_t o_WqB   = alloc((size_t)Dm*Dm*2);
  size_t o_WkB   = alloc((size_t)Dm*Dm*2);
  size_t o_WvB   = alloc((size_t)Dm*Dm*2);
  size_t o_WoB   = alloc((size_t)Dm*Dm*2);
  size_t o_u1    = alloc((size_t)BT*Dm*2);        // later reused as vr
  size_t o_proj  = alloc((size_t)BT*TOTx*4);      // later: qkvf (48MiB), qr/kr (bf16)
  size_t o_xc    = alloc((size_t)BT*DIx*4);       // later: sout @+0, att @+16MiB
  size_t o_dtA   = alloc((size_t)BT*H_SSM*Nst*4);
  size_t o_dtB   = alloc((size_t)BT*H_SSM*Nst*4);
  size_t o_expS  = alloc((size_t)BT*H_SSM*Nst*4);
  size_t o_LS    = alloc((size_t)Bsz*H_SSM*NCH*Px*Nst*4);
  size_t o_H0    = alloc((size_t)Bsz*H_SSM*NCH*Px*Nst*4);
  size_t o_y     = alloc((size_t)BT*DIx*4);       // later: y_att bf16 @+0
  size_t o_yn    = alloc((size_t)BT*DIx*2);
  size_t o_hb    = alloc((size_t)BT*Dm*4);

  u16* WinB  = (u16*)(ws + o_WinB);
  u16* WresB = (u16*)(ws + o_WresB);
  u16* WoutB = (u16*)(ws + o_WoutB);
  u16* WqB   = (u16*)(ws + o_WqB);
  u16* WkB   = (u16*)(ws + o_WkB);
  u16* WvB   = (u16*)(ws + o_WvB);
  u16* WoB   = (u16*)(ws + o_WoB);
  u16* u1    = (u16*)(ws + o_u1);
  float* proj = (float*)(ws + o_proj);
  float* xc   = (float*)(ws + o_xc);
  float* dtA  = (float*)(ws + o_dtA);
  float* dtB  = (float*)(ws + o_dtB);
  float* expS = (float*)(ws + o_expS);
  float* LS   = (float*)(ws + o_LS);
  float* H0   = (float*)(ws + o_H0);
  float* ybuf = (float*)(ws + o_y);
  u16*   yn   = (u16*)(ws + o_yn);
  float* hb   = (float*)(ws + o_hb);
  // aliases (lifetimes disjoint)
  float* qkvf = (float*)(ws + o_proj);            // [BT][3072] fp32 = 48MiB
  u16* qr = (u16*)(ws + o_proj + 50331648);
  u16* kr = (u16*)(ws + o_proj + 58720256);
  u16* vr = u1;
  float* sout = (float*)(ws + o_xc);
  float* att  = (float*)(ws + o_xc + 16777216);
  u16* yatt = (u16*)(ws + o_y);

  // fused weight convert
  {
    CvtArgs a;
    a.s[0]=Win;  a.d[0]=WinB;  a.n[0]=TOTx*Dm;
    a.s[1]=Wres; a.d[1]=WresB; a.n[1]=DIx*Dm;
    a.s[2]=Wout_ssd; a.d[2]=WoutB; a.n[2]=Dm*DIx;
    a.s[3]=Wq; a.d[3]=WqB; a.n[3]=Dm*Dm;
    a.s[4]=Wk; a.d[4]=WkB; a.n[4]=Dm*Dm;
    a.s[5]=Wv; a.d[5]=WvB; a.n[5]=Dm*Dm;
    a.s[6]=Wo; a.d[6]=WoB; a.n[6]=Dm*Dm;
    int total4 = (a.n[0]+a.n[1]+a.n[2]+a.n[3]+a.n[4]+a.n[5]+a.n[6])/4;
    k_cvt_all<<<dim3((total4+255)/256), dim3(256), 0, stream>>>(a, total4);
  }

  // 1) u1 = rms(x, norm1_w)
  k_rms1024<<<dim3(BT), dim3(256), 0, stream>>>(x, norm1_w, u1);
  // 2) proj = u1 @ Win^T   (256^2 pipeline; grid 18x16=288, %8==0)
  k_gemm256<<<dim3(18*16), dim3(512), 0, stream>>>(u1, WinB, proj, BT, TOTx, Dm, 18);
  // 3) xc = silu(conv(xin))
  k_conv_silu<<<dim3(BT*DIx/256), dim3(256), 0, stream>>>(proj, conv_w, conv_b, xc);
  // 4) dt prep
  k_dtprep<<<dim3(BT*H_SSM/256), dim3(256), 0, stream>>>(proj, Wdt, dt_bias, A_log, dtA, dtB);
  // 5) chunked scan
  k_scan1<<<dim3(Bsz*H_SSM*NCH), dim3(256), 0, stream>>>(dtA, dtB, proj, xc, expS, ybuf, LS);
  k_scan2<<<dim3(Bsz*H_SSM), dim3(256), 0, stream>>>(expS, LS, H0);
  k_scan3<<<dim3(Bsz*H_SSM*NCH), dim3(256), 0, stream>>>(proj, expS, H0, xc, Dskip, ybuf);
  // 6) y += u1 @ Wres^T
  k_gemm_bt<<<dim3(DIx/128, BT/128), dim3(256), 0, stream>>>(u1, WresB, ybuf, BT, DIx, Dm, 1);
  // 7) yn = rms(y * silu(z)) * ssd_norm_w
  k_gatedrms<<<dim3(BT), dim3(256), 0, stream>>>(ybuf, proj, ssd_norm, yn);
  // 8) sout = yn @ Wout^T
  k_gemm_bt<<<dim3(Dm/128, BT/128), dim3(256), 0, stream>>>(yn, WoutB, sout, BT, Dm, DIx, 0);
  // 9) h = x + sout; u2 = rms(h)*norm2_w
  k_addrms<<<dim3(BT), dim3(256), 0, stream>>>(x, sout, norm2_w, hb, (u16*)(ws + o_yn));
  u16* u2p = (u16*)(ws + o_yn);
  // 10) fused QKV projection: qkvf = u2 @ [Wq;Wk;Wv]^T  (grid 12x16=192, %8==0)
  k_gemm256<<<dim3(12*16), dim3(512), 0, stream>>>(u2p, WqB, qkvf, BT, 3*Dm, Dm, 12);
  // 11) rope + transpose
  k_rope<<<dim3(BT*Dm/256), dim3(256), 0, stream>>>(qkvf, qr, kr, vr);
  // 12) attention (MFMA sliding-window)
  k_attn_mfma<<<dim3(Bsz*H_ATTN*(Tn/QT)), dim3(256), 0, stream>>>(qr, kr, vr, yatt);
  // 13) att = yatt @ Wo^T
  k_gemm_bt<<<dim3(Dm/128, BT/128), dim3(256), 0, stream>>>(yatt, WoB, att, BT, Dm, Dm, 0);
  // 14) out = h + att
  k_final<<<dim3(BT*Dm/256), dim3(256), 0, stream>>>(hb, att, (float*)d_out);
  (void)in_sizes; (void)n_in; (void)out_size; (void)ws_size;
}

// Round 4
// 484.445 us; speedup vs baseline: 1.9129x; 1.0069x over previous
//
#include <hip/hip_runtime.h>
#include <stdint.h>

typedef unsigned short u16;
typedef unsigned int u32;
typedef __attribute__((ext_vector_type(8))) short short8;
typedef __attribute__((ext_vector_type(4))) float f32x4;

// ---------------- problem constants ----------------
#define Bsz 2
#define Tn 2048
#define Dm 1024
#define H_ATTN 16
#define HDx 64
#define WINx 128
#define H_SSM 8
#define DIx 2048
#define Nst 16
#define DTRx 64
#define Px 256          // DI / H_SSM
#define TOTx 4416       // 2*DI + DTR + 2*H*N
#define BT (Bsz*Tn)     // 4096
#define NCH 32          // chunks
#define LCH 64          // chunk length

// ---------------- helpers ----------------
__device__ __forceinline__ float b2f(u16 u){ u32 x = ((u32)u)<<16; float f; __builtin_memcpy(&f,&x,4); return f; }
__device__ __forceinline__ u16 f2b(float f){ u32 x; __builtin_memcpy(&x,&f,4); u32 r = x + 0x7fffu + ((x>>16)&1u); return (u16)(r>>16); }

__device__ __forceinline__ float block_sum256(float v){
  #pragma unroll
  for (int o=32;o;o>>=1) v += __shfl_xor(v,o,64);
  __shared__ float sb[4];
  int wid = threadIdx.x>>6;
  if ((threadIdx.x&63)==0) sb[wid]=v;
  __syncthreads();
  v = sb[0]+sb[1]+sb[2]+sb[3];
  __syncthreads();
  return v;
}

__device__ __forceinline__ void gload_lds16(const void* g, void* l){
  __builtin_amdgcn_global_load_lds((const __attribute__((address_space(1))) void*)g,
                                   (__attribute__((address_space(3))) void*)l, 16, 0, 0);
}

// ---------------- fused fp32 -> bf16 convert (all 7 weights, 1 launch) ----------------
struct CvtArgs { const float* s[7]; u16* d[7]; int n[7]; };
__global__ __launch_bounds__(256) void k_cvt_all(CvtArgs a, int total4){
  int i = blockIdx.x*256 + threadIdx.x;   // in float4 units
  if (i >= total4) return;
  int e = i*4;
  #pragma unroll
  for (int j=0;j<7;j++){
    if (e < a.n[j]){
      float4 v = *(const float4*)(a.s[j]+e);
      u16* d = a.d[j]+e;
      d[0]=f2b(v.x); d[1]=f2b(v.y); d[2]=f2b(v.z); d[3]=f2b(v.w);
      return;
    }
    e -= a.n[j];
  }
}

// ---------------- rms over 1024 (fp32 in -> bf16 out) ----------------
__global__ __launch_bounds__(256) void k_rms1024(const float* __restrict__ src, const float* __restrict__ w,
                                                 u16* __restrict__ dst){
  int row = blockIdx.x, tid = threadIdx.x;
  const float* s = src + (size_t)row*1024;
  float v[4]; float ss=0.f;
  #pragma unroll
  for (int i=0;i<4;i++){ v[i] = s[tid + i*256]; ss += v[i]*v[i]; }
  ss = block_sum256(ss);
  float sc = rsqrtf(ss*(1.0f/1024.0f) + 1e-6f);
  u16* d = dst + (size_t)row*1024;
  #pragma unroll
  for (int i=0;i<4;i++){ int c = tid+i*256; d[c] = f2b(v[i]*sc*w[c]); }
}

// ---------------- GEMM 128x128, BK=64, 2-phase dbuf, 4 waves, 64KB LDS (2 blk/CU) ----------------
// 1D grid (nwg%8==0), XCD-bijective swizzle. C[M,N] (+)= A[M,K]*W[N,K]^T fp32 out.
#define BKq 64
__global__ __launch_bounds__(256,2) void k_gemm128(const u16* __restrict__ A, const u16* __restrict__ W,
                                                   float* __restrict__ C, int M, int N, int K,
                                                   int gx, int accum){
  __shared__ u16 lA[2][128*BKq];   // 2 x 16KB
  __shared__ u16 lB[2][128*BKq];   // 2 x 16KB
  int tid = threadIdx.x, lane = tid&63, wid = tid>>6;
  int nwg = gridDim.x;
  int cpx = nwg>>3;
  int bid = blockIdx.x;
  int swz = (bid&7)*cpx + (bid>>3);
  int bx = swz % gx, by = swz / gx;
  int bm = by*128, bn = bx*128;
  int wr = wid>>1, wc = wid&1;
  int fr = lane&15, fq = lane>>4;
  f32x4 acc[4][4];
  #pragma unroll
  for (int mi=0;mi<4;mi++)
    #pragma unroll
    for (int ni=0;ni<4;ni++)
      #pragma unroll
      for (int r=0;r<4;r++) acc[mi][ni][r]=0.f;

  int srow = lane>>3;          // 0..7
  int scol = (lane&7)*8;       // 0..56
  auto stage = [&](int buf, int t){
    int k0 = t*BKq;
    #pragma unroll
    for (int i=0;i<4;i++){
      int row = (wid*4+i)*8 + srow;          // 0..127
      int ra = bm + row; if (ra > M-1) ra = M-1;
      gload_lds16(A + (size_t)ra*K + k0 + scol, &lA[buf][(wid*4+i)*512]);
      int rb = bn + row; if (rb > N-1) rb = N-1;
      gload_lds16(W + (size_t)rb*K + k0 + scol, &lB[buf][(wid*4+i)*512]);
    }
  };

  stage(0, 0);
  __syncthreads();
  int NT = K/BKq;
  for (int t=0;t<NT;t++){
    int cur = t&1;
    if (t+1 < NT) stage(cur^1, t+1);
    #pragma unroll
    for (int kk=0;kk<2;kk++){
      short8 bf4[4], af4[4];
      #pragma unroll
      for (int ni=0;ni<4;ni++)
        bf4[ni] = *(const short8*)(&lB[cur][(wc*64 + ni*16 + fr)*BKq + kk*32 + fq*8]);
      #pragma unroll
      for (int mi=0;mi<4;mi++)
        af4[mi] = *(const short8*)(&lA[cur][(wr*64 + mi*16 + fr)*BKq + kk*32 + fq*8]);
      #pragma unroll
      for (int mi=0;mi<4;mi++)
        #pragma unroll
        for (int ni=0;ni<4;ni++)
          acc[mi][ni] = __builtin_amdgcn_mfma_f32_16x16x32_bf16(af4[mi], bf4[ni], acc[mi][ni], 0,0,0);
    }
    __syncthreads();
  }
  // epilogue
  #pragma unroll
  for (int mi=0;mi<4;mi++){
    int row0 = bm + wr*64 + mi*16 + fq*4;
    #pragma unroll
    for (int ni=0;ni<4;ni++){
      int col = bn + wc*64 + ni*16 + fr;
      if (col < N){
        #pragma unroll
        for (int r=0;r<4;r++){
          size_t idx = (size_t)(row0+r)*N + col;
          float v = acc[mi][ni][r];
          C[idx] = accum ? (C[idx] + v) : v;
        }
      }
    }
  }
}

// ---------------- depthwise causal conv (K=4) + silu ----------------
__global__ __launch_bounds__(256) void k_conv_silu(const float* __restrict__ proj, const float* __restrict__ cw,
                                                   const float* __restrict__ cb, float* __restrict__ xc){
  int idx = blockIdx.x*256 + threadIdx.x;   // over BT*DI
  int c = idx & (DIx-1);
  int bt = idx >> 11;
  int t = bt & (Tn-1);
  float acc = cb[c];
  #pragma unroll
  for (int k=0;k<4;k++){
    int tt = t - 3 + k;
    if (tt >= 0) acc += proj[(size_t)(bt-3+k)*TOTx + c] * cw[c*4+k];
  }
  xc[idx] = acc / (1.0f + expf(-acc));
}

// ---------------- dt prep ----------------
__global__ __launch_bounds__(256) void k_dtprep(const float* __restrict__ proj, const float* __restrict__ Wdt,
      const float* __restrict__ dt_bias, const float* __restrict__ A_log,
      float* __restrict__ dtA, float* __restrict__ dtB){
  int idx = blockIdx.x*256 + threadIdx.x;  // BT*H_SSM
  int h = idx & 7; int bt = idx >> 3;
  const float* dtl  = proj + (size_t)bt*TOTx + 2*DIx;
  const float* wrow = Wdt + h*64;
  float v = dt_bias[h];
  #pragma unroll 8
  for (int i=0;i<64;i++) v += dtl[i]*wrow[i];
  float sp = (v > 20.0f) ? v : log1pf(expf(v));
  float dt = fminf(fmaxf(sp, 1e-4f), 1.0f);
  const float* bm = proj + (size_t)bt*TOTx + 2*DIx + DTRx + h*16;
  #pragma unroll
  for (int n=0;n<16;n++){
    float Av = -expf(A_log[h*16+n]);
    dtA[(size_t)idx*16+n] = dt*Av;
    dtB[(size_t)idx*16+n] = dt*bm[n];
  }
}

// ---------------- scan phase 1: per-chunk local scan ----------------
__global__ __launch_bounds__(256) void k_scan1(const float* __restrict__ dtA, const float* __restrict__ dtB,
    const float* __restrict__ proj, const float* __restrict__ xc,
    float* __restrict__ expS, float* __restrict__ y, float* __restrict__ LS){
  __shared__ float sA[1024], sS[1024], sB[1024], sC[1024];
  int bx = blockIdx.x;                 // b*256 + h*32 + c
  int c = bx & 31, h = (bx>>5)&7, b = bx>>8;
  int tid = threadIdx.x;
  size_t t0 = (size_t)b*Tn + c*64;
  int j = tid>>2, n0 = (tid&3)*4;
  {
    size_t ga = (t0 + j)*128 + h*16 + n0;
    float4 va = *(const float4*)(dtA + ga);
    float4 vb = *(const float4*)(dtB + ga);
    float4 vc = *(const float4*)(proj + (t0 + j)*TOTx + (2*DIx+DTRx+H_SSM*Nst) + h*16 + n0);
    *(float4*)(&sA[j*16+n0]) = va;
    *(float4*)(&sB[j*16+n0]) = vb;
    *(float4*)(&sC[j*16+n0]) = vc;
  }
  __syncthreads();
  if (tid < 16){
    float cum = 0.f;
    for (int jj=0;jj<64;jj++){ cum += sA[jj*16+tid]; sS[jj*16+tid] = cum; }
  }
  __syncthreads();
  {
    float e[4], s4[4];
    #pragma unroll
    for (int i=0;i<4;i++){ e[i] = expf(sA[j*16+n0+i]); s4[i] = expf(sS[j*16+n0+i]); }
    #pragma unroll
    for (int i=0;i<4;i++){ sA[j*16+n0+i] = e[i]; sS[j*16+n0+i] = s4[i]; }
    float4 ev; ev.x=s4[0]; ev.y=s4[1]; ev.z=s4[2]; ev.w=s4[3];
    *(float4*)(expS + (t0+j)*128 + h*16 + n0) = ev;
  }
  __syncthreads();
  float st[16];
  #pragma unroll
  for (int n=0;n<16;n++) st[n]=0.f;
  const float* xp = xc + t0*DIx + h*Px + tid;
  float* yp = y + t0*DIx + h*Px + tid;
  for (int jj=0;jj<64;jj++){
    float x = xp[(size_t)jj*DIx];
    float acc = 0.f;
    #pragma unroll
    for (int n=0;n<16;n++){ st[n] = st[n]*sA[jj*16+n] + x*sB[jj*16+n]; acc += st[n]*sC[jj*16+n]; }
    yp[(size_t)jj*DIx] = acc;
  }
  float* ls = LS + ((((size_t)b*8+h)*NCH + c)*Px + tid)*16;
  #pragma unroll
  for (int n=0;n<16;n++) ls[n] = st[n];
}

// ---------------- scan phase 2: chunk-state scan ----------------
__global__ __launch_bounds__(256) void k_scan2(const float* __restrict__ expS, const float* __restrict__ LS,
                                               float* __restrict__ H0){
  int bh = blockIdx.x; int b = bh>>3, h = bh&7;
  int tid = threadIdx.x;
  __shared__ float dl[16];
  float Hs[16];
  #pragma unroll
  for (int n=0;n<16;n++) Hs[n]=0.f;
  for (int c=0;c<NCH;c++){
    if (tid<16) dl[tid] = expS[((size_t)b*Tn + c*64 + 63)*128 + h*16 + tid];
    __syncthreads();
    size_t base = ((((size_t)b*8+h)*NCH + c)*Px + tid)*16;
    #pragma unroll
    for (int n=0;n<16;n++){ H0[base+n] = Hs[n]; Hs[n] = Hs[n]*dl[n] + LS[base+n]; }
    __syncthreads();
  }
}

// ---------------- scan phase 3: fixup + Dskip ----------------
__global__ __launch_bounds__(256) void k_scan3(const float* __restrict__ proj, const float* __restrict__ expS,
    const float* __restrict__ H0, const float* __restrict__ xc, const float* __restrict__ Dskip,
    float* __restrict__ y){
  __shared__ float ce[1024];
  int bx = blockIdx.x; int c = bx&31, h=(bx>>5)&7, b=bx>>8;
  int tid = threadIdx.x;
  size_t t0 = (size_t)b*Tn + c*64;
  int j = tid>>2, n0=(tid&3)*4;
  {
    float4 cv = *(const float4*)(proj + (t0+j)*TOTx + (2*DIx+DTRx+H_SSM*Nst) + h*16 + n0);
    float4 evv = *(const float4*)(expS + (t0+j)*128 + h*16 + n0);
    float4 o; o.x=cv.x*evv.x; o.y=cv.y*evv.y; o.z=cv.z*evv.z; o.w=cv.w*evv.w;
    *(float4*)(&ce[j*16+n0]) = o;
  }
  __syncthreads();
  float h0[16];
  size_t base = ((((size_t)b*8+h)*NCH + c)*Px + tid)*16;
  #pragma unroll
  for (int n=0;n<16;n++) h0[n] = H0[base+n];
  float dsk = Dskip[h*Px + tid];
  const float* xp = xc + t0*DIx + h*Px + tid;
  float* yp = y + t0*DIx + h*Px + tid;
  for (int jj=0;jj<64;jj++){
    float x = xp[(size_t)jj*DIx];
    float f = 0.f;
    #pragma unroll
    for (int n=0;n<16;n++) f += ce[jj*16+n]*h0[n];
    yp[(size_t)jj*DIx] += f + dsk*x;
  }
}

// ---------------- gated rms ----------------
__global__ __launch_bounds__(256) void k_gatedrms(const float* __restrict__ y, const float* __restrict__ proj,
     const float* __restrict__ w, u16* __restrict__ yn){
  int row = blockIdx.x, tid = threadIdx.x;
  const float* yr = y + (size_t)row*DIx;
  const float* zr = proj + (size_t)row*TOTx + DIx;
  float v[8]; float ss=0.f;
  #pragma unroll
  for (int i=0;i<8;i++){
    int cidx = tid + i*256;
    float z = zr[cidx];
    float g = yr[cidx] * (z / (1.0f + expf(-z)));
    v[i]=g; ss += g*g;
  }
  ss = block_sum256(ss);
  float sc = rsqrtf(ss*(1.0f/2048.0f) + 1e-6f);
  u16* d = yn + (size_t)row*DIx;
  #pragma unroll
  for (int i=0;i<8;i++){ int cidx=tid+i*256; d[cidx] = f2b(v[i]*sc*w[cidx]); }
}

// ---------------- h = x + sout; u2 = rms(h)*w (bf16) ----------------
__global__ __launch_bounds__(256) void k_addrms(const float* __restrict__ x, const float* __restrict__ sout,
     const float* __restrict__ w, float* __restrict__ hbuf, u16* __restrict__ u2){
  int row=blockIdx.x, tid=threadIdx.x;
  float v[4]; float ss=0.f;
  #pragma unroll
  for (int i=0;i<4;i++){
    int cidx = tid + i*256;
    size_t idx = (size_t)row*1024 + cidx;
    float hv = x[idx] + sout[idx];
    hbuf[idx]=hv; v[i]=hv; ss+=hv*hv;
  }
  ss = block_sum256(ss);
  float sc = rsqrtf(ss*(1.0f/1024.0f)+1e-6f);
  #pragma unroll
  for (int i=0;i<4;i++){ int cidx=tid+i*256; u2[(size_t)row*1024+cidx] = f2b(v[i]*sc*w[cidx]); }
}

// ---------------- rope + transpose to [B,H,T,HD] (bf16), fused-QKV input ----------------
__global__ __launch_bounds__(256) void k_rope(const float* __restrict__ qkvf,
    u16* __restrict__ qr, u16* __restrict__ kr, u16* __restrict__ vr){
  int idx = blockIdx.x*256 + threadIdx.x;  // B*T*D
  int d = idx & 63;
  int h = (idx>>6) & 15;
  int t = (idx>>10) & 2047;
  int b = idx >> 21;
  int col = idx & 1023;
  size_t base = (size_t)(idx>>10)*3072;
  int dh = d & 31;
  float ang = (float)t * exp2f(-(float)dh * (13.287712379549449f/32.0f));  // t * 10000^(-dh/32)
  float cs = cosf(ang), sn = sinf(ang);
  int part = (d<32) ? 32 : -32;
  float q = qkvf[base + col],        qp = qkvf[base + col + part];
  float k = qkvf[base + 1024 + col], kp = qkvf[base + 1024 + col + part];
  float vv = qkvf[base + 2048 + col];
  float rq = (d<32)? -qp : qp;
  float rk = (d<32)? -kp : kp;
  size_t dst = (((size_t)b*H_ATTN + h)*Tn + t)*64 + d;
  qr[dst] = f2b(q*cs + rq*sn);
  kr[dst] = f2b(k*cs + rk*sn);
  vr[dst] = f2b(vv);
}

// ---------------- MFMA sliding-window attention ----------------
#define QT 64
#define KSPAN 192
__device__ __forceinline__ u32 swz128a(int row, int b){  // tile stride 128B
  return (u32)((row*128 + b) ^ ((((row&7)^((row>>3)&7)))<<4));
}
__device__ __forceinline__ u32 swz384a(int row, int b){  // tile stride 384B
  return (u32)((row*384 + b) ^ ((((row&7)^((row>>3)&7)))<<4));
}

__global__ __launch_bounds__(256) void k_attn_mfma(const u16* __restrict__ qr, const u16* __restrict__ kr,
    const u16* __restrict__ vr, u16* __restrict__ ya){
  __shared__ u16 bufK[KSPAN*64];   // 24576 B ; later P[64][192]
  __shared__ u16 bufV[64*KSPAN];   // 24576 B
  int tid = threadIdx.x, lane = tid&63, wid = tid>>6;
  int fr = lane&15, fq = lane>>4;
  int blk = blockIdx.x;            // bh*32 + qt
  int qt = blk & 31, bh = blk >> 5;
  int t0 = qt*QT;
  size_t rowbase = (size_t)bh*Tn;
  char* cK = (char*)bufK;
  char* cV = (char*)bufV;

  #pragma unroll
  for (int it=0; it<6; ++it){
    int chunk = it*256 + tid;
    int row = chunk>>3, c8 = chunk&7;
    int sg = t0 - 128 + row;
    if (sg >= 0){
      short8 v = *(const short8*)(kr + (rowbase+sg)*64 + c8*8);
      *(short8*)(cK + swz128a(row, c8*16)) = v;
    }
  }
  #pragma unroll
  for (int it=0; it<24; ++it){
    int idx = it*256 + tid;
    int s = idx>>5, dp = idx&31, d0 = dp*2;
    int sg = t0 - 128 + s;
    u16 lo = 0, hi = 0;
    if (sg >= 0){
      u32 w = *(const u32*)(vr + (rowbase+sg)*64 + d0);
      lo = (u16)(w & 0xffffu); hi = (u16)(w >> 16);
    }
    *(u16*)(cV + swz384a(d0,   s*2)) = lo;
    *(u16*)(cV + swz384a(d0+1, s*2)) = hi;
  }
  __syncthreads();

  f32x4 acc[12];
  #pragma unroll
  for (int j=0;j<12;j++)
    #pragma unroll
    for (int r=0;r<4;r++) acc[j][r]=0.f;
  #pragma unroll
  for (int kk=0;kk<2;kk++){
    short8 aq = *(const short8*)(qr + (rowbase + t0 + wid*16 + fr)*64 + kk*32 + fq*8);
    #pragma unroll
    for (int j=0;j<12;j++){
      short8 bk = *(const short8*)(cK + swz128a(j*16+fr, kk*64 + fq*16));
      acc[j] = __builtin_amdgcn_mfma_f32_16x16x32_bf16(aq, bk, acc[j], 0,0,0);
    }
  }

  float p[12][4];
  int cb = lane&15;
  #pragma unroll
  for (int r=0;r<4;r++){
    int rq = wid*16 + (lane>>4)*4 + r;
    float m = -3.0e38f;
    #pragma unroll
    for (int j=0;j<12;j++){
      int c = j*16 + cb;
      bool allowed = (c > rq) && (c <= rq+128) && (c >= 128 - t0);
      float v = allowed ? acc[j][r]*0.125f : -3.0e38f;
      p[j][r] = v;
      m = fmaxf(m, v);
    }
    #pragma unroll
    for (int o=1;o<16;o<<=1) m = fmaxf(m, __shfl_xor(m, o, 64));
    float sum = 0.f;
    #pragma unroll
    for (int j=0;j<12;j++){ float e = __expf(p[j][r]-m); p[j][r]=e; sum += e; }
    #pragma unroll
    for (int o=1;o<16;o<<=1) sum += __shfl_xor(sum, o, 64);
    float inv = 1.0f/sum;
    #pragma unroll
    for (int j=0;j<12;j++) p[j][r] *= inv;
  }
  __syncthreads();

  #pragma unroll
  for (int r=0;r<4;r++){
    int rq = wid*16 + (lane>>4)*4 + r;
    #pragma unroll
    for (int j=0;j<12;j++){
      *(u16*)(cK + swz384a(rq, (j*16+cb)*2)) = f2b(p[j][r]);
    }
  }
  __syncthreads();

  f32x4 acc2[4];
  #pragma unroll
  for (int f=0;f<4;f++)
    #pragma unroll
    for (int r=0;r<4;r++) acc2[f][r]=0.f;
  #pragma unroll
  for (int kk=0;kk<6;kk++){
    short8 ap = *(const short8*)(cK + swz384a(wid*16 + fr, kk*64 + fq*16));
    #pragma unroll
    for (int f=0;f<4;f++){
      short8 bv = *(const short8*)(cV + swz384a(f*16+fr, kk*64 + fq*16));
      acc2[f] = __builtin_amdgcn_mfma_f32_16x16x32_bf16(ap, bv, acc2[f], 0,0,0);
    }
  }
  int b = bh >> 4, h = bh & 15;
  #pragma unroll
  for (int f=0;f<4;f++){
    int d = f*16 + cb;
    #pragma unroll
    for (int r=0;r<4;r++){
      int q = t0 + wid*16 + (lane>>4)*4 + r;
      ya[((size_t)b*Tn + q)*Dm + h*64 + d] = f2b(acc2[f][r]);
    }
  }
}

// ---------------- final: out = h + att (fp32) ----------------
__global__ __launch_bounds__(256) void k_final(const float* __restrict__ hbuf, const float* __restrict__ att,
                                               float* __restrict__ out){
  int i = blockIdx.x*256 + threadIdx.x;
  out[i] = hbuf[i] + att[i];
}

// =================================================================
extern "C" void kernel_launch(void* const* d_in, const int* in_sizes, int n_in,
                              void* d_out, int out_size, void* d_ws, size_t ws_size,
                              hipStream_t stream) {
  const float* x        = (const float*)d_in[0];
  const float* norm1_w  = (const float*)d_in[1];
  const float* norm2_w  = (const float*)d_in[2];
  const float* Win      = (const float*)d_in[3];
  const float* Wdt      = (const float*)d_in[4];
  const float* conv_w   = (const float*)d_in[5];
  const float* conv_b   = (const float*)d_in[6];
  const float* A_log    = (const float*)d_in[7];
  const float* Dskip    = (const float*)d_in[8];
  const float* dt_bias  = (const float*)d_in[9];
  const float* ssd_norm = (const float*)d_in[10];
  const float* Wout_ssd = (const float*)d_in[11];
  const float* Wres     = (const float*)d_in[12];
  const float* Wq       = (const float*)d_in[13];
  const float* Wk       = (const float*)d_in[14];
  const float* Wv       = (const float*)d_in[15];
  const float* Wo       = (const float*)d_in[16];

  char* ws = (char*)d_ws;
  size_t off = 0;
  auto alloc = [&](size_t bytes){ size_t r = off; off += (bytes + 255) & ~(size_t)255; return r; };

  size_t o_WinB  = alloc((size_t)TOTx*Dm*2);
  size_t o_WresB = alloc((size_t)DIx*Dm*2);
  size_t o_WoutB = alloc((size_t)Dm*DIx*2);
  size_t o_WqB   = alloc((size_t)Dm*Dm*2);
  size_t o_WkB   = alloc((size_t)Dm*Dm*2);
  size_t o_WvB   = alloc((size_t)Dm*Dm*2);
  size_t o_WoB   = alloc((size_t)Dm*Dm*2);
  size_t o_u1    = alloc((size_t)BT*Dm*2);        // later reused as vr
  size_t o_proj  = alloc((size_t)BT*TOTx*4);      // later: qkvf (48MiB), qr/kr (bf16)
  size_t o_xc    = alloc((size_t)BT*DIx*4);       // later: sout @+0, att @+16MiB
  size_t o_dtA   = alloc((size_t)BT*H_SSM*Nst*4);
  size_t o_dtB   = alloc((size_t)BT*H_SSM*Nst*4);
  size_t o_expS  = alloc((size_t)BT*H_SSM*Nst*4);
  size_t o_LS    = alloc((size_t)Bsz*H_SSM*NCH*Px*Nst*4);
  size_t o_H0    = alloc((size_t)Bsz*H_SSM*NCH*Px*Nst*4);
  size_t o_y     = alloc((size_t)BT*DIx*4);       // later: y_att bf16 @+0
  size_t o_yn    = alloc((size_t)BT*DIx*2);
  size_t o_hb    = alloc((size_t)BT*Dm*4);

  u16* WinB  = (u16*)(ws + o_WinB);
  u16* WresB = (u16*)(ws + o_WresB);
  u16* WoutB = (u16*)(ws + o_WoutB);
  u16* WqB   = (u16*)(ws + o_WqB);
  u16* WkB   = (u16*)(ws + o_WkB);
  u16* WvB   = (u16*)(ws + o_WvB);
  u16* WoB   = (u16*)(ws + o_WoB);
  u16* u1    = (u16*)(ws + o_u1);
  float* proj = (float*)(ws + o_proj);
  float* xc   = (float*)(ws + o_xc);
  float* dtA  = (float*)(ws + o_dtA);
  float* dtB  = (float*)(ws + o_dtB);
  float* expS = (float*)(ws + o_expS);
  float* LS   = (float*)(ws + o_LS);
  float* H0   = (float*)(ws + o_H0);
  float* ybuf = (float*)(ws + o_y);
  u16*   yn   = (u16*)(ws + o_yn);
  float* hb   = (float*)(ws + o_hb);
  // aliases (lifetimes disjoint)
  float* qkvf = (float*)(ws + o_proj);            // [BT][3072] fp32 = 48MiB
  u16* qr = (u16*)(ws + o_proj + 50331648);
  u16* kr = (u16*)(ws + o_proj + 58720256);
  u16* vr = u1;
  float* sout = (float*)(ws + o_xc);
  float* att  = (float*)(ws + o_xc + 16777216);
  u16* yatt = (u16*)(ws + o_y);

  // fused weight convert
  {
    CvtArgs a;
    a.s[0]=Win;  a.d[0]=WinB;  a.n[0]=TOTx*Dm;
    a.s[1]=Wres; a.d[1]=WresB; a.n[1]=DIx*Dm;
    a.s[2]=Wout_ssd; a.d[2]=WoutB; a.n[2]=Dm*DIx;
    a.s[3]=Wq; a.d[3]=WqB; a.n[3]=Dm*Dm;
    a.s[4]=Wk; a.d[4]=WkB; a.n[4]=Dm*Dm;
    a.s[5]=Wv; a.d[5]=WvB; a.n[5]=Dm*Dm;
    a.s[6]=Wo; a.d[6]=WoB; a.n[6]=Dm*Dm;
    int total4 = (a.n[0]+a.n[1]+a.n[2]+a.n[3]+a.n[4]+a.n[5]+a.n[6])/4;
    k_cvt_all<<<dim3((total4+255)/256), dim3(256), 0, stream>>>(a, total4);
  }

  // 1) u1 = rms(x, norm1_w)
  k_rms1024<<<dim3(BT), dim3(256), 0, stream>>>(x, norm1_w, u1);
  // 2) proj = u1 @ Win^T   (gx=35 col tiles, 35*32=1120 blocks, %8==0)
  k_gemm128<<<dim3(35*32), dim3(256), 0, stream>>>(u1, WinB, proj, BT, TOTx, Dm, 35, 0);
  // 3) xc = silu(conv(xin))
  k_conv_silu<<<dim3(BT*DIx/256), dim3(256), 0, stream>>>(proj, conv_w, conv_b, xc);
  // 4) dt prep
  k_dtprep<<<dim3(BT*H_SSM/256), dim3(256), 0, stream>>>(proj, Wdt, dt_bias, A_log, dtA, dtB);
  // 5) chunked scan
  k_scan1<<<dim3(Bsz*H_SSM*NCH), dim3(256), 0, stream>>>(dtA, dtB, proj, xc, expS, ybuf, LS);
  k_scan2<<<dim3(Bsz*H_SSM), dim3(256), 0, stream>>>(expS, LS, H0);
  k_scan3<<<dim3(Bsz*H_SSM*NCH), dim3(256), 0, stream>>>(proj, expS, H0, xc, Dskip, ybuf);
  // 6) y += u1 @ Wres^T  (16*32=512 blocks)
  k_gemm128<<<dim3(16*32), dim3(256), 0, stream>>>(u1, WresB, ybuf, BT, DIx, Dm, 16, 1);
  // 7) yn = rms(y * silu(z)) * ssd_norm_w
  k_gatedrms<<<dim3(BT), dim3(256), 0, stream>>>(ybuf, proj, ssd_norm, yn);
  // 8) sout = yn @ Wout^T  (8*32=256 blocks, K=2048)
  k_gemm128<<<dim3(8*32), dim3(256), 0, stream>>>(yn, WoutB, sout, BT, Dm, DIx, 8, 0);
  // 9) h = x + sout; u2 = rms(h)*norm2_w
  k_addrms<<<dim3(BT), dim3(256), 0, stream>>>(x, sout, norm2_w, hb, (u16*)(ws + o_yn));
  u16* u2p = (u16*)(ws + o_yn);
  // 10) fused QKV projection: qkvf = u2 @ [Wq;Wk;Wv]^T  (24*32=768 blocks)
  k_gemm128<<<dim3(24*32), dim3(256), 0, stream>>>(u2p, WqB, qkvf, BT, 3*Dm, Dm, 24, 0);
  // 11) rope + transpose
  k_rope<<<dim3(BT*Dm/256), dim3(256), 0, stream>>>(qkvf, qr, kr, vr);
  // 12) attention (MFMA sliding-window)
  k_attn_mfma<<<dim3(Bsz*H_ATTN*(Tn/QT)), dim3(256), 0, stream>>>(qr, kr, vr, yatt);
  // 13) att = yatt @ Wo^T  (8*32=256 blocks)
  k_gemm128<<<dim3(8*32), dim3(256), 0, stream>>>(yatt, WoB, att, BT, Dm, Dm, 8, 0);
  // 14) out = h + att
  k_final<<<dim3(BT*Dm/256), dim3(256), 0, stream>>>(hb, att, (float*)d_out);
  (void)in_sizes; (void)n_in; (void)out_size; (void)ws_size;
}

// Round 5
// 433.384 us; speedup vs baseline: 2.1383x; 1.1178x over previous
//
#include <hip/hip_runtime.h>
#include <stdint.h>

typedef unsigned short u16;
typedef unsigned int u32;
typedef __attribute__((ext_vector_type(8))) short short8;
typedef __attribute__((ext_vector_type(4))) float f32x4;

// ---------------- problem constants ----------------
#define Bsz 2
#define Tn 2048
#define Dm 1024
#define H_ATTN 16
#define HDx 64
#define WINx 128
#define H_SSM 8
#define DIx 2048
#define Nst 16
#define DTRx 64
#define Px 256          // DI / H_SSM
#define TOTx 4416       // 2*DI + DTR + 2*H*N
#define BT (Bsz*Tn)     // 4096
#define NCH 32          // chunks
#define LCH 64          // chunk length

// ---------------- helpers ----------------
__device__ __forceinline__ float b2f(u16 u){ u32 x = ((u32)u)<<16; float f; __builtin_memcpy(&f,&x,4); return f; }
__device__ __forceinline__ u16 f2b(float f){ u32 x; __builtin_memcpy(&x,&f,4); u32 r = x + 0x7fffu + ((x>>16)&1u); return (u16)(r>>16); }

__device__ __forceinline__ float block_sum256(float v){
  #pragma unroll
  for (int o=32;o;o>>=1) v += __shfl_xor(v,o,64);
  __shared__ float sb[4];
  int wid = threadIdx.x>>6;
  if ((threadIdx.x&63)==0) sb[wid]=v;
  __syncthreads();
  v = sb[0]+sb[1]+sb[2]+sb[3];
  __syncthreads();
  return v;
}

__device__ __forceinline__ void gload_lds16(const void* g, void* l){
  __builtin_amdgcn_global_load_lds((const __attribute__((address_space(1))) void*)g,
                                   (__attribute__((address_space(3))) void*)l, 16, 0, 0);
}

// ---------------- fused fp32 -> bf16 convert (all 7 weights, 1 launch) ----------------
struct CvtArgs { const float* s[7]; u16* d[7]; int n[7]; };
__global__ __launch_bounds__(256) void k_cvt_all(CvtArgs a, int total4){
  int i = blockIdx.x*256 + threadIdx.x;   // in float4 units
  if (i >= total4) return;
  int e = i*4;
  #pragma unroll
  for (int j=0;j<7;j++){
    if (e < a.n[j]){
      float4 v = *(const float4*)(a.s[j]+e);
      u16* d = a.d[j]+e;
      d[0]=f2b(v.x); d[1]=f2b(v.y); d[2]=f2b(v.z); d[3]=f2b(v.w);
      return;
    }
    e -= a.n[j];
  }
}

// ---------------- rms over 1024 (fp32 in -> bf16 out) ----------------
__global__ __launch_bounds__(256) void k_rms1024(const float* __restrict__ src, const float* __restrict__ w,
                                                 u16* __restrict__ dst){
  int row = blockIdx.x, tid = threadIdx.x;
  const float* s = src + (size_t)row*1024;
  float v[4]; float ss=0.f;
  #pragma unroll
  for (int i=0;i<4;i++){ v[i] = s[tid + i*256]; ss += v[i]*v[i]; }
  ss = block_sum256(ss);
  float sc = rsqrtf(ss*(1.0f/1024.0f) + 1e-6f);
  u16* d = dst + (size_t)row*1024;
  #pragma unroll
  for (int i=0;i<4;i++){ int c = tid+i*256; d[c] = f2b(v[i]*sc*w[c]); }
}

// ---------------- GEMM 128x128, BK=64, counted-vmcnt pipeline (depth 2), swizzled LDS ----
// LDS layout: lX[buf][row][slot] where slot holds global 16B-chunk (slot ^ (row&7)).
// Staged via gload_lds with pre-swizzled GLOBAL source (linear LDS dest, rule #21);
// read with the same XOR on the slot index -> conflict-free ds_read_b128.
// Sync: raw s_barrier + s_waitcnt vmcnt(8) (stage of tile issued 2 iters ago), never 0 in-loop.
#define BKq 64
__global__ __launch_bounds__(256,2) void k_gemm128p(const u16* __restrict__ A, const u16* __restrict__ W,
                                                    float* __restrict__ C, int M, int N, int K,
                                                    int gx, int accum){
  __shared__ u16 lA[2][128*BKq];   // 2 x 16KB
  __shared__ u16 lB[2][128*BKq];   // 2 x 16KB
  int tid = threadIdx.x, lane = tid&63, wid = tid>>6;
  int nwg = gridDim.x;
  int cpx = nwg>>3;
  int bid = blockIdx.x;
  int swz = (bid&7)*cpx + (bid>>3);
  int bx = swz % gx, by = swz / gx;
  int bm = by*128, bn = bx*128;
  int wr = wid>>1, wc = wid&1;
  int fr = lane&15, fq = lane>>4;
  int s7 = fr&7;
  f32x4 acc[4][4];
  #pragma unroll
  for (int mi=0;mi<4;mi++)
    #pragma unroll
    for (int ni=0;ni<4;ni++)
      #pragma unroll
      for (int r=0;r<4;r++) acc[mi][ni][r]=0.f;

  int srow = lane>>3;                    // 0..7 (local row within 8-row chunk)
  int scol = (((lane&7) ^ srow))*8;      // swizzled 16B-slot -> element offset
  auto stage = [&](int buf, int t){
    int k0 = t*BKq;
    #pragma unroll
    for (int i=0;i<4;i++){
      int row = (wid*4+i)*8 + srow;      // 0..127
      int ra = bm + row; if (ra > M-1) ra = M-1;
      gload_lds16(A + (size_t)ra*K + k0 + scol, &lA[buf][(wid*4+i)*512]);
      int rb = bn + row; if (rb > N-1) rb = N-1;
      gload_lds16(W + (size_t)rb*K + k0 + scol, &lB[buf][(wid*4+i)*512]);
    }
  };

  int NT = K/BKq;                        // >= 16 for all our shapes
  stage(0, 0);
  stage(1, 1);
  for (int t=0;t<NT;t++){
    int cur = t&1;
    // wait for stage(t) (issued 2 iters ago); stage(t+1)'s 8 loads may stay in flight
    if (t+1 < NT) asm volatile("s_waitcnt vmcnt(8)" ::: "memory");
    else          asm volatile("s_waitcnt vmcnt(0)" ::: "memory");
    __builtin_amdgcn_sched_barrier(0);
    __builtin_amdgcn_s_barrier();        // all waves' stage(t) landed
    #pragma unroll
    for (int kk=0;kk<2;kk++){
      short8 bf4[4], af4[4];
      int slotb = ((kk*4 + fq) ^ s7)*8;  // swizzled element offset within row
      #pragma unroll
      for (int ni=0;ni<4;ni++)
        bf4[ni] = *(const short8*)(&lB[cur][(wc*64 + ni*16 + fr)*BKq + slotb]);
      #pragma unroll
      for (int mi=0;mi<4;mi++)
        af4[mi] = *(const short8*)(&lA[cur][(wr*64 + mi*16 + fr)*BKq + slotb]);
      #pragma unroll
      for (int mi=0;mi<4;mi++)
        #pragma unroll
        for (int ni=0;ni<4;ni++)
          acc[mi][ni] = __builtin_amdgcn_mfma_f32_16x16x32_bf16(af4[mi], bf4[ni], acc[mi][ni], 0,0,0);
    }
    // release buf cur for overwrite: my ds_reads done + rendezvous
    asm volatile("s_waitcnt lgkmcnt(0)" ::: "memory");
    __builtin_amdgcn_sched_barrier(0);
    __builtin_amdgcn_s_barrier();
    if (t+2 < NT) stage(cur, t+2);
  }
  // epilogue
  #pragma unroll
  for (int mi=0;mi<4;mi++){
    int row0 = bm + wr*64 + mi*16 + fq*4;
    #pragma unroll
    for (int ni=0;ni<4;ni++){
      int col = bn + wc*64 + ni*16 + fr;
      if (col < N){
        #pragma unroll
        for (int r=0;r<4;r++){
          size_t idx = (size_t)(row0+r)*N + col;
          float v = acc[mi][ni][r];
          C[idx] = accum ? (C[idx] + v) : v;
        }
      }
    }
  }
}

// ---------------- depthwise causal conv (K=4) + silu ----------------
__global__ __launch_bounds__(256) void k_conv_silu(const float* __restrict__ proj, const float* __restrict__ cw,
                                                   const float* __restrict__ cb, float* __restrict__ xc){
  int idx = blockIdx.x*256 + threadIdx.x;   // over BT*DI
  int c = idx & (DIx-1);
  int bt = idx >> 11;
  int t = bt & (Tn-1);
  float acc = cb[c];
  #pragma unroll
  for (int k=0;k<4;k++){
    int tt = t - 3 + k;
    if (tt >= 0) acc += proj[(size_t)(bt-3+k)*TOTx + c] * cw[c*4+k];
  }
  xc[idx] = acc / (1.0f + expf(-acc));
}

// ---------------- dt prep ----------------
__global__ __launch_bounds__(256) void k_dtprep(const float* __restrict__ proj, const float* __restrict__ Wdt,
      const float* __restrict__ dt_bias, const float* __restrict__ A_log,
      float* __restrict__ dtA, float* __restrict__ dtB){
  int idx = blockIdx.x*256 + threadIdx.x;  // BT*H_SSM
  int h = idx & 7; int bt = idx >> 3;
  const float* dtl  = proj + (size_t)bt*TOTx + 2*DIx;
  const float* wrow = Wdt + h*64;
  float v = dt_bias[h];
  #pragma unroll 8
  for (int i=0;i<64;i++) v += dtl[i]*wrow[i];
  float sp = (v > 20.0f) ? v : log1pf(expf(v));
  float dt = fminf(fmaxf(sp, 1e-4f), 1.0f);
  const float* bm = proj + (size_t)bt*TOTx + 2*DIx + DTRx + h*16;
  #pragma unroll
  for (int n=0;n<16;n++){
    float Av = -expf(A_log[h*16+n]);
    dtA[(size_t)idx*16+n] = dt*Av;
    dtB[(size_t)idx*16+n] = dt*bm[n];
  }
}

// ---------------- scan phase 1: per-chunk local scan ----------------
__global__ __launch_bounds__(256) void k_scan1(const float* __restrict__ dtA, const float* __restrict__ dtB,
    const float* __restrict__ proj, const float* __restrict__ xc,
    float* __restrict__ expS, float* __restrict__ y, float* __restrict__ LS){
  __shared__ float sA[1024], sS[1024], sB[1024], sC[1024];
  int bx = blockIdx.x;                 // b*256 + h*32 + c
  int c = bx & 31, h = (bx>>5)&7, b = bx>>8;
  int tid = threadIdx.x;
  size_t t0 = (size_t)b*Tn + c*64;
  int j = tid>>2, n0 = (tid&3)*4;
  {
    size_t ga = (t0 + j)*128 + h*16 + n0;
    float4 va = *(const float4*)(dtA + ga);
    float4 vb = *(const float4*)(dtB + ga);
    float4 vc = *(const float4*)(proj + (t0 + j)*TOTx + (2*DIx+DTRx+H_SSM*Nst) + h*16 + n0);
    *(float4*)(&sA[j*16+n0]) = va;
    *(float4*)(&sB[j*16+n0]) = vb;
    *(float4*)(&sC[j*16+n0]) = vc;
  }
  __syncthreads();
  if (tid < 16){
    float cum = 0.f;
    for (int jj=0;jj<64;jj++){ cum += sA[jj*16+tid]; sS[jj*16+tid] = cum; }
  }
  __syncthreads();
  {
    float e[4], s4[4];
    #pragma unroll
    for (int i=0;i<4;i++){ e[i] = expf(sA[j*16+n0+i]); s4[i] = expf(sS[j*16+n0+i]); }
    #pragma unroll
    for (int i=0;i<4;i++){ sA[j*16+n0+i] = e[i]; sS[j*16+n0+i] = s4[i]; }
    float4 ev; ev.x=s4[0]; ev.y=s4[1]; ev.z=s4[2]; ev.w=s4[3];
    *(float4*)(expS + (t0+j)*128 + h*16 + n0) = ev;
  }
  __syncthreads();
  float st[16];
  #pragma unroll
  for (int n=0;n<16;n++) st[n]=0.f;
  const float* xp = xc + t0*DIx + h*Px + tid;
  float* yp = y + t0*DIx + h*Px + tid;
  for (int jj=0;jj<64;jj++){
    float x = xp[(size_t)jj*DIx];
    float acc = 0.f;
    #pragma unroll
    for (int n=0;n<16;n++){ st[n] = st[n]*sA[jj*16+n] + x*sB[jj*16+n]; acc += st[n]*sC[jj*16+n]; }
    yp[(size_t)jj*DIx] = acc;
  }
  float* ls = LS + ((((size_t)b*8+h)*NCH + c)*Px + tid)*16;
  #pragma unroll
  for (int n=0;n<16;n++) ls[n] = st[n];
}

// ---------------- scan phase 2: chunk-state scan ----------------
__global__ __launch_bounds__(256) void k_scan2(const float* __restrict__ expS, const float* __restrict__ LS,
                                               float* __restrict__ H0){
  int bh = blockIdx.x; int b = bh>>3, h = bh&7;
  int tid = threadIdx.x;
  __shared__ float dl[16];
  float Hs[16];
  #pragma unroll
  for (int n=0;n<16;n++) Hs[n]=0.f;
  for (int c=0;c<NCH;c++){
    if (tid<16) dl[tid] = expS[((size_t)b*Tn + c*64 + 63)*128 + h*16 + tid];
    __syncthreads();
    size_t base = ((((size_t)b*8+h)*NCH + c)*Px + tid)*16;
    #pragma unroll
    for (int n=0;n<16;n++){ H0[base+n] = Hs[n]; Hs[n] = Hs[n]*dl[n] + LS[base+n]; }
    __syncthreads();
  }
}

// ---------------- scan phase 3: fixup + Dskip ----------------
__global__ __launch_bounds__(256) void k_scan3(const float* __restrict__ proj, const float* __restrict__ expS,
    const float* __restrict__ H0, const float* __restrict__ xc, const float* __restrict__ Dskip,
    float* __restrict__ y){
  __shared__ float ce[1024];
  int bx = blockIdx.x; int c = bx&31, h=(bx>>5)&7, b=bx>>8;
  int tid = threadIdx.x;
  size_t t0 = (size_t)b*Tn + c*64;
  int j = tid>>2, n0=(tid&3)*4;
  {
    float4 cv = *(const float4*)(proj + (t0+j)*TOTx + (2*DIx+DTRx+H_SSM*Nst) + h*16 + n0);
    float4 evv = *(const float4*)(expS + (t0+j)*128 + h*16 + n0);
    float4 o; o.x=cv.x*evv.x; o.y=cv.y*evv.y; o.z=cv.z*evv.z; o.w=cv.w*evv.w;
    *(float4*)(&ce[j*16+n0]) = o;
  }
  __syncthreads();
  float h0[16];
  size_t base = ((((size_t)b*8+h)*NCH + c)*Px + tid)*16;
  #pragma unroll
  for (int n=0;n<16;n++) h0[n] = H0[base+n];
  float dsk = Dskip[h*Px + tid];
  const float* xp = xc + t0*DIx + h*Px + tid;
  float* yp = y + t0*DIx + h*Px + tid;
  for (int jj=0;jj<64;jj++){
    float x = xp[(size_t)jj*DIx];
    float f = 0.f;
    #pragma unroll
    for (int n=0;n<16;n++) f += ce[jj*16+n]*h0[n];
    yp[(size_t)jj*DIx] += f + dsk*x;
  }
}

// ---------------- gated rms ----------------
__global__ __launch_bounds__(256) void k_gatedrms(const float* __restrict__ y, const float* __restrict__ proj,
     const float* __restrict__ w, u16* __restrict__ yn){
  int row = blockIdx.x, tid = threadIdx.x;
  const float* yr = y + (size_t)row*DIx;
  const float* zr = proj + (size_t)row*TOTx + DIx;
  float v[8]; float ss=0.f;
  #pragma unroll
  for (int i=0;i<8;i++){
    int cidx = tid + i*256;
    float z = zr[cidx];
    float g = yr[cidx] * (z / (1.0f + expf(-z)));
    v[i]=g; ss += g*g;
  }
  ss = block_sum256(ss);
  float sc = rsqrtf(ss*(1.0f/2048.0f) + 1e-6f);
  u16* d = yn + (size_t)row*DIx;
  #pragma unroll
  for (int i=0;i<8;i++){ int cidx=tid+i*256; d[cidx] = f2b(v[i]*sc*w[cidx]); }
}

// ---------------- h = x + sout; u2 = rms(h)*w (bf16) ----------------
__global__ __launch_bounds__(256) void k_addrms(const float* __restrict__ x, const float* __restrict__ sout,
     const float* __restrict__ w, float* __restrict__ hbuf, u16* __restrict__ u2){
  int row=blockIdx.x, tid=threadIdx.x;
  float v[4]; float ss=0.f;
  #pragma unroll
  for (int i=0;i<4;i++){
    int cidx = tid + i*256;
    size_t idx = (size_t)row*1024 + cidx;
    float hv = x[idx] + sout[idx];
    hbuf[idx]=hv; v[i]=hv; ss+=hv*hv;
  }
  ss = block_sum256(ss);
  float sc = rsqrtf(ss*(1.0f/1024.0f)+1e-6f);
  #pragma unroll
  for (int i=0;i<4;i++){ int cidx=tid+i*256; u2[(size_t)row*1024+cidx] = f2b(v[i]*sc*w[cidx]); }
}

// ---------------- rope + transpose to [B,H,T,HD] (bf16), fused-QKV input ----------------
__global__ __launch_bounds__(256) void k_rope(const float* __restrict__ qkvf,
    u16* __restrict__ qr, u16* __restrict__ kr, u16* __restrict__ vr){
  int idx = blockIdx.x*256 + threadIdx.x;  // B*T*D
  int d = idx & 63;
  int h = (idx>>6) & 15;
  int t = (idx>>10) & 2047;
  int b = idx >> 21;
  int col = idx & 1023;
  size_t base = (size_t)(idx>>10)*3072;
  int dh = d & 31;
  float ang = (float)t * exp2f(-(float)dh * (13.287712379549449f/32.0f));  // t * 10000^(-dh/32)
  float cs = cosf(ang), sn = sinf(ang);
  int part = (d<32) ? 32 : -32;
  float q = qkvf[base + col],        qp = qkvf[base + col + part];
  float k = qkvf[base + 1024 + col], kp = qkvf[base + 1024 + col + part];
  float vv = qkvf[base + 2048 + col];
  float rq = (d<32)? -qp : qp;
  float rk = (d<32)? -kp : kp;
  size_t dst = (((size_t)b*H_ATTN + h)*Tn + t)*64 + d;
  qr[dst] = f2b(q*cs + rq*sn);
  kr[dst] = f2b(k*cs + rk*sn);
  vr[dst] = f2b(vv);
}

// ---------------- MFMA sliding-window attention ----------------
#define QT 64
#define KSPAN 192
__device__ __forceinline__ u32 swz128a(int row, int b){  // tile stride 128B
  return (u32)((row*128 + b) ^ ((((row&7)^((row>>3)&7)))<<4));
}
__device__ __forceinline__ u32 swz384a(int row, int b){  // tile stride 384B
  return (u32)((row*384 + b) ^ ((((row&7)^((row>>3)&7)))<<4));
}

__global__ __launch_bounds__(256) void k_attn_mfma(const u16* __restrict__ qr, const u16* __restrict__ kr,
    const u16* __restrict__ vr, u16* __restrict__ ya){
  __shared__ u16 bufK[KSPAN*64];   // 24576 B ; later P[64][192]
  __shared__ u16 bufV[64*KSPAN];   // 24576 B
  int tid = threadIdx.x, lane = tid&63, wid = tid>>6;
  int fr = lane&15, fq = lane>>4;
  int blk = blockIdx.x;            // bh*32 + qt
  int qt = blk & 31, bh = blk >> 5;
  int t0 = qt*QT;
  size_t rowbase = (size_t)bh*Tn;
  char* cK = (char*)bufK;
  char* cV = (char*)bufV;

  #pragma unroll
  for (int it=0; it<6; ++it){
    int chunk = it*256 + tid;
    int row = chunk>>3, c8 = chunk&7;
    int sg = t0 - 128 + row;
    if (sg >= 0){
      short8 v = *(const short8*)(kr + (rowbase+sg)*64 + c8*8);
      *(short8*)(cK + swz128a(row, c8*16)) = v;
    }
  }
  #pragma unroll
  for (int it=0; it<24; ++it){
    int idx = it*256 + tid;
    int s = idx>>5, dp = idx&31, d0 = dp*2;
    int sg = t0 - 128 + s;
    u16 lo = 0, hi = 0;
    if (sg >= 0){
      u32 w = *(const u32*)(vr + (rowbase+sg)*64 + d0);
      lo = (u16)(w & 0xffffu); hi = (u16)(w >> 16);
    }
    *(u16*)(cV + swz384a(d0,   s*2)) = lo;
    *(u16*)(cV + swz384a(d0+1, s*2)) = hi;
  }
  __syncthreads();

  f32x4 acc[12];
  #pragma unroll
  for (int j=0;j<12;j++)
    #pragma unroll
    for (int r=0;r<4;r++) acc[j][r]=0.f;
  #pragma unroll
  for (int kk=0;kk<2;kk++){
    short8 aq = *(const short8*)(qr + (rowbase + t0 + wid*16 + fr)*64 + kk*32 + fq*8);
    #pragma unroll
    for (int j=0;j<12;j++){
      short8 bk = *(const short8*)(cK + swz128a(j*16+fr, kk*64 + fq*16));
      acc[j] = __builtin_amdgcn_mfma_f32_16x16x32_bf16(aq, bk, acc[j], 0,0,0);
    }
  }

  float p[12][4];
  int cb = lane&15;
  #pragma unroll
  for (int r=0;r<4;r++){
    int rq = wid*16 + (lane>>4)*4 + r;
    float m = -3.0e38f;
    #pragma unroll
    for (int j=0;j<12;j++){
      int c = j*16 + cb;
      bool allowed = (c > rq) && (c <= rq+128) && (c >= 128 - t0);
      float v = allowed ? acc[j][r]*0.125f : -3.0e38f;
      p[j][r] = v;
      m = fmaxf(m, v);
    }
    #pragma unroll
    for (int o=1;o<16;o<<=1) m = fmaxf(m, __shfl_xor(m, o, 64));
    float sum = 0.f;
    #pragma unroll
    for (int j=0;j<12;j++){ float e = __expf(p[j][r]-m); p[j][r]=e; sum += e; }
    #pragma unroll
    for (int o=1;o<16;o<<=1) sum += __shfl_xor(sum, o, 64);
    float inv = 1.0f/sum;
    #pragma unroll
    for (int j=0;j<12;j++) p[j][r] *= inv;
  }
  __syncthreads();

  #pragma unroll
  for (int r=0;r<4;r++){
    int rq = wid*16 + (lane>>4)*4 + r;
    #pragma unroll
    for (int j=0;j<12;j++){
      *(u16*)(cK + swz384a(rq, (j*16+cb)*2)) = f2b(p[j][r]);
    }
  }
  __syncthreads();

  f32x4 acc2[4];
  #pragma unroll
  for (int f=0;f<4;f++)
    #pragma unroll
    for (int r=0;r<4;r++) acc2[f][r]=0.f;
  #pragma unroll
  for (int kk=0;kk<6;kk++){
    short8 ap = *(const short8*)(cK + swz384a(wid*16 + fr, kk*64 + fq*16));
    #pragma unroll
    for (int f=0;f<4;f++){
      short8 bv = *(const short8*)(cV + swz384a(f*16+fr, kk*64 + fq*16));
      acc2[f] = __builtin_amdgcn_mfma_f32_16x16x32_bf16(ap, bv, acc2[f], 0,0,0);
    }
  }
  int b = bh >> 4, h = bh & 15;
  #pragma unroll
  for (int f=0;f<4;f++){
    int d = f*16 + cb;
    #pragma unroll
    for (int r=0;r<4;r++){
      int q = t0 + wid*16 + (lane>>4)*4 + r;
      ya[((size_t)b*Tn + q)*Dm + h*64 + d] = f2b(acc2[f][r]);
    }
  }
}

// ---------------- final: out = h + att (fp32) ----------------
__global__ __launch_bounds__(256) void k_final(const float* __restrict__ hbuf, const float* __restrict__ att,
                                               float* __restrict__ out){
  int i = blockIdx.x*256 + threadIdx.x;
  out[i] = hbuf[i] + att[i];
}

// =================================================================
extern "C" void kernel_launch(void* const* d_in, const int* in_sizes, int n_in,
                              void* d_out, int out_size, void* d_ws, size_t ws_size,
                              hipStream_t stream) {
  const float* x        = (const float*)d_in[0];
  const float* norm1_w  = (const float*)d_in[1];
  const float* norm2_w  = (const float*)d_in[2];
  const float* Win      = (const float*)d_in[3];
  const float* Wdt      = (const float*)d_in[4];
  const float* conv_w   = (const float*)d_in[5];
  const float* conv_b   = (const float*)d_in[6];
  const float* A_log    = (const float*)d_in[7];
  const float* Dskip    = (const float*)d_in[8];
  const float* dt_bias  = (const float*)d_in[9];
  const float* ssd_norm = (const float*)d_in[10];
  const float* Wout_ssd = (const float*)d_in[11];
  const float* Wres     = (const float*)d_in[12];
  const float* Wq       = (const float*)d_in[13];
  const float* Wk       = (const float*)d_in[14];
  const float* Wv       = (const float*)d_in[15];
  const float* Wo       = (const float*)d_in[16];

  char* ws = (char*)d_ws;
  size_t off = 0;
  auto alloc = [&](size_t bytes){ size_t r = off; off += (bytes + 255) & ~(size_t)255; return r; };

  size_t o_WinB  = alloc((size_t)TOTx*Dm*2);
  size_t o_WresB = alloc((size_t)DIx*Dm*2);
  size_t o_WoutB = alloc((size_t)Dm*DIx*2);
  size_t o_WqB   = alloc((size_t)Dm*Dm*2);
  size_t o_WkB   = alloc((size_t)Dm*Dm*2);
  size_t o_WvB   = alloc((size_t)Dm*Dm*2);
  size_t o_WoB   = alloc((size_t)Dm*Dm*2);
  size_t o_u1    = alloc((size_t)BT*Dm*2);        // later reused as vr
  size_t o_proj  = alloc((size_t)BT*TOTx*4);      // later: qkvf (48MiB), qr/kr (bf16)
  size_t o_xc    = alloc((size_t)BT*DIx*4);       // later: sout @+0, att @+16MiB
  size_t o_dtA   = alloc((size_t)BT*H_SSM*Nst*4);
  size_t o_dtB   = alloc((size_t)BT*H_SSM*Nst*4);
  size_t o_expS  = alloc((size_t)BT*H_SSM*Nst*4);
  size_t o_LS    = alloc((size_t)Bsz*H_SSM*NCH*Px*Nst*4);
  size_t o_H0    = alloc((size_t)Bsz*H_SSM*NCH*Px*Nst*4);
  size_t o_y     = alloc((size_t)BT*DIx*4);       // later: y_att bf16 @+0
  size_t o_yn    = alloc((size_t)BT*DIx*2);
  size_t o_hb    = alloc((size_t)BT*Dm*4);

  u16* WinB  = (u16*)(ws + o_WinB);
  u16* WresB = (u16*)(ws + o_WresB);
  u16* WoutB = (u16*)(ws + o_WoutB);
  u16* WqB   = (u16*)(ws + o_WqB);
  u16* WkB   = (u16*)(ws + o_WkB);
  u16* WvB   = (u16*)(ws + o_WvB);
  u16* WoB   = (u16*)(ws + o_WoB);
  u16* u1    = (u16*)(ws + o_u1);
  float* proj = (float*)(ws + o_proj);
  float* xc   = (float*)(ws + o_xc);
  float* dtA  = (float*)(ws + o_dtA);
  float* dtB  = (float*)(ws + o_dtB);
  float* expS = (float*)(ws + o_expS);
  float* LS   = (float*)(ws + o_LS);
  float* H0   = (float*)(ws + o_H0);
  float* ybuf = (float*)(ws + o_y);
  u16*   yn   = (u16*)(ws + o_yn);
  float* hb   = (float*)(ws + o_hb);
  // aliases (lifetimes disjoint)
  float* qkvf = (float*)(ws + o_proj);            // [BT][3072] fp32 = 48MiB
  u16* qr = (u16*)(ws + o_proj + 50331648);
  u16* kr = (u16*)(ws + o_proj + 58720256);
  u16* vr = u1;
  float* sout = (float*)(ws + o_xc);
  float* att  = (float*)(ws + o_xc + 16777216);
  u16* yatt = (u16*)(ws + o_y);

  // fused weight convert
  {
    CvtArgs a;
    a.s[0]=Win;  a.d[0]=WinB;  a.n[0]=TOTx*Dm;
    a.s[1]=Wres; a.d[1]=WresB; a.n[1]=DIx*Dm;
    a.s[2]=Wout_ssd; a.d[2]=WoutB; a.n[2]=Dm*DIx;
    a.s[3]=Wq; a.d[3]=WqB; a.n[3]=Dm*Dm;
    a.s[4]=Wk; a.d[4]=WkB; a.n[4]=Dm*Dm;
    a.s[5]=Wv; a.d[5]=WvB; a.n[5]=Dm*Dm;
    a.s[6]=Wo; a.d[6]=WoB; a.n[6]=Dm*Dm;
    int total4 = (a.n[0]+a.n[1]+a.n[2]+a.n[3]+a.n[4]+a.n[5]+a.n[6])/4;
    k_cvt_all<<<dim3((total4+255)/256), dim3(256), 0, stream>>>(a, total4);
  }

  // 1) u1 = rms(x, norm1_w)
  k_rms1024<<<dim3(BT), dim3(256), 0, stream>>>(x, norm1_w, u1);
  // 2) proj = u1 @ Win^T   (gx=35 col tiles, 35*32=1120 blocks, %8==0)
  k_gemm128p<<<dim3(35*32), dim3(256), 0, stream>>>(u1, WinB, proj, BT, TOTx, Dm, 35, 0);
  // 3) xc = silu(conv(xin))
  k_conv_silu<<<dim3(BT*DIx/256), dim3(256), 0, stream>>>(proj, conv_w, conv_b, xc);
  // 4) dt prep
  k_dtprep<<<dim3(BT*H_SSM/256), dim3(256), 0, stream>>>(proj, Wdt, dt_bias, A_log, dtA, dtB);
  // 5) chunked scan
  k_scan1<<<dim3(Bsz*H_SSM*NCH), dim3(256), 0, stream>>>(dtA, dtB, proj, xc, expS, ybuf, LS);
  k_scan2<<<dim3(Bsz*H_SSM), dim3(256), 0, stream>>>(expS, LS, H0);
  k_scan3<<<dim3(Bsz*H_SSM*NCH), dim3(256), 0, stream>>>(proj, expS, H0, xc, Dskip, ybuf);
  // 6) y += u1 @ Wres^T  (16*32=512 blocks)
  k_gemm128p<<<dim3(16*32), dim3(256), 0, stream>>>(u1, WresB, ybuf, BT, DIx, Dm, 16, 1);
  // 7) yn = rms(y * silu(z)) * ssd_norm_w
  k_gatedrms<<<dim3(BT), dim3(256), 0, stream>>>(ybuf, proj, ssd_norm, yn);
  // 8) sout = yn @ Wout^T  (8*32=256 blocks, K=2048)
  k_gemm128p<<<dim3(8*32), dim3(256), 0, stream>>>(yn, WoutB, sout, BT, Dm, DIx, 8, 0);
  // 9) h = x + sout; u2 = rms(h)*norm2_w
  k_addrms<<<dim3(BT), dim3(256), 0, stream>>>(x, sout, norm2_w, hb, (u16*)(ws + o_yn));
  u16* u2p = (u16*)(ws + o_yn);
  // 10) fused QKV projection: qkvf = u2 @ [Wq;Wk;Wv]^T  (24*32=768 blocks)
  k_gemm128p<<<dim3(24*32), dim3(256), 0, stream>>>(u2p, WqB, qkvf, BT, 3*Dm, Dm, 24, 0);
  // 11) rope + transpose
  k_rope<<<dim3(BT*Dm/256), dim3(256), 0, stream>>>(qkvf, qr, kr, vr);
  // 12) attention (MFMA sliding-window)
  k_attn_mfma<<<dim3(Bsz*H_ATTN*(Tn/QT)), dim3(256), 0, stream>>>(qr, kr, vr, yatt);
  // 13) att = yatt @ Wo^T  (8*32=256 blocks)
  k_gemm128p<<<dim3(8*32), dim3(256), 0, stream>>>(yatt, WoB, att, BT, Dm, Dm, 8, 0);
  // 14) out = h + att
  k_final<<<dim3(BT*Dm/256), dim3(256), 0, stream>>>(hb, att, (float*)d_out);
  (void)in_sizes; (void)n_in; (void)out_size; (void)ws_size;
}

// Round 6
// 428.258 us; speedup vs baseline: 2.1639x; 1.0120x over previous
//
#include <hip/hip_runtime.h>
#include <stdint.h>

typedef unsigned short u16;
typedef unsigned int u32;
typedef __attribute__((ext_vector_type(8))) short short8;
typedef __attribute__((ext_vector_type(4))) float f32x4;

// ---------------- problem constants ----------------
#define Bsz 2
#define Tn 2048
#define Dm 1024
#define H_ATTN 16
#define HDx 64
#define WINx 128
#define H_SSM 8
#define DIx 2048
#define Nst 16
#define DTRx 64
#define Px 256          // DI / H_SSM
#define TOTx 4416       // 2*DI + DTR + 2*H*N
#define BT (Bsz*Tn)     // 4096
#define NCH 32          // chunks
#define LCH 64          // chunk length

// ---------------- helpers ----------------
__device__ __forceinline__ float b2f(u16 u){ u32 x = ((u32)u)<<16; float f; __builtin_memcpy(&f,&x,4); return f; }
__device__ __forceinline__ u16 f2b(float f){ u32 x; __builtin_memcpy(&x,&f,4); u32 r = x + 0x7fffu + ((x>>16)&1u); return (u16)(r>>16); }

__device__ __forceinline__ float block_sum256(float v){
  #pragma unroll
  for (int o=32;o;o>>=1) v += __shfl_xor(v,o,64);
  __shared__ float sb[4];
  int wid = threadIdx.x>>6;
  if ((threadIdx.x&63)==0) sb[wid]=v;
  __syncthreads();
  v = sb[0]+sb[1]+sb[2]+sb[3];
  __syncthreads();
  return v;
}

__device__ __forceinline__ void gload_lds16(const void* g, void* l){
  __builtin_amdgcn_global_load_lds((const __attribute__((address_space(1))) void*)g,
                                   (__attribute__((address_space(3))) void*)l, 16, 0, 0);
}

// ---------------- fused fp32 -> bf16 convert (all 7 weights, 1 launch) ----------------
struct CvtArgs { const float* s[7]; u16* d[7]; int n[7]; };
__global__ __launch_bounds__(256) void k_cvt_all(CvtArgs a, int total4){
  int i = blockIdx.x*256 + threadIdx.x;   // in float4 units
  if (i >= total4) return;
  int e = i*4;
  #pragma unroll
  for (int j=0;j<7;j++){
    if (e < a.n[j]){
      float4 v = *(const float4*)(a.s[j]+e);
      u16* d = a.d[j]+e;
      d[0]=f2b(v.x); d[1]=f2b(v.y); d[2]=f2b(v.z); d[3]=f2b(v.w);
      return;
    }
    e -= a.n[j];
  }
}

// ---------------- rms over 1024 (fp32 in -> bf16 out) ----------------
__global__ __launch_bounds__(256) void k_rms1024(const float* __restrict__ src, const float* __restrict__ w,
                                                 u16* __restrict__ dst){
  int row = blockIdx.x, tid = threadIdx.x;
  const float* s = src + (size_t)row*1024;
  float v[4]; float ss=0.f;
  #pragma unroll
  for (int i=0;i<4;i++){ v[i] = s[tid + i*256]; ss += v[i]*v[i]; }
  ss = block_sum256(ss);
  float sc = rsqrtf(ss*(1.0f/1024.0f) + 1e-6f);
  u16* d = dst + (size_t)row*1024;
  #pragma unroll
  for (int i=0;i<4;i++){ int c = tid+i*256; d[c] = f2b(v[i]*sc*w[c]); }
}

// ---------------- GEMM 128x128, BK=32, depth-2 counted-vmcnt pipeline, 32KB LDS (4 blk/CU) ----
// LDS [128][4 chunks of 16B]: LDS[row][c] holds global chunk c ^ ((row>>1)&3).
// Staged via gload_lds with pre-swizzled GLOBAL source (linear LDS dest, rule #21);
// read with the same XOR -> per-16-lane fragment group spreads over 8 bank-quads (2-way, free).
// mode: 0 = C=acc (f32), 1 = C+=acc, 2 = C16=bf16(acc), 3 = C = ADD + acc (f32)
#define BKq 32
__global__ __launch_bounds__(256,4) void k_gemm128p(const u16* __restrict__ A, const u16* __restrict__ W,
                                                    float* __restrict__ C, u16* __restrict__ C16,
                                                    const float* __restrict__ ADD,
                                                    int M, int N, int K, int gx, int mode){
  __shared__ u16 lA[2][128*BKq];   // 2 x 8KB
  __shared__ u16 lB[2][128*BKq];   // 2 x 8KB
  int tid = threadIdx.x, lane = tid&63, wid = tid>>6;
  int nwg = gridDim.x;
  int cpx = nwg>>3;
  int bid = blockIdx.x;
  int swz = (bid&7)*cpx + (bid>>3);
  int bx = swz % gx, by = swz / gx;
  int bm = by*128, bn = bx*128;
  int wr = wid>>1, wc = wid&1;
  int fr = lane&15, fq = lane>>4;
  f32x4 acc[4][4];
  #pragma unroll
  for (int mi=0;mi<4;mi++)
    #pragma unroll
    for (int ni=0;ni<4;ni++)
      #pragma unroll
      for (int r=0;r<4;r++) acc[mi][ni][r]=0.f;

  auto stage = [&](int buf, int t){
    int k0 = t*BKq;
    #pragma unroll
    for (int i=0;i<2;i++){
      int row = i*64 + (tid>>2);                 // 0..127
      int chunk = (tid&3) ^ ((row>>1)&3);        // pre-swizzled global chunk
      int ra = bm + row; if (ra > M-1) ra = M-1;
      gload_lds16(A + (size_t)ra*K + k0 + chunk*8, &lA[buf][i*2048 + tid*8]);
      int rb = bn + row; if (rb > N-1) rb = N-1;
      gload_lds16(W + (size_t)rb*K + k0 + chunk*8, &lB[buf][i*2048 + tid*8]);
    }
  };

  int NT = K/BKq;
  stage(0, 0);
  stage(1, 1);
  int slot = (fq ^ ((fr>>1)&3))*8;               // swizzled element offset within row
  for (int t=0;t<NT;t++){
    int cur = t&1;
    // wait for stage(t) (4 loads, oldest); stage(t+1)'s 4 loads may stay in flight
    if (t+1 < NT) asm volatile("s_waitcnt vmcnt(4)" ::: "memory");
    else          asm volatile("s_waitcnt vmcnt(0)" ::: "memory");
    __builtin_amdgcn_sched_barrier(0);
    __builtin_amdgcn_s_barrier();                // all waves' stage(t) landed
    {
      short8 bf4[4], af4[4];
      #pragma unroll
      for (int ni=0;ni<4;ni++)
        bf4[ni] = *(const short8*)(&lB[cur][(wc*64 + ni*16 + fr)*BKq + slot]);
      #pragma unroll
      for (int mi=0;mi<4;mi++)
        af4[mi] = *(const short8*)(&lA[cur][(wr*64 + mi*16 + fr)*BKq + slot]);
      #pragma unroll
      for (int mi=0;mi<4;mi++)
        #pragma unroll
        for (int ni=0;ni<4;ni++)
          acc[mi][ni] = __builtin_amdgcn_mfma_f32_16x16x32_bf16(af4[mi], bf4[ni], acc[mi][ni], 0,0,0);
    }
    // release buf cur for overwrite: my ds_reads done + rendezvous
    asm volatile("s_waitcnt lgkmcnt(0)" ::: "memory");
    __builtin_amdgcn_sched_barrier(0);
    __builtin_amdgcn_s_barrier();
    if (t+2 < NT) stage(cur, t+2);
  }
  // epilogue
  #pragma unroll
  for (int mi=0;mi<4;mi++){
    int row0 = bm + wr*64 + mi*16 + fq*4;
    #pragma unroll
    for (int ni=0;ni<4;ni++){
      int col = bn + wc*64 + ni*16 + fr;
      if (col < N){
        #pragma unroll
        for (int r=0;r<4;r++){
          size_t idx = (size_t)(row0+r)*N + col;
          float v = acc[mi][ni][r];
          if (mode == 2)      C16[idx] = f2b(v);
          else if (mode == 1) C[idx] += v;
          else if (mode == 3) C[idx] = ADD[idx] + v;
          else                C[idx] = v;
        }
      }
    }
  }
}

// ---------------- dt prep ----------------
__global__ __launch_bounds__(256) void k_dtprep(const float* __restrict__ proj, const float* __restrict__ Wdt,
      const float* __restrict__ dt_bias, const float* __restrict__ A_log,
      float* __restrict__ dtA, float* __restrict__ dtB){
  int idx = blockIdx.x*256 + threadIdx.x;  // BT*H_SSM
  int h = idx & 7; int bt = idx >> 3;
  const float* dtl  = proj + (size_t)bt*TOTx + 2*DIx;
  const float* wrow = Wdt + h*64;
  float v = dt_bias[h];
  #pragma unroll 8
  for (int i=0;i<64;i++) v += dtl[i]*wrow[i];
  float sp = (v > 20.0f) ? v : log1pf(expf(v));
  float dt = fminf(fmaxf(sp, 1e-4f), 1.0f);
  const float* bm = proj + (size_t)bt*TOTx + 2*DIx + DTRx + h*16;
  #pragma unroll
  for (int n=0;n<16;n++){
    float Av = -expf(A_log[h*16+n]);
    dtA[(size_t)idx*16+n] = dt*Av;
    dtB[(size_t)idx*16+n] = dt*bm[n];
  }
}

// ---------------- scan phase 1: per-chunk local scan (conv+silu fused, rolling window) ----------------
__global__ __launch_bounds__(256) void k_scan1(const float* __restrict__ dtA, const float* __restrict__ dtB,
    const float* __restrict__ proj, const float* __restrict__ cw, const float* __restrict__ cb,
    float* __restrict__ expS, float* __restrict__ y, float* __restrict__ LS){
  __shared__ float sA[1024], sS[1024], sB[1024], sC[1024];
  int bx = blockIdx.x;                 // b*256 + h*32 + c
  int c = bx & 31, h = (bx>>5)&7, b = bx>>8;
  int tid = threadIdx.x;
  size_t t0 = (size_t)b*Tn + c*64;
  int j = tid>>2, n0 = (tid&3)*4;
  {
    size_t ga = (t0 + j)*128 + h*16 + n0;
    float4 va = *(const float4*)(dtA + ga);
    float4 vb = *(const float4*)(dtB + ga);
    float4 vc = *(const float4*)(proj + (t0 + j)*TOTx + (2*DIx+DTRx+H_SSM*Nst) + h*16 + n0);
    *(float4*)(&sA[j*16+n0]) = va;
    *(float4*)(&sB[j*16+n0]) = vb;
    *(float4*)(&sC[j*16+n0]) = vc;
  }
  __syncthreads();
  if (tid < 16){
    float cum = 0.f;
    for (int jj=0;jj<64;jj++){ cum += sA[jj*16+tid]; sS[jj*16+tid] = cum; }
  }
  __syncthreads();
  {
    float e[4], s4[4];
    #pragma unroll
    for (int i=0;i<4;i++){ e[i] = expf(sA[j*16+n0+i]); s4[i] = expf(sS[j*16+n0+i]); }
    #pragma unroll
    for (int i=0;i<4;i++){ sA[j*16+n0+i] = e[i]; sS[j*16+n0+i] = s4[i]; }
    float4 ev; ev.x=s4[0]; ev.y=s4[1]; ev.z=s4[2]; ev.w=s4[3];
    *(float4*)(expS + (t0+j)*128 + h*16 + n0) = ev;
  }
  __syncthreads();
  float st[16];
  #pragma unroll
  for (int n=0;n<16;n++) st[n]=0.f;
  int ch = h*Px + tid;                        // xin channel
  const float* pxin = proj + t0*TOTx + ch;
  float w0=cw[ch*4+0], w1=cw[ch*4+1], w2=cw[ch*4+2], w3=cw[ch*4+3];
  float bcv = cb[ch];
  float x3=0.f, x2=0.f, x1=0.f;
  if (c > 0){
    x3 = pxin[-(ptrdiff_t)3*TOTx];
    x2 = pxin[-(ptrdiff_t)2*TOTx];
    x1 = pxin[-(ptrdiff_t)TOTx];
  }
  float* yp = y + t0*DIx + ch;
  for (int jj=0;jj<64;jj++){
    float x0 = pxin[(size_t)jj*TOTx];
    float cv = bcv + x3*w0 + x2*w1 + x1*w2 + x0*w3;
    float x = cv / (1.0f + expf(-cv));       // silu(conv)
    x3=x2; x2=x1; x1=x0;
    float acc = 0.f;
    #pragma unroll
    for (int n=0;n<16;n++){ st[n] = st[n]*sA[jj*16+n] + x*sB[jj*16+n]; acc += st[n]*sC[jj*16+n]; }
    yp[(size_t)jj*DIx] = acc;
  }
  float* ls = LS + ((((size_t)b*8+h)*NCH + c)*Px + tid)*16;
  #pragma unroll
  for (int n=0;n<16;n++) ls[n] = st[n];
}

// ---------------- scan phase 2: chunk-state scan ----------------
__global__ __launch_bounds__(256) void k_scan2(const float* __restrict__ expS, const float* __restrict__ LS,
                                               float* __restrict__ H0){
  int bh = blockIdx.x; int b = bh>>3, h = bh&7;
  int tid = threadIdx.x;
  __shared__ float dl[16];
  float Hs[16];
  #pragma unroll
  for (int n=0;n<16;n++) Hs[n]=0.f;
  for (int c=0;c<NCH;c++){
    if (tid<16) dl[tid] = expS[((size_t)b*Tn + c*64 + 63)*128 + h*16 + tid];
    __syncthreads();
    size_t base = ((((size_t)b*8+h)*NCH + c)*Px + tid)*16;
    #pragma unroll
    for (int n=0;n<16;n++){ H0[base+n] = Hs[n]; Hs[n] = Hs[n]*dl[n] + LS[base+n]; }
    __syncthreads();
  }
}

// ---------------- scan phase 3: fixup + Dskip (conv+silu refused, rolling window) ----------------
__global__ __launch_bounds__(256) void k_scan3(const float* __restrict__ proj, const float* __restrict__ expS,
    const float* __restrict__ H0, const float* __restrict__ cw, const float* __restrict__ cb,
    const float* __restrict__ Dskip, float* __restrict__ y){
  __shared__ float ce[1024];
  int bx = blockIdx.x; int c = bx&31, h=(bx>>5)&7, b=bx>>8;
  int tid = threadIdx.x;
  size_t t0 = (size_t)b*Tn + c*64;
  int j = tid>>2, n0=(tid&3)*4;
  {
    float4 cv = *(const float4*)(proj + (t0+j)*TOTx + (2*DIx+DTRx+H_SSM*Nst) + h*16 + n0);
    float4 evv = *(const float4*)(expS + (t0+j)*128 + h*16 + n0);
    float4 o; o.x=cv.x*evv.x; o.y=cv.y*evv.y; o.z=cv.z*evv.z; o.w=cv.w*evv.w;
    *(float4*)(&ce[j*16+n0]) = o;
  }
  __syncthreads();
  float h0[16];
  size_t base = ((((size_t)b*8+h)*NCH + c)*Px + tid)*16;
  #pragma unroll
  for (int n=0;n<16;n++) h0[n] = H0[base+n];
  int ch = h*Px + tid;
  float dsk = Dskip[ch];
  const float* pxin = proj + t0*TOTx + ch;
  float w0=cw[ch*4+0], w1=cw[ch*4+1], w2=cw[ch*4+2], w3=cw[ch*4+3];
  float bcv = cb[ch];
  float x3=0.f, x2=0.f, x1=0.f;
  if (c > 0){
    x3 = pxin[-(ptrdiff_t)3*TOTx];
    x2 = pxin[-(ptrdiff_t)2*TOTx];
    x1 = pxin[-(ptrdiff_t)TOTx];
  }
  float* yp = y + t0*DIx + ch;
  for (int jj=0;jj<64;jj++){
    float x0 = pxin[(size_t)jj*TOTx];
    float cv = bcv + x3*w0 + x2*w1 + x1*w2 + x0*w3;
    float x = cv / (1.0f + expf(-cv));
    x3=x2; x2=x1; x1=x0;
    float f = 0.f;
    #pragma unroll
    for (int n=0;n<16;n++) f += ce[jj*16+n]*h0[n];
    yp[(size_t)jj*DIx] += f + dsk*x;
  }
}

// ---------------- gated rms ----------------
__global__ __launch_bounds__(256) void k_gatedrms(const float* __restrict__ y, const float* __restrict__ proj,
     const float* __restrict__ w, u16* __restrict__ yn){
  int row = blockIdx.x, tid = threadIdx.x;
  const float* yr = y + (size_t)row*DIx;
  const float* zr = proj + (size_t)row*TOTx + DIx;
  float v[8]; float ss=0.f;
  #pragma unroll
  for (int i=0;i<8;i++){
    int cidx = tid + i*256;
    float z = zr[cidx];
    float g = yr[cidx] * (z / (1.0f + expf(-z)));
    v[i]=g; ss += g*g;
  }
  ss = block_sum256(ss);
  float sc = rsqrtf(ss*(1.0f/2048.0f) + 1e-6f);
  u16* d = yn + (size_t)row*DIx;
  #pragma unroll
  for (int i=0;i<8;i++){ int cidx=tid+i*256; d[cidx] = f2b(v[i]*sc*w[cidx]); }
}

// ---------------- h = x + sout; u2 = rms(h)*w (bf16) ----------------
__global__ __launch_bounds__(256) void k_addrms(const float* __restrict__ x, const float* __restrict__ sout,
     const float* __restrict__ w, float* __restrict__ hbuf, u16* __restrict__ u2){
  int row=blockIdx.x, tid=threadIdx.x;
  float v[4]; float ss=0.f;
  #pragma unroll
  for (int i=0;i<4;i++){
    int cidx = tid + i*256;
    size_t idx = (size_t)row*1024 + cidx;
    float hv = x[idx] + sout[idx];
    hbuf[idx]=hv; v[i]=hv; ss+=hv*hv;
  }
  ss = block_sum256(ss);
  float sc = rsqrtf(ss*(1.0f/1024.0f)+1e-6f);
  #pragma unroll
  for (int i=0;i<4;i++){ int cidx=tid+i*256; u2[(size_t)row*1024+cidx] = f2b(v[i]*sc*w[cidx]); }
}

// ---------------- rope + transpose to [B,H,T,HD] (bf16), fused-QKV bf16 input ----------------
__global__ __launch_bounds__(256) void k_rope(const u16* __restrict__ qkvb,
    u16* __restrict__ qr, u16* __restrict__ kr, u16* __restrict__ vr){
  int idx = blockIdx.x*256 + threadIdx.x;  // B*T*D
  int d = idx & 63;
  int h = (idx>>6) & 15;
  int t = (idx>>10) & 2047;
  int b = idx >> 21;
  int col = idx & 1023;
  size_t base = (size_t)(idx>>10)*3072;
  int dh = d & 31;
  float ang = (float)t * exp2f(-(float)dh * (13.287712379549449f/32.0f));  // t * 10000^(-dh/32)
  float cs = cosf(ang), sn = sinf(ang);
  int part = (d<32) ? 32 : -32;
  float q = b2f(qkvb[base + col]),        qp = b2f(qkvb[base + col + part]);
  float k = b2f(qkvb[base + 1024 + col]), kp = b2f(qkvb[base + 1024 + col + part]);
  float vv = b2f(qkvb[base + 2048 + col]);
  float rq = (d<32)? -qp : qp;
  float rk = (d<32)? -kp : kp;
  size_t dst = (((size_t)b*H_ATTN + h)*Tn + t)*64 + d;
  qr[dst] = f2b(q*cs + rq*sn);
  kr[dst] = f2b(k*cs + rk*sn);
  vr[dst] = f2b(vv);
}

// ---------------- MFMA sliding-window attention ----------------
#define QT 64
#define KSPAN 192
__device__ __forceinline__ u32 swz128a(int row, int b){  // tile stride 128B
  return (u32)((row*128 + b) ^ ((((row&7)^((row>>3)&7)))<<4));
}
__device__ __forceinline__ u32 swz384a(int row, int b){  // tile stride 384B
  return (u32)((row*384 + b) ^ ((((row&7)^((row>>3)&7)))<<4));
}

__global__ __launch_bounds__(256) void k_attn_mfma(const u16* __restrict__ qr, const u16* __restrict__ kr,
    const u16* __restrict__ vr, u16* __restrict__ ya){
  __shared__ u16 bufK[KSPAN*64];   // 24576 B ; later P[64][192]
  __shared__ u16 bufV[64*KSPAN];   // 24576 B
  int tid = threadIdx.x, lane = tid&63, wid = tid>>6;
  int fr = lane&15, fq = lane>>4;
  int blk = blockIdx.x;            // bh*32 + qt
  int qt = blk & 31, bh = blk >> 5;
  int t0 = qt*QT;
  size_t rowbase = (size_t)bh*Tn;
  char* cK = (char*)bufK;
  char* cV = (char*)bufV;

  #pragma unroll
  for (int it=0; it<6; ++it){
    int chunk = it*256 + tid;
    int row = chunk>>3, c8 = chunk&7;
    int sg = t0 - 128 + row;
    if (sg >= 0){
      short8 v = *(const short8*)(kr + (rowbase+sg)*64 + c8*8);
      *(short8*)(cK + swz128a(row, c8*16)) = v;
    }
  }
  #pragma unroll
  for (int it=0; it<24; ++it){
    int idx = it*256 + tid;
    int s = idx>>5, dp = idx&31, d0 = dp*2;
    int sg = t0 - 128 + s;
    u16 lo = 0, hi = 0;
    if (sg >= 0){
      u32 w = *(const u32*)(vr + (rowbase+sg)*64 + d0);
      lo = (u16)(w & 0xffffu); hi = (u16)(w >> 16);
    }
    *(u16*)(cV + swz384a(d0,   s*2)) = lo;
    *(u16*)(cV + swz384a(d0+1, s*2)) = hi;
  }
  __syncthreads();

  f32x4 acc[12];
  #pragma unroll
  for (int j=0;j<12;j++)
    #pragma unroll
    for (int r=0;r<4;r++) acc[j][r]=0.f;
  #pragma unroll
  for (int kk=0;kk<2;kk++){
    short8 aq = *(const short8*)(qr + (rowbase + t0 + wid*16 + fr)*64 + kk*32 + fq*8);
    #pragma unroll
    for (int j=0;j<12;j++){
      short8 bk = *(const short8*)(cK + swz128a(j*16+fr, kk*64 + fq*16));
      acc[j] = __builtin_amdgcn_mfma_f32_16x16x32_bf16(aq, bk, acc[j], 0,0,0);
    }
  }

  float p[12][4];
  int cb = lane&15;
  #pragma unroll
  for (int r=0;r<4;r++){
    int rq = wid*16 + (lane>>4)*4 + r;
    float m = -3.0e38f;
    #pragma unroll
    for (int j=0;j<12;j++){
      int c = j*16 + cb;
      bool allowed = (c > rq) && (c <= rq+128) && (c >= 128 - t0);
      float v = allowed ? acc[j][r]*0.125f : -3.0e38f;
      p[j][r] = v;
      m = fmaxf(m, v);
    }
    #pragma unroll
    for (int o=1;o<16;o<<=1) m = fmaxf(m, __shfl_xor(m, o, 64));
    float sum = 0.f;
    #pragma unroll
    for (int j=0;j<12;j++){ float e = __expf(p[j][r]-m); p[j][r]=e; sum += e; }
    #pragma unroll
    for (int o=1;o<16;o<<=1) sum += __shfl_xor(sum, o, 64);
    float inv = 1.0f/sum;
    #pragma unroll
    for (int j=0;j<12;j++) p[j][r] *= inv;
  }
  __syncthreads();

  #pragma unroll
  for (int r=0;r<4;r++){
    int rq = wid*16 + (lane>>4)*4 + r;
    #pragma unroll
    for (int j=0;j<12;j++){
      *(u16*)(cK + swz384a(rq, (j*16+cb)*2)) = f2b(p[j][r]);
    }
  }
  __syncthreads();

  f32x4 acc2[4];
  #pragma unroll
  for (int f=0;f<4;f++)
    #pragma unroll
    for (int r=0;r<4;r++) acc2[f][r]=0.f;
  #pragma unroll
  for (int kk=0;kk<6;kk++){
    short8 ap = *(const short8*)(cK + swz384a(wid*16 + fr, kk*64 + fq*16));
    #pragma unroll
    for (int f=0;f<4;f++){
      short8 bv = *(const short8*)(cV + swz384a(f*16+fr, kk*64 + fq*16));
      acc2[f] = __builtin_amdgcn_mfma_f32_16x16x32_bf16(ap, bv, acc2[f], 0,0,0);
    }
  }
  int b = bh >> 4, h = bh & 15;
  #pragma unroll
  for (int f=0;f<4;f++){
    int d = f*16 + cb;
    #pragma unroll
    for (int r=0;r<4;r++){
      int q = t0 + wid*16 + (lane>>4)*4 + r;
      ya[((size_t)b*Tn + q)*Dm + h*64 + d] = f2b(acc2[f][r]);
    }
  }
}

// =================================================================
extern "C" void kernel_launch(void* const* d_in, const int* in_sizes, int n_in,
                              void* d_out, int out_size, void* d_ws, size_t ws_size,
                              hipStream_t stream) {
  const float* x        = (const float*)d_in[0];
  const float* norm1_w  = (const float*)d_in[1];
  const float* norm2_w  = (const float*)d_in[2];
  const float* Win      = (const float*)d_in[3];
  const float* Wdt      = (const float*)d_in[4];
  const float* conv_w   = (const float*)d_in[5];
  const float* conv_b   = (const float*)d_in[6];
  const float* A_log    = (const float*)d_in[7];
  const float* Dskip    = (const float*)d_in[8];
  const float* dt_bias  = (const float*)d_in[9];
  const float* ssd_norm = (const float*)d_in[10];
  const float* Wout_ssd = (const float*)d_in[11];
  const float* Wres     = (const float*)d_in[12];
  const float* Wq       = (const float*)d_in[13];
  const float* Wk       = (const float*)d_in[14];
  const float* Wv       = (const float*)d_in[15];
  const float* Wo       = (const float*)d_in[16];

  char* ws = (char*)d_ws;
  size_t off = 0;
  auto alloc = [&](size_t bytes){ size_t r = off; off += (bytes + 255) & ~(size_t)255; return r; };

  size_t o_WinB  = alloc((size_t)TOTx*Dm*2);
  size_t o_WresB = alloc((size_t)DIx*Dm*2);
  size_t o_WoutB = alloc((size_t)Dm*DIx*2);
  size_t o_WqB   = alloc((size_t)Dm*Dm*2);
  size_t o_WkB   = alloc((size_t)Dm*Dm*2);
  size_t o_WvB   = alloc((size_t)Dm*Dm*2);
  size_t o_WoB   = alloc((size_t)Dm*Dm*2);
  size_t o_u1    = alloc((size_t)BT*Dm*2);        // later reused as vr
  size_t o_proj  = alloc((size_t)BT*TOTx*4);      // later: qkvb (bf16), qr/kr (bf16)
  size_t o_xc    = alloc((size_t)BT*DIx*4);       // sout @+0, att-region free
  size_t o_dtA   = alloc((size_t)BT*H_SSM*Nst*4);
  size_t o_dtB   = alloc((size_t)BT*H_SSM*Nst*4);
  size_t o_expS  = alloc((size_t)BT*H_SSM*Nst*4);
  size_t o_LS    = alloc((size_t)Bsz*H_SSM*NCH*Px*Nst*4);
  size_t o_H0    = alloc((size_t)Bsz*H_SSM*NCH*Px*Nst*4);
  size_t o_y     = alloc((size_t)BT*DIx*4);       // later: y_att bf16 @+0
  size_t o_yn    = alloc((size_t)BT*DIx*2);
  size_t o_hb    = alloc((size_t)BT*Dm*4);

  u16* WinB  = (u16*)(ws + o_WinB);
  u16* WresB = (u16*)(ws + o_WresB);
  u16* WoutB = (u16*)(ws + o_WoutB);
  u16* WqB   = (u16*)(ws + o_WqB);
  u16* u1    = (u16*)(ws + o_u1);
  float* proj = (float*)(ws + o_proj);
  float* dtA  = (float*)(ws + o_dtA);
  float* dtB  = (float*)(ws + o_dtB);
  float* expS = (float*)(ws + o_expS);
  float* LS   = (float*)(ws + o_LS);
  float* H0   = (float*)(ws + o_H0);
  float* ybuf = (float*)(ws + o_y);
  u16*   yn   = (u16*)(ws + o_yn);
  float* hb   = (float*)(ws + o_hb);
  // aliases (lifetimes disjoint)
  u16* qkvb = (u16*)(ws + o_proj);                // [BT][3072] bf16 = 24MiB (proj dead by then)
  u16* qr = (u16*)(ws + o_proj + 50331648);
  u16* kr = (u16*)(ws + o_proj + 58720256);
  u16* vr = u1;
  float* sout = (float*)(ws + o_xc);
  u16* yatt = (u16*)(ws + o_y);

  // fused weight convert
  {
    CvtArgs a;
    a.s[0]=Win;  a.d[0]=WinB;  a.n[0]=TOTx*Dm;
    a.s[1]=Wres; a.d[1]=WresB; a.n[1]=DIx*Dm;
    a.s[2]=Wout_ssd; a.d[2]=WoutB; a.n[2]=Dm*DIx;
    a.s[3]=Wq; a.d[3]=WqB; a.n[3]=Dm*Dm;
    a.s[4]=Wk; a.d[4]=(u16*)(ws + o_WkB); a.n[4]=Dm*Dm;
    a.s[5]=Wv; a.d[5]=(u16*)(ws + o_WvB); a.n[5]=Dm*Dm;
    a.s[6]=Wo; a.d[6]=(u16*)(ws + o_WoB); a.n[6]=Dm*Dm;
    int total4 = (a.n[0]+a.n[1]+a.n[2]+a.n[3]+a.n[4]+a.n[5]+a.n[6])/4;
    k_cvt_all<<<dim3((total4+255)/256), dim3(256), 0, stream>>>(a, total4);
  }

  // 1) u1 = rms(x, norm1_w)
  k_rms1024<<<dim3(BT), dim3(256), 0, stream>>>(x, norm1_w, u1);
  // 2) proj = u1 @ Win^T   (gx=35, 1120 blocks)
  k_gemm128p<<<dim3(35*32), dim3(256), 0, stream>>>(u1, WinB, proj, nullptr, nullptr, BT, TOTx, Dm, 35, 0);
  // 3) dt prep
  k_dtprep<<<dim3(BT*H_SSM/256), dim3(256), 0, stream>>>(proj, Wdt, dt_bias, A_log, dtA, dtB);
  // 4) chunked scan (conv+silu fused into scan1/scan3)
  k_scan1<<<dim3(Bsz*H_SSM*NCH), dim3(256), 0, stream>>>(dtA, dtB, proj, conv_w, conv_b, expS, ybuf, LS);
  k_scan2<<<dim3(Bsz*H_SSM), dim3(256), 0, stream>>>(expS, LS, H0);
  k_scan3<<<dim3(Bsz*H_SSM*NCH), dim3(256), 0, stream>>>(proj, expS, H0, conv_w, conv_b, Dskip, ybuf);
  // 5) y += u1 @ Wres^T  (512 blocks)
  k_gemm128p<<<dim3(16*32), dim3(256), 0, stream>>>(u1, WresB, ybuf, nullptr, nullptr, BT, DIx, Dm, 16, 1);
  // 6) yn = rms(y * silu(z)) * ssd_norm_w
  k_gatedrms<<<dim3(BT), dim3(256), 0, stream>>>(ybuf, proj, ssd_norm, yn);
  // 7) sout = yn @ Wout^T  (256 blocks, K=2048)
  k_gemm128p<<<dim3(8*32), dim3(256), 0, stream>>>(yn, WoutB, sout, nullptr, nullptr, BT, Dm, DIx, 8, 0);
  // 8) h = x + sout; u2 = rms(h)*norm2_w
  k_addrms<<<dim3(BT), dim3(256), 0, stream>>>(x, sout, norm2_w, hb, (u16*)(ws + o_yn));
  u16* u2p = (u16*)(ws + o_yn);
  // 9) fused QKV projection, bf16 out: qkvb = bf16(u2 @ [Wq;Wk;Wv]^T)  (768 blocks)
  k_gemm128p<<<dim3(24*32), dim3(256), 0, stream>>>(u2p, WqB, nullptr, qkvb, nullptr, BT, 3*Dm, Dm, 24, 2);
  // 10) rope + transpose (bf16 in)
  k_rope<<<dim3(BT*Dm/256), dim3(256), 0, stream>>>(qkvb, qr, kr, vr);
  // 11) attention (MFMA sliding-window)
  k_attn_mfma<<<dim3(Bsz*H_ATTN*(Tn/QT)), dim3(256), 0, stream>>>(qr, kr, vr, yatt);
  // 12) out = hb + yatt @ Wo^T  (256 blocks, fused final add)
  k_gemm128p<<<dim3(8*32), dim3(256), 0, stream>>>(yatt, (u16*)(ws + o_WoB), (float*)d_out, nullptr, hb, BT, Dm, Dm, 8, 3);
  (void)in_sizes; (void)n_in; (void)out_size; (void)ws_size;
}

// Round 7
// 420.702 us; speedup vs baseline: 2.2028x; 1.0180x over previous
//
#include <hip/hip_runtime.h>
#include <stdint.h>

typedef unsigned short u16;
typedef unsigned int u32;
typedef __attribute__((ext_vector_type(8))) short short8;
typedef __attribute__((ext_vector_type(4))) float f32x4;

// ---------------- problem constants ----------------
#define Bsz 2
#define Tn 2048
#define Dm 1024
#define H_ATTN 16
#define HDx 64
#define WINx 128
#define H_SSM 8
#define DIx 2048
#define Nst 16
#define DTRx 64
#define Px 256          // DI / H_SSM
#define TOTx 4416       // 2*DI + DTR + 2*H*N
#define BT (Bsz*Tn)     // 4096
#define NCH 32          // chunks
#define LCH 64          // chunk length

// ---------------- helpers ----------------
__device__ __forceinline__ float b2f(u16 u){ u32 x = ((u32)u)<<16; float f; __builtin_memcpy(&f,&x,4); return f; }
__device__ __forceinline__ u16 f2b(float f){ u32 x; __builtin_memcpy(&x,&f,4); u32 r = x + 0x7fffu + ((x>>16)&1u); return (u16)(r>>16); }

__device__ __forceinline__ float block_sum256(float v){
  #pragma unroll
  for (int o=32;o;o>>=1) v += __shfl_xor(v,o,64);
  __shared__ float sb[4];
  int wid = threadIdx.x>>6;
  if ((threadIdx.x&63)==0) sb[wid]=v;
  __syncthreads();
  v = sb[0]+sb[1]+sb[2]+sb[3];
  __syncthreads();
  return v;
}

__device__ __forceinline__ void gload_lds16(const void* g, void* l){
  __builtin_amdgcn_global_load_lds((const __attribute__((address_space(1))) void*)g,
                                   (__attribute__((address_space(3))) void*)l, 16, 0, 0);
}

// ---------------- fused fp32 -> bf16 convert (all 7 weights, 1 launch) ----------------
struct CvtArgs { const float* s[7]; u16* d[7]; int n[7]; };
__global__ __launch_bounds__(256) void k_cvt_all(CvtArgs a, int total4){
  int i = blockIdx.x*256 + threadIdx.x;   // in float4 units
  if (i >= total4) return;
  int e = i*4;
  #pragma unroll
  for (int j=0;j<7;j++){
    if (e < a.n[j]){
      float4 v = *(const float4*)(a.s[j]+e);
      u16* d = a.d[j]+e;
      d[0]=f2b(v.x); d[1]=f2b(v.y); d[2]=f2b(v.z); d[3]=f2b(v.w);
      return;
    }
    e -= a.n[j];
  }
}

// ---------------- rms over 1024 (fp32 in -> bf16 out) ----------------
__global__ __launch_bounds__(256) void k_rms1024(const float* __restrict__ src, const float* __restrict__ w,
                                                 u16* __restrict__ dst){
  int row = blockIdx.x, tid = threadIdx.x;
  const float* s = src + (size_t)row*1024;
  float v[4]; float ss=0.f;
  #pragma unroll
  for (int i=0;i<4;i++){ v[i] = s[tid + i*256]; ss += v[i]*v[i]; }
  ss = block_sum256(ss);
  float sc = rsqrtf(ss*(1.0f/1024.0f) + 1e-6f);
  u16* d = dst + (size_t)row*1024;
  #pragma unroll
  for (int i=0;i<4;i++){ int c = tid+i*256; d[c] = f2b(v[i]*sc*w[c]); }
}

// ---------------- GEMM 128x128, BK=64, depth-2 counted-vmcnt pipeline, swizzled LDS ----
// (r5-proven geometry: 64KB LDS, 2 blk/CU, vmcnt(8), zero bank conflicts)
// mode: 0 = C=acc (f32), 1 = C+=acc (f32), 2 = C16=bf16(acc), 3 = C=ADD+acc (f32),
//       4 = C16 = bf16(b2f(C16)+acc)
#define BKq 64
__global__ __launch_bounds__(256,2) void k_gemm128p(const u16* __restrict__ A, const u16* __restrict__ W,
                                                    float* __restrict__ C, u16* __restrict__ C16,
                                                    const float* __restrict__ ADD,
                                                    int M, int N, int K, int gx, int mode){
  __shared__ u16 lA[2][128*BKq];   // 2 x 16KB
  __shared__ u16 lB[2][128*BKq];   // 2 x 16KB
  int tid = threadIdx.x, lane = tid&63, wid = tid>>6;
  int nwg = gridDim.x;
  int cpx = nwg>>3;
  int bid = blockIdx.x;
  int swz = (bid&7)*cpx + (bid>>3);
  int bx = swz % gx, by = swz / gx;
  int bm = by*128, bn = bx*128;
  int wr = wid>>1, wc = wid&1;
  int fr = lane&15, fq = lane>>4;
  int s7 = fr&7;
  f32x4 acc[4][4];
  #pragma unroll
  for (int mi=0;mi<4;mi++)
    #pragma unroll
    for (int ni=0;ni<4;ni++)
      #pragma unroll
      for (int r=0;r<4;r++) acc[mi][ni][r]=0.f;

  int srow = lane>>3;                    // 0..7 (row within 8-row chunk)
  int scol = (((lane&7) ^ srow))*8;      // pre-swizzled global 16B-chunk -> elem offset
  auto stage = [&](int buf, int t){
    int k0 = t*BKq;
    #pragma unroll
    for (int i=0;i<4;i++){
      int row = (wid*4+i)*8 + srow;      // 0..127
      int ra = bm + row; if (ra > M-1) ra = M-1;
      gload_lds16(A + (size_t)ra*K + k0 + scol, &lA[buf][(wid*4+i)*512]);
      int rb = bn + row; if (rb > N-1) rb = N-1;
      gload_lds16(W + (size_t)rb*K + k0 + scol, &lB[buf][(wid*4+i)*512]);
    }
  };

  int NT = K/BKq;
  stage(0, 0);
  stage(1, 1);
  for (int t=0;t<NT;t++){
    int cur = t&1;
    // wait for stage(t) (issued 2 iters ago); stage(t+1)'s 8 loads stay in flight
    if (t+1 < NT) asm volatile("s_waitcnt vmcnt(8)" ::: "memory");
    else          asm volatile("s_waitcnt vmcnt(0)" ::: "memory");
    __builtin_amdgcn_sched_barrier(0);
    __builtin_amdgcn_s_barrier();        // all waves' stage(t) landed
    #pragma unroll
    for (int kk=0;kk<2;kk++){
      short8 bf4[4], af4[4];
      int slotb = ((kk*4 + fq) ^ s7)*8;  // swizzled element offset within row
      #pragma unroll
      for (int ni=0;ni<4;ni++)
        bf4[ni] = *(const short8*)(&lB[cur][(wc*64 + ni*16 + fr)*BKq + slotb]);
      #pragma unroll
      for (int mi=0;mi<4;mi++)
        af4[mi] = *(const short8*)(&lA[cur][(wr*64 + mi*16 + fr)*BKq + slotb]);
      #pragma unroll
      for (int mi=0;mi<4;mi++)
        #pragma unroll
        for (int ni=0;ni<4;ni++)
          acc[mi][ni] = __builtin_amdgcn_mfma_f32_16x16x32_bf16(af4[mi], bf4[ni], acc[mi][ni], 0,0,0);
    }
    // release buf cur for overwrite
    asm volatile("s_waitcnt lgkmcnt(0)" ::: "memory");
    __builtin_amdgcn_sched_barrier(0);
    __builtin_amdgcn_s_barrier();
    if (t+2 < NT) stage(cur, t+2);
  }
  // epilogue
  #pragma unroll
  for (int mi=0;mi<4;mi++){
    int row0 = bm + wr*64 + mi*16 + fq*4;
    #pragma unroll
    for (int ni=0;ni<4;ni++){
      int col = bn + wc*64 + ni*16 + fr;
      if (col < N){
        #pragma unroll
        for (int r=0;r<4;r++){
          size_t idx = (size_t)(row0+r)*N + col;
          float v = acc[mi][ni][r];
          if (mode == 0)      C[idx] = v;
          else if (mode == 1) C[idx] += v;
          else if (mode == 2) C16[idx] = f2b(v);
          else if (mode == 3) C[idx] = ADD[idx] + v;
          else                C16[idx] = f2b(b2f(C16[idx]) + v);
        }
      }
    }
  }
}

// ---------------- dt prep ----------------
__global__ __launch_bounds__(256) void k_dtprep(const float* __restrict__ proj, const float* __restrict__ Wdt,
      const float* __restrict__ dt_bias, const float* __restrict__ A_log,
      float* __restrict__ dtA, float* __restrict__ dtB){
  int idx = blockIdx.x*256 + threadIdx.x;  // BT*H_SSM
  int h = idx & 7; int bt = idx >> 3;
  const float* dtl  = proj + (size_t)bt*TOTx + 2*DIx;
  const float* wrow = Wdt + h*64;
  float v = dt_bias[h];
  #pragma unroll 8
  for (int i=0;i<64;i++) v += dtl[i]*wrow[i];
  float sp = (v > 20.0f) ? v : log1pf(expf(v));
  float dt = fminf(fmaxf(sp, 1e-4f), 1.0f);
  const float* bm = proj + (size_t)bt*TOTx + 2*DIx + DTRx + h*16;
  #pragma unroll
  for (int n=0;n<16;n++){
    float Av = -expf(A_log[h*16+n]);
    dtA[(size_t)idx*16+n] = dt*Av;
    dtB[(size_t)idx*16+n] = dt*bm[n];
  }
}

// ---------------- scan phase 1: per-chunk local scan (conv+silu fused), bf16 y out ----------------
__global__ __launch_bounds__(256) void k_scan1(const float* __restrict__ dtA, const float* __restrict__ dtB,
    const float* __restrict__ proj, const float* __restrict__ cw, const float* __restrict__ cb,
    float* __restrict__ expS, u16* __restrict__ y, float* __restrict__ LS){
  __shared__ float sA[1024], sS[1024], sB[1024], sC[1024];
  int bx = blockIdx.x;                 // b*256 + h*32 + c
  int c = bx & 31, h = (bx>>5)&7, b = bx>>8;
  int tid = threadIdx.x;
  size_t t0 = (size_t)b*Tn + c*64;
  int j = tid>>2, n0 = (tid&3)*4;
  {
    size_t ga = (t0 + j)*128 + h*16 + n0;
    float4 va = *(const float4*)(dtA + ga);
    float4 vb = *(const float4*)(dtB + ga);
    float4 vc = *(const float4*)(proj + (t0 + j)*TOTx + (2*DIx+DTRx+H_SSM*Nst) + h*16 + n0);
    *(float4*)(&sA[j*16+n0]) = va;
    *(float4*)(&sB[j*16+n0]) = vb;
    *(float4*)(&sC[j*16+n0]) = vc;
  }
  __syncthreads();
  if (tid < 16){
    float cum = 0.f;
    for (int jj=0;jj<64;jj++){ cum += sA[jj*16+tid]; sS[jj*16+tid] = cum; }
  }
  __syncthreads();
  {
    float e[4], s4[4];
    #pragma unroll
    for (int i=0;i<4;i++){ e[i] = expf(sA[j*16+n0+i]); s4[i] = expf(sS[j*16+n0+i]); }
    #pragma unroll
    for (int i=0;i<4;i++){ sA[j*16+n0+i] = e[i]; sS[j*16+n0+i] = s4[i]; }
    float4 ev; ev.x=s4[0]; ev.y=s4[1]; ev.z=s4[2]; ev.w=s4[3];
    *(float4*)(expS + (t0+j)*128 + h*16 + n0) = ev;
  }
  __syncthreads();
  float st[16];
  #pragma unroll
  for (int n=0;n<16;n++) st[n]=0.f;
  int ch = h*Px + tid;                        // xin channel
  const float* pxin = proj + t0*TOTx + ch;
  float w0=cw[ch*4+0], w1=cw[ch*4+1], w2=cw[ch*4+2], w3=cw[ch*4+3];
  float bcv = cb[ch];
  float x3=0.f, x2=0.f, x1=0.f;
  if (c > 0){
    x3 = pxin[-(ptrdiff_t)3*TOTx];
    x2 = pxin[-(ptrdiff_t)2*TOTx];
    x1 = pxin[-(ptrdiff_t)TOTx];
  }
  u16* yp = y + t0*DIx + ch;
  for (int jj=0;jj<64;jj++){
    float x0 = pxin[(size_t)jj*TOTx];
    float cv = bcv + x3*w0 + x2*w1 + x1*w2 + x0*w3;
    float x = cv / (1.0f + expf(-cv));       // silu(conv)
    x3=x2; x2=x1; x1=x0;
    float acc = 0.f;
    #pragma unroll
    for (int n=0;n<16;n++){ st[n] = st[n]*sA[jj*16+n] + x*sB[jj*16+n]; acc += st[n]*sC[jj*16+n]; }
    yp[(size_t)jj*DIx] = f2b(acc);
  }
  float* ls = LS + ((((size_t)b*8+h)*NCH + c)*Px + tid)*16;
  #pragma unroll
  for (int n=0;n<16;n++) ls[n] = st[n];
}

// ---------------- scan phase 2: chunk-state scan ----------------
__global__ __launch_bounds__(256) void k_scan2(const float* __restrict__ expS, const float* __restrict__ LS,
                                               float* __restrict__ H0){
  int bh = blockIdx.x; int b = bh>>3, h = bh&7;
  int tid = threadIdx.x;
  __shared__ float dl[16];
  float Hs[16];
  #pragma unroll
  for (int n=0;n<16;n++) Hs[n]=0.f;
  for (int c=0;c<NCH;c++){
    if (tid<16) dl[tid] = expS[((size_t)b*Tn + c*64 + 63)*128 + h*16 + tid];
    __syncthreads();
    size_t base = ((((size_t)b*8+h)*NCH + c)*Px + tid)*16;
    #pragma unroll
    for (int n=0;n<16;n++){ H0[base+n] = Hs[n]; Hs[n] = Hs[n]*dl[n] + LS[base+n]; }
    __syncthreads();
  }
}

// ---------------- scan phase 3: fixup + Dskip (conv refused), bf16 y RMW ----------------
__global__ __launch_bounds__(256) void k_scan3(const float* __restrict__ proj, const float* __restrict__ expS,
    const float* __restrict__ H0, const float* __restrict__ cw, const float* __restrict__ cb,
    const float* __restrict__ Dskip, u16* __restrict__ y){
  __shared__ float ce[1024];
  int bx = blockIdx.x; int c = bx&31, h=(bx>>5)&7, b=bx>>8;
  int tid = threadIdx.x;
  size_t t0 = (size_t)b*Tn + c*64;
  int j = tid>>2, n0=(tid&3)*4;
  {
    float4 cv = *(const float4*)(proj + (t0+j)*TOTx + (2*DIx+DTRx+H_SSM*Nst) + h*16 + n0);
    float4 evv = *(const float4*)(expS + (t0+j)*128 + h*16 + n0);
    float4 o; o.x=cv.x*evv.x; o.y=cv.y*evv.y; o.z=cv.z*evv.z; o.w=cv.w*evv.w;
    *(float4*)(&ce[j*16+n0]) = o;
  }
  __syncthreads();
  float h0[16];
  size_t base = ((((size_t)b*8+h)*NCH + c)*Px + tid)*16;
  #pragma unroll
  for (int n=0;n<16;n++) h0[n] = H0[base+n];
  int ch = h*Px + tid;
  float dsk = Dskip[ch];
  const float* pxin = proj + t0*TOTx + ch;
  float w0=cw[ch*4+0], w1=cw[ch*4+1], w2=cw[ch*4+2], w3=cw[ch*4+3];
  float bcv = cb[ch];
  float x3=0.f, x2=0.f, x1=0.f;
  if (c > 0){
    x3 = pxin[-(ptrdiff_t)3*TOTx];
    x2 = pxin[-(ptrdiff_t)2*TOTx];
    x1 = pxin[-(ptrdiff_t)TOTx];
  }
  u16* yp = y + t0*DIx + ch;
  for (int jj=0;jj<64;jj++){
    float x0 = pxin[(size_t)jj*TOTx];
    float cv = bcv + x3*w0 + x2*w1 + x1*w2 + x0*w3;
    float x = cv / (1.0f + expf(-cv));
    x3=x2; x2=x1; x1=x0;
    float f = 0.f;
    #pragma unroll
    for (int n=0;n<16;n++) f += ce[jj*16+n]*h0[n];
    size_t yi = (size_t)jj*DIx;
    yp[yi] = f2b(b2f(yp[yi]) + f + dsk*x);
  }
}

// ---------------- gated rms (y bf16 in) ----------------
__global__ __launch_bounds__(256) void k_gatedrms(const u16* __restrict__ y, const float* __restrict__ proj,
     const float* __restrict__ w, u16* __restrict__ yn){
  int row = blockIdx.x, tid = threadIdx.x;
  const u16* yr = y + (size_t)row*DIx;
  const float* zr = proj + (size_t)row*TOTx + DIx;
  float v[8]; float ss=0.f;
  #pragma unroll
  for (int i=0;i<8;i++){
    int cidx = tid + i*256;
    float z = zr[cidx];
    float g = b2f(yr[cidx]) * (z / (1.0f + expf(-z)));
    v[i]=g; ss += g*g;
  }
  ss = block_sum256(ss);
  float sc = rsqrtf(ss*(1.0f/2048.0f) + 1e-6f);
  u16* d = yn + (size_t)row*DIx;
  #pragma unroll
  for (int i=0;i<8;i++){ int cidx=tid+i*256; d[cidx] = f2b(v[i]*sc*w[cidx]); }
}

// ---------------- h = x + sout; u2 = rms(h)*w (bf16) ----------------
__global__ __launch_bounds__(256) void k_addrms(const float* __restrict__ x, const float* __restrict__ sout,
     const float* __restrict__ w, float* __restrict__ hbuf, u16* __restrict__ u2){
  int row=blockIdx.x, tid=threadIdx.x;
  float v[4]; float ss=0.f;
  #pragma unroll
  for (int i=0;i<4;i++){
    int cidx = tid + i*256;
    size_t idx = (size_t)row*1024 + cidx;
    float hv = x[idx] + sout[idx];
    hbuf[idx]=hv; v[i]=hv; ss+=hv*hv;
  }
  ss = block_sum256(ss);
  float sc = rsqrtf(ss*(1.0f/1024.0f)+1e-6f);
  #pragma unroll
  for (int i=0;i<4;i++){ int cidx=tid+i*256; u2[(size_t)row*1024+cidx] = f2b(v[i]*sc*w[cidx]); }
}

// ---------------- rope + transpose to [B,H,T,HD] (bf16), fused-QKV bf16 input ----------------
__global__ __launch_bounds__(256) void k_rope(const u16* __restrict__ qkvb,
    u16* __restrict__ qr, u16* __restrict__ kr, u16* __restrict__ vr){
  int idx = blockIdx.x*256 + threadIdx.x;  // B*T*D
  int d = idx & 63;
  int h = (idx>>6) & 15;
  int t = (idx>>10) & 2047;
  int b = idx >> 21;
  int col = idx & 1023;
  size_t base = (size_t)(idx>>10)*3072;
  int dh = d & 31;
  float ang = (float)t * exp2f(-(float)dh * (13.287712379549449f/32.0f));  // t * 10000^(-dh/32)
  float cs = cosf(ang), sn = sinf(ang);
  int part = (d<32) ? 32 : -32;
  float q = b2f(qkvb[base + col]),        qp = b2f(qkvb[base + col + part]);
  float k = b2f(qkvb[base + 1024 + col]), kp = b2f(qkvb[base + 1024 + col + part]);
  float vv = b2f(qkvb[base + 2048 + col]);
  float rq = (d<32)? -qp : qp;
  float rk = (d<32)? -kp : kp;
  size_t dst = (((size_t)b*H_ATTN + h)*Tn + t)*64 + d;
  qr[dst] = f2b(q*cs + rq*sn);
  kr[dst] = f2b(k*cs + rk*sn);
  vr[dst] = f2b(vv);
}

// ---------------- MFMA sliding-window attention ----------------
#define QT 64
#define KSPAN 192
__device__ __forceinline__ u32 swz128a(int row, int b){  // tile stride 128B
  return (u32)((row*128 + b) ^ ((((row&7)^((row>>3)&7)))<<4));
}
__device__ __forceinline__ u32 swz384a(int row, int b){  // tile stride 384B
  return (u32)((row*384 + b) ^ ((((row&7)^((row>>3)&7)))<<4));
}

__global__ __launch_bounds__(256) void k_attn_mfma(const u16* __restrict__ qr, const u16* __restrict__ kr,
    const u16* __restrict__ vr, u16* __restrict__ ya){
  __shared__ u16 bufK[KSPAN*64];   // 24576 B ; later P[64][192]
  __shared__ u16 bufV[64*KSPAN];   // 24576 B
  int tid = threadIdx.x, lane = tid&63, wid = tid>>6;
  int fr = lane&15, fq = lane>>4;
  int blk = blockIdx.x;            // bh*32 + qt
  int qt = blk & 31, bh = blk >> 5;
  int t0 = qt*QT;
  size_t rowbase = (size_t)bh*Tn;
  char* cK = (char*)bufK;
  char* cV = (char*)bufV;

  #pragma unroll
  for (int it=0; it<6; ++it){
    int chunk = it*256 + tid;
    int row = chunk>>3, c8 = chunk&7;
    int sg = t0 - 128 + row;
    if (sg >= 0){
      short8 v = *(const short8*)(kr + (rowbase+sg)*64 + c8*8);
      *(short8*)(cK + swz128a(row, c8*16)) = v;
    }
  }
  // V transposed staging: 192 s-rows x 8 chunks of 8 d each; vectorized 16B reads
  #pragma unroll
  for (int it=0; it<6; ++it){
    int idx = it*256 + tid;          // 1536 items
    int s = idx>>3, c8 = idx&7, d0 = c8*8;
    int sg = t0 - 128 + s;
    short8 v;
    if (sg >= 0) v = *(const short8*)(vr + (rowbase+sg)*64 + d0);
    else         v = short8{0,0,0,0,0,0,0,0};
    #pragma unroll
    for (int e=0;e<8;e++)
      *(u16*)(cV + swz384a(d0+e, s*2)) = (u16)v[e];
  }
  __syncthreads();

  f32x4 acc[12];
  #pragma unroll
  for (int j=0;j<12;j++)
    #pragma unroll
    for (int r=0;r<4;r++) acc[j][r]=0.f;
  #pragma unroll
  for (int kk=0;kk<2;kk++){
    short8 aq = *(const short8*)(qr + (rowbase + t0 + wid*16 + fr)*64 + kk*32 + fq*8);
    #pragma unroll
    for (int j=0;j<12;j++){
      short8 bk = *(const short8*)(cK + swz128a(j*16+fr, kk*64 + fq*16));
      acc[j] = __builtin_amdgcn_mfma_f32_16x16x32_bf16(aq, bk, acc[j], 0,0,0);
    }
  }

  float p[12][4];
  int cb = lane&15;
  #pragma unroll
  for (int r=0;r<4;r++){
    int rq = wid*16 + (lane>>4)*4 + r;
    float m = -3.0e38f;
    #pragma unroll
    for (int j=0;j<12;j++){
      int c = j*16 + cb;
      bool allowed = (c > rq) && (c <= rq+128) && (c >= 128 - t0);
      float v = allowed ? acc[j][r]*0.125f : -3.0e38f;
      p[j][r] = v;
      m = fmaxf(m, v);
    }
    #pragma unroll
    for (int o=1;o<16;o<<=1) m = fmaxf(m, __shfl_xor(m, o, 64));
    float sum = 0.f;
    #pragma unroll
    for (int j=0;j<12;j++){ float e = __expf(p[j][r]-m); p[j][r]=e; sum += e; }
    #pragma unroll
    for (int o=1;o<16;o<<=1) sum += __shfl_xor(sum, o, 64);
    float inv = 1.0f/sum;
    #pragma unroll
    for (int j=0;j<12;j++) p[j][r] *= inv;
  }
  __syncthreads();

  #pragma unroll
  for (int r=0;r<4;r++){
    int rq = wid*16 + (lane>>4)*4 + r;
    #pragma unroll
    for (int j=0;j<12;j++){
      *(u16*)(cK + swz384a(rq, (j*16+cb)*2)) = f2b(p[j][r]);
    }
  }
  __syncthreads();

  f32x4 acc2[4];
  #pragma unroll
  for (int f=0;f<4;f++)
    #pragma unroll
    for (int r=0;r<4;r++) acc2[f][r]=0.f;
  #pragma unroll
  for (int kk=0;kk<6;kk++){
    short8 ap = *(const short8*)(cK + swz384a(wid*16 + fr, kk*64 + fq*16));
    #pragma unroll
    for (int f=0;f<4;f++){
      short8 bv = *(const short8*)(cV + swz384a(f*16+fr, kk*64 + fq*16));
      acc2[f] = __builtin_amdgcn_mfma_f32_16x16x32_bf16(ap, bv, acc2[f], 0,0,0);
    }
  }
  int b = bh >> 4, h = bh & 15;
  #pragma unroll
  for (int f=0;f<4;f++){
    int d = f*16 + cb;
    #pragma unroll
    for (int r=0;r<4;r++){
      int q = t0 + wid*16 + (lane>>4)*4 + r;
      ya[((size_t)b*Tn + q)*Dm + h*64 + d] = f2b(acc2[f][r]);
    }
  }
}

// =================================================================
extern "C" void kernel_launch(void* const* d_in, const int* in_sizes, int n_in,
                              void* d_out, int out_size, void* d_ws, size_t ws_size,
                              hipStream_t stream) {
  const float* x        = (const float*)d_in[0];
  const float* norm1_w  = (const float*)d_in[1];
  const float* norm2_w  = (const float*)d_in[2];
  const float* Win      = (const float*)d_in[3];
  const float* Wdt      = (const float*)d_in[4];
  const float* conv_w   = (const float*)d_in[5];
  const float* conv_b   = (const float*)d_in[6];
  const float* A_log    = (const float*)d_in[7];
  const float* Dskip    = (const float*)d_in[8];
  const float* dt_bias  = (const float*)d_in[9];
  const float* ssd_norm = (const float*)d_in[10];
  const float* Wout_ssd = (const float*)d_in[11];
  const float* Wres     = (const float*)d_in[12];
  const float* Wq       = (const float*)d_in[13];
  const float* Wk       = (const float*)d_in[14];
  const float* Wv       = (const float*)d_in[15];
  const float* Wo       = (const float*)d_in[16];

  char* ws = (char*)d_ws;
  size_t off = 0;
  auto alloc = [&](size_t bytes){ size_t r = off; off += (bytes + 255) & ~(size_t)255; return r; };

  size_t o_WinB  = alloc((size_t)TOTx*Dm*2);
  size_t o_WresB = alloc((size_t)DIx*Dm*2);
  size_t o_WoutB = alloc((size_t)Dm*DIx*2);
  size_t o_WqB   = alloc((size_t)Dm*Dm*2);
  size_t o_WkB   = alloc((size_t)Dm*Dm*2);
  size_t o_WvB   = alloc((size_t)Dm*Dm*2);
  size_t o_WoB   = alloc((size_t)Dm*Dm*2);
  size_t o_u1    = alloc((size_t)BT*Dm*2);        // later reused as vr
  size_t o_proj  = alloc((size_t)BT*TOTx*4);      // later: qkvb (bf16), qr/kr (bf16)
  size_t o_xc    = alloc((size_t)BT*DIx*4);       // sout @+0
  size_t o_dtA   = alloc((size_t)BT*H_SSM*Nst*4);
  size_t o_dtB   = alloc((size_t)BT*H_SSM*Nst*4);
  size_t o_expS  = alloc((size_t)BT*H_SSM*Nst*4);
  size_t o_LS    = alloc((size_t)Bsz*H_SSM*NCH*Px*Nst*4);
  size_t o_H0    = alloc((size_t)Bsz*H_SSM*NCH*Px*Nst*4);
  size_t o_y     = alloc((size_t)BT*DIx*2);       // bf16 now; later yatt @+0
  size_t o_yn    = alloc((size_t)BT*DIx*2);
  size_t o_hb    = alloc((size_t)BT*Dm*4);

  u16* WinB  = (u16*)(ws + o_WinB);
  u16* WresB = (u16*)(ws + o_WresB);
  u16* WoutB = (u16*)(ws + o_WoutB);
  u16* WqB   = (u16*)(ws + o_WqB);
  u16* u1    = (u16*)(ws + o_u1);
  float* proj = (float*)(ws + o_proj);
  float* dtA  = (float*)(ws + o_dtA);
  float* dtB  = (float*)(ws + o_dtB);
  float* expS = (float*)(ws + o_expS);
  float* LS   = (float*)(ws + o_LS);
  float* H0   = (float*)(ws + o_H0);
  u16*   ybuf16 = (u16*)(ws + o_y);
  u16*   yn   = (u16*)(ws + o_yn);
  float* hb   = (float*)(ws + o_hb);
  // aliases (lifetimes disjoint)
  u16* qkvb = (u16*)(ws + o_proj);                // [BT][3072] bf16 = 24MiB (proj dead by then)
  u16* qr = (u16*)(ws + o_proj + 50331648);
  u16* kr = (u16*)(ws + o_proj + 58720256);
  u16* vr = u1;
  float* sout = (float*)(ws + o_xc);
  u16* yatt = (u16*)(ws + o_y);

  // fused weight convert
  {
    CvtArgs a;
    a.s[0]=Win;  a.d[0]=WinB;  a.n[0]=TOTx*Dm;
    a.s[1]=Wres; a.d[1]=WresB; a.n[1]=DIx*Dm;
    a.s[2]=Wout_ssd; a.d[2]=WoutB; a.n[2]=Dm*DIx;
    a.s[3]=Wq; a.d[3]=WqB; a.n[3]=Dm*Dm;
    a.s[4]=Wk; a.d[4]=(u16*)(ws + o_WkB); a.n[4]=Dm*Dm;
    a.s[5]=Wv; a.d[5]=(u16*)(ws + o_WvB); a.n[5]=Dm*Dm;
    a.s[6]=Wo; a.d[6]=(u16*)(ws + o_WoB); a.n[6]=Dm*Dm;
    int total4 = (a.n[0]+a.n[1]+a.n[2]+a.n[3]+a.n[4]+a.n[5]+a.n[6])/4;
    k_cvt_all<<<dim3((total4+255)/256), dim3(256), 0, stream>>>(a, total4);
  }

  // 1) u1 = rms(x, norm1_w)
  k_rms1024<<<dim3(BT), dim3(256), 0, stream>>>(x, norm1_w, u1);
  // 2) proj = u1 @ Win^T   (gx=35, 1120 blocks)
  k_gemm128p<<<dim3(35*32), dim3(256), 0, stream>>>(u1, WinB, proj, nullptr, nullptr, BT, TOTx, Dm, 35, 0);
  // 3) dt prep
  k_dtprep<<<dim3(BT*H_SSM/256), dim3(256), 0, stream>>>(proj, Wdt, dt_bias, A_log, dtA, dtB);
  // 4) chunked scan (conv+silu fused into scan1/scan3; y bf16)
  k_scan1<<<dim3(Bsz*H_SSM*NCH), dim3(256), 0, stream>>>(dtA, dtB, proj, conv_w, conv_b, expS, ybuf16, LS);
  k_scan2<<<dim3(Bsz*H_SSM), dim3(256), 0, stream>>>(expS, LS, H0);
  k_scan3<<<dim3(Bsz*H_SSM*NCH), dim3(256), 0, stream>>>(proj, expS, H0, conv_w, conv_b, Dskip, ybuf16);
  // 5) y += u1 @ Wres^T  (512 blocks, bf16 RMW epilogue)
  k_gemm128p<<<dim3(16*32), dim3(256), 0, stream>>>(u1, WresB, nullptr, ybuf16, nullptr, BT, DIx, Dm, 16, 4);
  // 6) yn = rms(y * silu(z)) * ssd_norm_w
  k_gatedrms<<<dim3(BT), dim3(256), 0, stream>>>(ybuf16, proj, ssd_norm, yn);
  // 7) sout = yn @ Wout^T  (256 blocks, K=2048)
  k_gemm128p<<<dim3(8*32), dim3(256), 0, stream>>>(yn, WoutB, sout, nullptr, nullptr, BT, Dm, DIx, 8, 0);
  // 8) h = x + sout; u2 = rms(h)*norm2_w
  k_addrms<<<dim3(BT), dim3(256), 0, stream>>>(x, sout, norm2_w, hb, (u16*)(ws + o_yn));
  u16* u2p = (u16*)(ws + o_yn);
  // 9) fused QKV projection, bf16 out  (768 blocks)
  k_gemm128p<<<dim3(24*32), dim3(256), 0, stream>>>(u2p, WqB, nullptr, qkvb, nullptr, BT, 3*Dm, Dm, 24, 2);
  // 10) rope + transpose (bf16 in)
  k_rope<<<dim3(BT*Dm/256), dim3(256), 0, stream>>>(qkvb, qr, kr, vr);
  // 11) attention (MFMA sliding-window)
  k_attn_mfma<<<dim3(Bsz*H_ATTN*(Tn/QT)), dim3(256), 0, stream>>>(qr, kr, vr, yatt);
  // 12) out = hb + yatt @ Wo^T  (256 blocks, fused final add)
  k_gemm128p<<<dim3(8*32), dim3(256), 0, stream>>>(yatt, (u16*)(ws + o_WoB), (float*)d_out, nullptr, hb, BT, Dm, Dm, 8, 3);
  (void)in_sizes; (void)n_in; (void)out_size; (void)ws_size;
}